// Round 1
// baseline (2987.420 us; speedup 1.0000x reference)
//
#include <hip/hip_runtime.h>
#include <math.h>

#define BB 8
#define PP 768
#define NPRI 76      // 4 + 72 prior channels
#define SS 36
#define CIN 64
#define CADJ 72
#define DD 512

#define H0 40
#define W0 100
#define H1 20
#define W1 50
#define H2 10
#define W2 25

// ---- bilinear sample, zeros outside (matches reference _bilinear) ----
__device__ __forceinline__ float bsample(const float* __restrict__ img, int H, int W,
                                         int C, int c, float x, float y)
{
    float x0f = floorf(x), y0f = floorf(y);
    int x0 = (int)x0f, y0 = (int)y0f;
    float wx1 = x - x0f, wy1 = y - y0f;
    float wx0 = 1.0f - wx1, wy0 = 1.0f - wy1;
    int xc0 = min(max(x0, 0), W - 1);
    int xc1 = min(max(x0 + 1, 0), W - 1);
    int yc0 = min(max(y0, 0), H - 1);
    int yc1 = min(max(y0 + 1, 0), H - 1);
    bool vx0 = (x0 >= 0) && (x0 < W);
    bool vx1 = (x0 + 1 >= 0) && (x0 + 1 < W);
    bool vy0 = (y0 >= 0) && (y0 < H);
    bool vy1 = (y0 + 1 >= 0) && (y0 + 1 < H);
    float w00 = (vx0 && vy0) ? wx0 * wy0 : 0.0f;
    float w01 = (vx1 && vy0) ? wx1 * wy0 : 0.0f;
    float w10 = (vx0 && vy1) ? wx0 * wy1 : 0.0f;
    float w11 = (vx1 && vy1) ? wx1 * wy1 : 0.0f;
    return w00 * img[((size_t)yc0 * W + xc0) * C + c]
         + w01 * img[((size_t)yc0 * W + xc1) * C + c]
         + w10 * img[((size_t)yc1 * W + xc0) * C + c]
         + w11 * img[((size_t)yc1 * W + xc1) * C + c];
}

// ---- channel adjust: NCHW (B,64,H,W) -> NHWC (B,H,W,72) ----
__global__ __launch_bounds__(256) void k_adjust(const float* __restrict__ f,
    const float* __restrict__ caw, const float* __restrict__ cab,
    float* __restrict__ outp, int H, int W)
{
    int idx = blockIdx.x * 256 + threadIdx.x;
    int total = BB * H * W * CADJ;
    if (idx >= total) return;
    int o = idx % CADJ;
    int pix = idx / CADJ;
    int w = pix % W;
    int h = (pix / W) % H;
    int b = pix / (W * H);
    const float* fb = f + (size_t)b * CIN * H * W + (size_t)h * W + w;
    const float* wr = caw + o * CIN;
    int HW = H * W;
    float acc = cab[o];
#pragma unroll 8
    for (int c = 0; c < CIN; ++c) acc = fmaf(fb[(size_t)c * HW], wr[c], acc);
    outp[idx] = acc;
}

// ---- offset head on level-0 adjusted features: 72 -> 72 ----
__global__ __launch_bounds__(256) void k_off(const float* __restrict__ fe,
    const float* __restrict__ ow, const float* __restrict__ ob, float* __restrict__ outp)
{
    int idx = blockIdx.x * 256 + threadIdx.x;
    const int total = BB * H0 * W0 * CADJ;
    if (idx >= total) return;
    int o = idx % CADJ;
    int pix = idx / CADJ;
    const float* fr = fe + (size_t)pix * CADJ;
    const float* wr = ow + o * CADJ;
    float acc = ob[o];
#pragma unroll 8
    for (int c = 0; c < CADJ; ++c) acc = fmaf(fr[c], wr[c], acc);
    outp[idx] = acc;
}

// ---- align-corners bilinear resize of offs0 (B,40,100,72) -> (B,Ht,Wt,72) ----
__global__ __launch_bounds__(256) void k_resize(const float* __restrict__ src,
    float* __restrict__ dst, int Ht, int Wt)
{
    int idx = blockIdx.x * 256 + threadIdx.x;
    int total = BB * Ht * Wt * CADJ;
    if (idx >= total) return;
    int c = idx % CADJ;
    int j = (idx / CADJ) % Wt;
    int i = (idx / (CADJ * Wt)) % Ht;
    int b = idx / (CADJ * Wt * Ht);
    float sy = fminf((float)i * ((float)(H0 - 1) / (float)(Ht - 1)), (float)(H0 - 1));
    float sx = fminf((float)j * ((float)(W0 - 1) / (float)(Wt - 1)), (float)(W0 - 1));
    dst[idx] = bsample(src + (size_t)b * H0 * W0 * CADJ, H0, W0, CADJ, c, sx, sy);
}

// ---- fused: deformable sampling (3 levels) + z-softmax fuse + dp + grouped gf ----
// one block per (b,p)
__global__ __launch_bounds__(256) void k_sample(
    const float* __restrict__ priors,
    const float* __restrict__ feats0, const float* __restrict__ feats1, const float* __restrict__ feats2,
    const float* __restrict__ offs0,  const float* __restrict__ offs1,  const float* __restrict__ offs2,
    const float* __restrict__ z_emb,
    const float* __restrict__ dp_w, const float* __restrict__ dp_b,
    const float* __restrict__ gf_w, const float* __restrict__ gf_b,
    float* __restrict__ feature)
{
    const int bp = blockIdx.x;
    const int b = bp / PP;
    const int tid = threadIdx.x;

    __shared__ float smp[SS][CADJ];
    __shared__ float fs[SS][CADJ];
    __shared__ float zw[3][SS];
    __shared__ float wgt[3][SS][4];
    __shared__ int cx0s[3][SS];
    __shared__ int cy0s[3][SS];

    const int Hs[3] = {H0, H1, H2};
    const int Wsz[3] = {W0, W1, W2};
    const float* Fb[3] = { feats0 + (size_t)b * H0 * W0 * CADJ,
                           feats1 + (size_t)b * H1 * W1 * CADJ,
                           feats2 + (size_t)b * H2 * W2 * CADJ };
    const float* Ob[3] = { offs0 + (size_t)b * H0 * W0 * CADJ,
                           offs1 + (size_t)b * H1 * W1 * CADJ,
                           offs2 + (size_t)b * H2 * W2 * CADJ };

    if (tid < SS) {
        const int s = tid;
        // m = sx_idx[35 - s], sx_idx = floor(linspace(0,1,36)*71)
        const float t = (float)(35 - s) / 35.0f;
        const int m = (int)floorf(t * 71.0f);
        const float pfx = priors[(size_t)bp * NPRI + 4 + m];
        const float gxv = fminf(fmaxf(pfx / 71.0f, 0.0f), 1.0f) * 2.0f - 1.0f;
        const float gyv = (1.0f - (float)m / 71.0f) * 2.0f - 1.0f;
        // z-softmax over 3 levels (sums to 1 -> dp_b applied once later)
        const float z = z_emb[s];
        const float e0 = expf(-0.5f * z * z);
        const float e1 = expf(-0.5f * (z - 1.0f) * (z - 1.0f));
        const float e2 = expf(-0.5f * (z - 2.0f) * (z - 2.0f));
        const float inv = 1.0f / (e0 + e1 + e2);
        zw[0][s] = e0 * inv; zw[1][s] = e1 * inv; zw[2][s] = e2 * inv;
#pragma unroll
        for (int l = 0; l < 3; ++l) {
            const int Hl = Hs[l], Wl = Wsz[l];
            const float px = (gxv + 1.0f) * 0.5f * (float)(Wl - 1);
            const float py = (gyv + 1.0f) * 0.5f * (float)(Hl - 1);
            // only channels 2s, 2s+1 survive the diagonal gather in the reference
            const float dy = bsample(Ob[l], Hl, Wl, CADJ, 2 * s,     px, py);
            const float dx = bsample(Ob[l], Hl, Wl, CADJ, 2 * s + 1, px, py);
            const float sx = px + dx, sy = py + dy;
            const float x0f = floorf(sx), y0f = floorf(sy);
            const int x0 = (int)x0f, y0 = (int)y0f;
            const float wx1 = sx - x0f, wy1 = sy - y0f;
            const float wx0 = 1.0f - wx1, wy0 = 1.0f - wy1;
            const bool vx0 = (x0 >= 0) && (x0 < Wl);
            const bool vx1 = (x0 + 1 >= 0) && (x0 + 1 < Wl);
            const bool vy0 = (y0 >= 0) && (y0 < Hl);
            const bool vy1 = (y0 + 1 >= 0) && (y0 + 1 < Hl);
            wgt[l][s][0] = (vx0 && vy0) ? wx0 * wy0 : 0.0f;
            wgt[l][s][1] = (vx1 && vy0) ? wx1 * wy0 : 0.0f;
            wgt[l][s][2] = (vx0 && vy1) ? wx0 * wy1 : 0.0f;
            wgt[l][s][3] = (vx1 && vy1) ? wx1 * wy1 : 0.0f;
            cx0s[l][s] = x0; cy0s[l][s] = y0;
        }
    }
    __syncthreads();

    // 72-channel feature sample per (s, level), z-weighted sum over levels
    for (int idx = tid; idx < SS * CADJ; idx += 256) {
        const int s = idx / CADJ, k = idx % CADJ;
        float acc = 0.0f;
#pragma unroll
        for (int l = 0; l < 3; ++l) {
            const int Hl = Hs[l], Wl = Wsz[l];
            const int x0 = cx0s[l][s], y0 = cy0s[l][s];
            const int xc0 = min(max(x0, 0), Wl - 1);
            const int xc1 = min(max(x0 + 1, 0), Wl - 1);
            const int yc0 = min(max(y0, 0), Hl - 1);
            const int yc1 = min(max(y0 + 1, 0), Hl - 1);
            const float* F = Fb[l];
            float v = wgt[l][s][0] * F[((size_t)yc0 * Wl + xc0) * CADJ + k]
                    + wgt[l][s][1] * F[((size_t)yc0 * Wl + xc1) * CADJ + k]
                    + wgt[l][s][2] * F[((size_t)yc1 * Wl + xc0) * CADJ + k]
                    + wgt[l][s][3] * F[((size_t)yc1 * Wl + xc1) * CADJ + k];
            acc = fmaf(zw[l][s], v, acc);
        }
        smp[s][k] = acc;
    }
    __syncthreads();

    // dp: 72 -> 72 per s
    for (int idx = tid; idx < SS * CADJ; idx += 256) {
        const int s = idx / CADJ, c = idx % CADJ;
        const float* wr = dp_w + c * CADJ;
        float acc = dp_b[c];
#pragma unroll 8
        for (int k = 0; k < CADJ; ++k) acc = fmaf(smp[s][k], wr[k], acc);
        fs[s][c] = acc;
    }
    __syncthreads();

    // grouped gather-fc: out[g*128+o] = gf_b + sum_{i<9,k<72} fs[g*9+i][k]*gf_w[o][i][k]
    for (int o = tid; o < DD; o += 256) {
        const int g = o >> 7;
        const float* wr = gf_w + (size_t)o * (9 * CADJ);
        const float* fr = &fs[g * 9][0];
        float acc = gf_b[o];
#pragma unroll 8
        for (int ik = 0; ik < 9 * CADJ; ++ik) acc = fmaf(fr[ik], wr[ik], acc);
        feature[(size_t)bp * DD + o] = acc;
    }
}

// ---- f32 tiled GEMM: C[M,N] = act(A[M,K] @ W[N,K]^T + bias (+ Res)) ----
__global__ __launch_bounds__(256) void k_gemm(
    const float* __restrict__ A, const float* __restrict__ W,
    const float* __restrict__ bias, const float* __restrict__ Res,
    float* __restrict__ C, int M, int N, int K, int do_relu)
{
    __shared__ float As[64][17];
    __shared__ float Bs[64][17];
    const int tid = threadIdx.x;
    const int tx = tid & 15, ty = tid >> 4;
    const int m0 = blockIdx.y * 64, n0 = blockIdx.x * 64;
    float acc[4][4] = {{0.0f}};
    const int mm = tid >> 2, kkb = (tid & 3) << 2;
    for (int k0 = 0; k0 < K; k0 += 16) {
        float4 a4 = *reinterpret_cast<const float4*>(A + (size_t)(m0 + mm) * K + k0 + kkb);
        float4 b4 = *reinterpret_cast<const float4*>(W + (size_t)(n0 + mm) * K + k0 + kkb);
        As[mm][kkb] = a4.x; As[mm][kkb + 1] = a4.y; As[mm][kkb + 2] = a4.z; As[mm][kkb + 3] = a4.w;
        Bs[mm][kkb] = b4.x; Bs[mm][kkb + 1] = b4.y; Bs[mm][kkb + 2] = b4.z; Bs[mm][kkb + 3] = b4.w;
        __syncthreads();
#pragma unroll
        for (int kk = 0; kk < 16; ++kk) {
            float av[4], bv[4];
#pragma unroll
            for (int i = 0; i < 4; ++i) av[i] = As[ty * 4 + i][kk];
#pragma unroll
            for (int j = 0; j < 4; ++j) bv[j] = Bs[tx * 4 + j][kk];
#pragma unroll
            for (int i = 0; i < 4; ++i)
#pragma unroll
                for (int j = 0; j < 4; ++j) acc[i][j] = fmaf(av[i], bv[j], acc[i][j]);
        }
        __syncthreads();
    }
#pragma unroll
    for (int i = 0; i < 4; ++i) {
        const int m = m0 + ty * 4 + i;
#pragma unroll
        for (int j = 0; j < 4; ++j) {
            const int n = n0 + tx * 4 + j;
            float v = acc[i][j] + bias[n];
            if (Res) v += Res[(size_t)m * N + n];
            if (do_relu) v = fmaxf(v, 0.0f);
            C[(size_t)m * N + n] = v;
        }
    }
}

// ---- attention: one block per (b, g, 16-query tile) ----
__global__ __launch_bounds__(256) void k_attn(
    const float* __restrict__ Q, const float* __restrict__ Kx,
    const float* __restrict__ V, float* __restrict__ Out)
{
    const int nqt = PP / 16;
    int id = blockIdx.x;
    const int qt = id % nqt; id /= nqt;
    const int g = id % 4;
    const int b = id / 4;
    const int q0 = qt * 16;
    const int tid = threadIdx.x;

    __shared__ float Qs[16][129];
    __shared__ float sc[16][769];
    __shared__ float redm[16][17];
    __shared__ float reds[16][17];

    for (int idx = tid; idx < 16 * 128; idx += 256) {
        int r = idx >> 7, d = idx & 127;
        Qs[r][d] = Q[(size_t)(b * PP + q0 + r) * DD + g * 128 + d];
    }
    __syncthreads();
    const float scale = 0.08838834764831845f;  // 1/sqrt(128)
    for (int idx = tid; idx < 16 * PP; idx += 256) {
        int r = idx & 15, key = idx >> 4;
        const float* kp = Kx + (size_t)(b * PP + key) * DD + g * 128;
        const float* qp = Qs[r];
        float dot = 0.0f;
#pragma unroll 8
        for (int d = 0; d < 128; ++d) dot = fmaf(qp[d], kp[d], dot);
        sc[r][key] = dot * scale;
    }
    __syncthreads();
    {
        int r = tid >> 4, c = tid & 15;
        float mx = -3.0e38f;
        for (int key = c; key < PP; key += 16) mx = fmaxf(mx, sc[r][key]);
        redm[r][c] = mx;
    }
    __syncthreads();
    if (tid < 16) {
        float mx = -3.0e38f;
        for (int i = 0; i < 16; ++i) mx = fmaxf(mx, redm[tid][i]);
        redm[tid][16] = mx;
    }
    __syncthreads();
    {
        int r = tid >> 4, c = tid & 15;
        float mx = redm[r][16];
        float sum = 0.0f;
        for (int key = c; key < PP; key += 16) {
            float e = expf(sc[r][key] - mx);
            sc[r][key] = e;
            sum += e;
        }
        reds[r][c] = sum;
    }
    __syncthreads();
    if (tid < 16) {
        float sum = 0.0f;
        for (int i = 0; i < 16; ++i) sum += reds[tid][i];
        reds[tid][16] = 1.0f / sum;
    }
    __syncthreads();
    {
        const int d = tid & 127, h = tid >> 7;  // h in {0,1}: rows h*8..h*8+7
        float acc2[8] = {0.0f};
        for (int key = 0; key < PP; ++key) {
            float vv = V[(size_t)(b * PP + key) * DD + g * 128 + d];
#pragma unroll
            for (int rr = 0; rr < 8; ++rr) acc2[rr] = fmaf(sc[h * 8 + rr][key], vv, acc2[rr]);
        }
#pragma unroll
        for (int rr = 0; rr < 8; ++rr)
            Out[(size_t)(b * PP + q0 + h * 8 + rr) * DD + g * 128 + d]
                = acc2[rr] * reds[h * 8 + rr][16];
    }
}

// ---- final heads: cls (2), coeffs (4, with scale/bias), polynomial sigmoid (72) ----
__global__ __launch_bounds__(64) void k_head(
    const float* __restrict__ clsh, const float* __restrict__ ph,
    const float* __restrict__ cls_w2, const float* __restrict__ cls_b2,
    const float* __restrict__ p_w2, const float* __restrict__ p_b2,
    const float* __restrict__ b_scale, const float* __restrict__ b_bias,
    float* __restrict__ outp)
{
    const int bp = blockIdx.x;
    const int lane = threadIdx.x;
    const float* hr = clsh + (size_t)bp * DD;
    float a0 = 0.0f, a1 = 0.0f;
    for (int i = lane; i < DD; i += 64) {
        float h = hr[i];
        a0 = fmaf(h, cls_w2[i], a0);
        a1 = fmaf(h, cls_w2[DD + i], a1);
    }
    const float* pr = ph + (size_t)bp * 1024;
    float c0 = 0.0f, c1 = 0.0f, c2 = 0.0f, c3 = 0.0f;
    for (int i = lane; i < 1024; i += 64) {
        float h = pr[i];
        c0 = fmaf(h, p_w2[i], c0);
        c1 = fmaf(h, p_w2[1024 + i], c1);
        c2 = fmaf(h, p_w2[2048 + i], c2);
        c3 = fmaf(h, p_w2[3072 + i], c3);
    }
#pragma unroll
    for (int off = 32; off > 0; off >>= 1) {
        a0 += __shfl_down(a0, off);
        a1 += __shfl_down(a1, off);
        c0 += __shfl_down(c0, off);
        c1 += __shfl_down(c1, off);
        c2 += __shfl_down(c2, off);
        c3 += __shfl_down(c3, off);
    }
    a0 = __shfl(a0, 0); a1 = __shfl(a1, 0);
    c0 = __shfl(c0, 0); c1 = __shfl(c1, 0);
    c2 = __shfl(c2, 0); c3 = __shfl(c3, 0);
    const float k0 = c0 + p_b2[0];
    const float k1 = c1 + p_b2[1];
    const float scv = b_scale[0], biv = b_bias[0];
    const float k2 = (c2 + p_b2[2]) * scv + biv;
    const float k3 = (c3 + p_b2[3]) * scv + biv;
    float* orow = outp + (size_t)bp * 78;
    if (lane == 0) {
        orow[0] = a0 + cls_b2[0];
        orow[1] = a1 + cls_b2[1];
        orow[2] = k0; orow[3] = k1; orow[4] = k2; orow[5] = k3;
    }
    for (int o = lane; o < 72; o += 64) {
        float ys = (float)o / 71.0f;
        float tv = k0 + ys * (k1 + ys * (k2 + ys * k3));
        orow[6 + o] = 1.0f / (1.0f + expf(-tv));
    }
}

extern "C" void kernel_launch(void* const* d_in, const int* in_sizes, int n_in,
                              void* d_out, int out_size, void* d_ws, size_t ws_size,
                              hipStream_t stream)
{
    const float* feat0  = (const float*)d_in[0];
    const float* feat1  = (const float*)d_in[1];
    const float* feat2  = (const float*)d_in[2];
    const float* priors = (const float*)d_in[3];
    const float* ca_w   = (const float*)d_in[4];
    const float* ca_b   = (const float*)d_in[5];
    const float* off_w  = (const float*)d_in[6];
    const float* off_b  = (const float*)d_in[7];
    const float* dp_w   = (const float*)d_in[8];
    const float* dp_b   = (const float*)d_in[9];
    const float* z_emb  = (const float*)d_in[10];
    const float* gf_w   = (const float*)d_in[11];
    const float* gf_b   = (const float*)d_in[12];
    const float* wq     = (const float*)d_in[13];
    const float* bq     = (const float*)d_in[14];
    const float* wk     = (const float*)d_in[15];
    const float* bk     = (const float*)d_in[16];
    const float* wv     = (const float*)d_in[17];
    const float* bv     = (const float*)d_in[18];
    const float* wo     = (const float*)d_in[19];
    const float* bo     = (const float*)d_in[20];
    const float* cf_w1  = (const float*)d_in[21];
    const float* cf_b1  = (const float*)d_in[22];
    const float* cf_w2  = (const float*)d_in[23];
    const float* cf_b2  = (const float*)d_in[24];
    const float* cls_w1 = (const float*)d_in[25];
    const float* cls_b1 = (const float*)d_in[26];
    const float* cls_w2 = (const float*)d_in[27];
    const float* cls_b2 = (const float*)d_in[28];
    const float* reg_w1 = (const float*)d_in[29];
    const float* reg_b1 = (const float*)d_in[30];
    const float* p_w1   = (const float*)d_in[31];
    const float* p_b1   = (const float*)d_in[32];
    const float* p_w2   = (const float*)d_in[33];
    const float* p_b2   = (const float*)d_in[34];
    const float* b_scale = (const float*)d_in[35];
    const float* b_bias  = (const float*)d_in[36];
    float* out = (float*)d_out;

    // workspace layout (floats); peak ~25.2M floats = ~101 MB
    float* ws = (float*)d_ws;
    float* feature = ws;                       // [6144,512]
    float* fe0 = ws + 3145728;                 // [8,40,100,72]
    float* fe1 = fe0 + 2304000;                // [8,20,50,72]
    float* fe2 = fe1 + 576000;                 // [8,10,25,72]
    float* of0 = fe2 + 144000;                 // [8,40,100,72]
    float* of1 = of0 + 2304000;
    float* of2 = of1 + 576000;
    // post-sampling reuse (fe*/of* regions are dead after k_sample)
    float* qb = ws + 3145728;                  // [6144,512]
    float* kb = ws + 6291456;
    float* vb = ws + 9437184;
    float* tb = ws + 12582912;
    float* rb = ws + 15728640;
    float* hb = ws + 18874368;                 // [6144,1024]
    float* f2   = qb;                          // reuse after attention
    float* clsh = kb;
    float* regb = vb;
    float* phb  = hb;

    k_adjust<<<(BB * H0 * W0 * CADJ + 255) / 256, 256, 0, stream>>>(feat0, ca_w, ca_b, fe0, H0, W0);
    k_adjust<<<(BB * H1 * W1 * CADJ + 255) / 256, 256, 0, stream>>>(feat1, ca_w, ca_b, fe1, H1, W1);
    k_adjust<<<(BB * H2 * W2 * CADJ + 255) / 256, 256, 0, stream>>>(feat2, ca_w, ca_b, fe2, H2, W2);
    k_off<<<(BB * H0 * W0 * CADJ + 255) / 256, 256, 0, stream>>>(fe0, off_w, off_b, of0);
    k_resize<<<(BB * H1 * W1 * CADJ + 255) / 256, 256, 0, stream>>>(of0, of1, H1, W1);
    k_resize<<<(BB * H2 * W2 * CADJ + 255) / 256, 256, 0, stream>>>(of0, of2, H2, W2);
    k_sample<<<BB * PP, 256, 0, stream>>>(priors, fe0, fe1, fe2, of0, of1, of2,
                                          z_emb, dp_w, dp_b, gf_w, gf_b, feature);

    const int M = BB * PP;
    auto gemm = [&](const float* A, const float* W_, const float* bias,
                    const float* Res, float* Cp, int N, int K, int relu) {
        k_gemm<<<dim3(N / 64, M / 64), 256, 0, stream>>>(A, W_, bias, Res, Cp, M, N, K, relu);
    };

    gemm(feature, wq, bq, nullptr, qb, DD, DD, 0);
    gemm(feature, wk, bk, nullptr, kb, DD, DD, 0);
    gemm(feature, wv, bv, nullptr, vb, DD, DD, 0);
    k_attn<<<BB * 4 * (PP / 16), 256, 0, stream>>>(qb, kb, vb, tb);
    gemm(tb, wo, bo, nullptr, rb, DD, DD, 0);
    gemm(rb, cf_w1, cf_b1, nullptr, hb, 2 * DD, DD, 1);
    gemm(hb, cf_w2, cf_b2, feature, f2, DD, 2 * DD, 0);
    gemm(f2, cls_w1, cls_b1, nullptr, clsh, DD, DD, 1);
    gemm(f2, reg_w1, reg_b1, nullptr, regb, DD, DD, 1);
    gemm(regb, p_w1, p_b1, nullptr, phb, 2 * DD, DD, 1);
    k_head<<<M, 64, 0, stream>>>(clsh, phb, cls_w2, cls_b2, p_w2, p_b2, b_scale, b_bias, out);
}

// Round 2
// 1871.298 us; speedup vs baseline: 1.5964x; 1.5964x over previous
//
#include <hip/hip_runtime.h>
#include <math.h>

#define BB 8
#define PP 768
#define NPRI 76      // 4 + 72 prior channels
#define SS 36
#define CIN 64
#define CADJ 72
#define DD 512

#define H0 40
#define W0 100
#define H1 20
#define W1 50
#define H2 10
#define W2 25

// ---- bilinear sample, zeros outside (matches reference _bilinear) ----
__device__ __forceinline__ float bsample(const float* __restrict__ img, int H, int W,
                                         int C, int c, float x, float y)
{
    float x0f = floorf(x), y0f = floorf(y);
    int x0 = (int)x0f, y0 = (int)y0f;
    float wx1 = x - x0f, wy1 = y - y0f;
    float wx0 = 1.0f - wx1, wy0 = 1.0f - wy1;
    int xc0 = min(max(x0, 0), W - 1);
    int xc1 = min(max(x0 + 1, 0), W - 1);
    int yc0 = min(max(y0, 0), H - 1);
    int yc1 = min(max(y0 + 1, 0), H - 1);
    bool vx0 = (x0 >= 0) && (x0 < W);
    bool vx1 = (x0 + 1 >= 0) && (x0 + 1 < W);
    bool vy0 = (y0 >= 0) && (y0 < H);
    bool vy1 = (y0 + 1 >= 0) && (y0 + 1 < H);
    float w00 = (vx0 && vy0) ? wx0 * wy0 : 0.0f;
    float w01 = (vx1 && vy0) ? wx1 * wy0 : 0.0f;
    float w10 = (vx0 && vy1) ? wx0 * wy1 : 0.0f;
    float w11 = (vx1 && vy1) ? wx1 * wy1 : 0.0f;
    return w00 * img[((size_t)yc0 * W + xc0) * C + c]
         + w01 * img[((size_t)yc0 * W + xc1) * C + c]
         + w10 * img[((size_t)yc1 * W + xc0) * C + c]
         + w11 * img[((size_t)yc1 * W + xc1) * C + c];
}

// ---- channel adjust: NCHW (B,64,H,W) -> NHWC (B,H,W,72) ----
__global__ __launch_bounds__(256) void k_adjust(const float* __restrict__ f,
    const float* __restrict__ caw, const float* __restrict__ cab,
    float* __restrict__ outp, int H, int W)
{
    int idx = blockIdx.x * 256 + threadIdx.x;
    int total = BB * H * W * CADJ;
    if (idx >= total) return;
    int o = idx % CADJ;
    int pix = idx / CADJ;
    int w = pix % W;
    int h = (pix / W) % H;
    int b = pix / (W * H);
    const float* fb = f + (size_t)b * CIN * H * W + (size_t)h * W + w;
    const float* wr = caw + o * CIN;
    int HW = H * W;
    float acc = cab[o];
#pragma unroll 8
    for (int c = 0; c < CIN; ++c) acc = fmaf(fb[(size_t)c * HW], wr[c], acc);
    outp[idx] = acc;
}

// ---- offset head on level-0 adjusted features: 72 -> 72 ----
__global__ __launch_bounds__(256) void k_off(const float* __restrict__ fe,
    const float* __restrict__ ow, const float* __restrict__ ob, float* __restrict__ outp)
{
    int idx = blockIdx.x * 256 + threadIdx.x;
    const int total = BB * H0 * W0 * CADJ;
    if (idx >= total) return;
    int o = idx % CADJ;
    int pix = idx / CADJ;
    const float* fr = fe + (size_t)pix * CADJ;
    const float* wr = ow + o * CADJ;
    float acc = ob[o];
#pragma unroll 8
    for (int c = 0; c < CADJ; ++c) acc = fmaf(fr[c], wr[c], acc);
    outp[idx] = acc;
}

// ---- align-corners bilinear resize of offs0 (B,40,100,72) -> (B,Ht,Wt,72) ----
__global__ __launch_bounds__(256) void k_resize(const float* __restrict__ src,
    float* __restrict__ dst, int Ht, int Wt)
{
    int idx = blockIdx.x * 256 + threadIdx.x;
    int total = BB * Ht * Wt * CADJ;
    if (idx >= total) return;
    int c = idx % CADJ;
    int j = (idx / CADJ) % Wt;
    int i = (idx / (CADJ * Wt)) % Ht;
    int b = idx / (CADJ * Wt * Ht);
    float sy = fminf((float)i * ((float)(H0 - 1) / (float)(Ht - 1)), (float)(H0 - 1));
    float sx = fminf((float)j * ((float)(W0 - 1) / (float)(Wt - 1)), (float)(W0 - 1));
    dst[idx] = bsample(src + (size_t)b * H0 * W0 * CADJ, H0, W0, CADJ, c, sx, sy);
}

// ---- fused: deformable sampling (3 levels) + z-softmax fuse + dp (LDS-transposed) ----
// one block per (b,p); writes fs [M][36*72] coalesced
__global__ __launch_bounds__(256) void k_sample(
    const float* __restrict__ priors,
    const float* __restrict__ feats0, const float* __restrict__ feats1, const float* __restrict__ feats2,
    const float* __restrict__ offs0,  const float* __restrict__ offs1,  const float* __restrict__ offs2,
    const float* __restrict__ z_emb,
    const float* __restrict__ dp_w, const float* __restrict__ dp_b,
    float* __restrict__ fsout)
{
    const int bp = blockIdx.x;
    const int b = bp / PP;
    const int tid = threadIdx.x;

    __shared__ float dpT[CADJ][CADJ + 1];   // transposed dp_w, padded: conflict-free
    __shared__ float smp[SS][CADJ];
    __shared__ float zw[3][SS];
    __shared__ float wgt[3][SS][4];
    __shared__ int cx0s[3][SS];
    __shared__ int cy0s[3][SS];

    const int Hs[3] = {H0, H1, H2};
    const int Wsz[3] = {W0, W1, W2};
    const float* Fb[3] = { feats0 + (size_t)b * H0 * W0 * CADJ,
                           feats1 + (size_t)b * H1 * W1 * CADJ,
                           feats2 + (size_t)b * H2 * W2 * CADJ };
    const float* Ob[3] = { offs0 + (size_t)b * H0 * W0 * CADJ,
                           offs1 + (size_t)b * H1 * W1 * CADJ,
                           offs2 + (size_t)b * H2 * W2 * CADJ };

    // stage dp_w transposed into LDS (coalesced global read)
    for (int idx = tid; idx < CADJ * CADJ; idx += 256) {
        const int c = idx / CADJ, k = idx % CADJ;
        dpT[k][c] = dp_w[idx];
    }

    if (tid < 3 * SS) {
        const int s = tid % SS;
        const int l = tid / SS;
        // m = sx_idx[35 - s], sx_idx = floor(linspace(0,1,36)*71)
        const float t = (float)(35 - s) / 35.0f;
        const int m = (int)floorf(t * 71.0f);
        const float pfx = priors[(size_t)bp * NPRI + 4 + m];
        const float gxv = fminf(fmaxf(pfx / 71.0f, 0.0f), 1.0f) * 2.0f - 1.0f;
        const float gyv = (1.0f - (float)m / 71.0f) * 2.0f - 1.0f;
        // z-softmax over 3 levels (sums to 1 -> dp_b applied once later)
        const float z = z_emb[s];
        const float e0 = expf(-0.5f * z * z);
        const float e1 = expf(-0.5f * (z - 1.0f) * (z - 1.0f));
        const float e2 = expf(-0.5f * (z - 2.0f) * (z - 2.0f));
        const float inv = 1.0f / (e0 + e1 + e2);
        const float ev[3] = {e0, e1, e2};
        zw[l][s] = ev[l] * inv;

        const int Hl = Hs[l], Wl = Wsz[l];
        const float px = (gxv + 1.0f) * 0.5f * (float)(Wl - 1);
        const float py = (gyv + 1.0f) * 0.5f * (float)(Hl - 1);
        // only channels 2s, 2s+1 survive the diagonal gather in the reference
        const float dy = bsample(Ob[l], Hl, Wl, CADJ, 2 * s,     px, py);
        const float dx = bsample(Ob[l], Hl, Wl, CADJ, 2 * s + 1, px, py);
        const float sx = px + dx, sy = py + dy;
        const float x0f = floorf(sx), y0f = floorf(sy);
        const int x0 = (int)x0f, y0 = (int)y0f;
        const float wx1 = sx - x0f, wy1 = sy - y0f;
        const float wx0 = 1.0f - wx1, wy0 = 1.0f - wy1;
        const bool vx0 = (x0 >= 0) && (x0 < Wl);
        const bool vx1 = (x0 + 1 >= 0) && (x0 + 1 < Wl);
        const bool vy0 = (y0 >= 0) && (y0 < Hl);
        const bool vy1 = (y0 + 1 >= 0) && (y0 + 1 < Hl);
        wgt[l][s][0] = (vx0 && vy0) ? wx0 * wy0 : 0.0f;
        wgt[l][s][1] = (vx1 && vy0) ? wx1 * wy0 : 0.0f;
        wgt[l][s][2] = (vx0 && vy1) ? wx0 * wy1 : 0.0f;
        wgt[l][s][3] = (vx1 && vy1) ? wx1 * wy1 : 0.0f;
        cx0s[l][s] = x0; cy0s[l][s] = y0;
    }
    __syncthreads();

    // 72-channel feature sample per (s, level), z-weighted sum over levels
    for (int idx = tid; idx < SS * CADJ; idx += 256) {
        const int s = idx / CADJ, k = idx % CADJ;
        float acc = 0.0f;
#pragma unroll
        for (int l = 0; l < 3; ++l) {
            const int Hl = Hs[l], Wl = Wsz[l];
            const int x0 = cx0s[l][s], y0 = cy0s[l][s];
            const int xc0 = min(max(x0, 0), Wl - 1);
            const int xc1 = min(max(x0 + 1, 0), Wl - 1);
            const int yc0 = min(max(y0, 0), Hl - 1);
            const int yc1 = min(max(y0 + 1, 0), Hl - 1);
            const float* F = Fb[l];
            float v = wgt[l][s][0] * F[((size_t)yc0 * Wl + xc0) * CADJ + k]
                    + wgt[l][s][1] * F[((size_t)yc0 * Wl + xc1) * CADJ + k]
                    + wgt[l][s][2] * F[((size_t)yc1 * Wl + xc0) * CADJ + k]
                    + wgt[l][s][3] * F[((size_t)yc1 * Wl + xc1) * CADJ + k];
            acc = fmaf(zw[l][s], v, acc);
        }
        smp[s][k] = acc;
    }
    __syncthreads();

    // dp: 72 -> 72 per s; dpT read is stride-1 across lanes (conflict-free),
    // smp read is a broadcast. Coalesced global write.
    for (int idx = tid; idx < SS * CADJ; idx += 256) {
        const int s = idx / CADJ, c = idx % CADJ;
        const float* sr = smp[s];
        float acc = dp_b[c];
#pragma unroll 8
        for (int k = 0; k < CADJ; ++k) acc = fmaf(sr[k], dpT[k][c], acc);
        fsout[(size_t)bp * (SS * CADJ) + idx] = acc;
    }
}

// ---- grouped gather-fc as tiled GEMM: feature[m, g*128+n] =
//      gf_b[g*128+n] + sum_k fs[m, g*648+k] * gf_w[g*128+n, k]  (K=648) ----
__global__ __launch_bounds__(256) void k_gemm_gf(
    const float* __restrict__ A,    // fs [M][2592]
    const float* __restrict__ W,    // gf_w [512][648]
    const float* __restrict__ bias, // gf_b [512]
    float* __restrict__ C)          // feature [M][512]
{
    __shared__ float As[64][17];
    __shared__ float Bs[64][17];
    const int tid = threadIdx.x;
    const int tx = tid & 15, ty = tid >> 4;
    const int g = blockIdx.z;
    const int m0 = blockIdx.y * 64, n0 = blockIdx.x * 64;
    const int K = 648;
    float acc[4][4] = {{0.0f}};
    const int mm = tid >> 2, kkb = (tid & 3) << 2;
    const float* Abase = A + (size_t)(m0 + mm) * (SS * CADJ) + g * 648;
    const float* Wbase = W + (size_t)(g * 128 + n0 + mm) * 648;
    for (int k0 = 0; k0 < K; k0 += 16) {
        float4 a4 = make_float4(0.f, 0.f, 0.f, 0.f);
        float4 b4 = make_float4(0.f, 0.f, 0.f, 0.f);
        if (k0 + kkb < K) {
            a4 = *reinterpret_cast<const float4*>(Abase + k0 + kkb);
            b4 = *reinterpret_cast<const float4*>(Wbase + k0 + kkb);
        }
        As[mm][kkb] = a4.x; As[mm][kkb + 1] = a4.y; As[mm][kkb + 2] = a4.z; As[mm][kkb + 3] = a4.w;
        Bs[mm][kkb] = b4.x; Bs[mm][kkb + 1] = b4.y; Bs[mm][kkb + 2] = b4.z; Bs[mm][kkb + 3] = b4.w;
        __syncthreads();
#pragma unroll
        for (int kk = 0; kk < 16; ++kk) {
            float av[4], bv[4];
#pragma unroll
            for (int i = 0; i < 4; ++i) av[i] = As[ty * 4 + i][kk];
#pragma unroll
            for (int j = 0; j < 4; ++j) bv[j] = Bs[tx * 4 + j][kk];
#pragma unroll
            for (int i = 0; i < 4; ++i)
#pragma unroll
                for (int j = 0; j < 4; ++j) acc[i][j] = fmaf(av[i], bv[j], acc[i][j]);
        }
        __syncthreads();
    }
#pragma unroll
    for (int i = 0; i < 4; ++i) {
        const int m = m0 + ty * 4 + i;
#pragma unroll
        for (int j = 0; j < 4; ++j) {
            const int col = g * 128 + n0 + tx * 4 + j;
            C[(size_t)m * DD + col] = acc[i][j] + bias[col];
        }
    }
}

// ---- f32 tiled GEMM: C[M,N] = act(A[M,K] @ W[N,K]^T + bias (+ Res)) ----
__global__ __launch_bounds__(256) void k_gemm(
    const float* __restrict__ A, const float* __restrict__ W,
    const float* __restrict__ bias, const float* __restrict__ Res,
    float* __restrict__ C, int M, int N, int K, int do_relu)
{
    __shared__ float As[64][17];
    __shared__ float Bs[64][17];
    const int tid = threadIdx.x;
    const int tx = tid & 15, ty = tid >> 4;
    const int m0 = blockIdx.y * 64, n0 = blockIdx.x * 64;
    float acc[4][4] = {{0.0f}};
    const int mm = tid >> 2, kkb = (tid & 3) << 2;
    for (int k0 = 0; k0 < K; k0 += 16) {
        float4 a4 = *reinterpret_cast<const float4*>(A + (size_t)(m0 + mm) * K + k0 + kkb);
        float4 b4 = *reinterpret_cast<const float4*>(W + (size_t)(n0 + mm) * K + k0 + kkb);
        As[mm][kkb] = a4.x; As[mm][kkb + 1] = a4.y; As[mm][kkb + 2] = a4.z; As[mm][kkb + 3] = a4.w;
        Bs[mm][kkb] = b4.x; Bs[mm][kkb + 1] = b4.y; Bs[mm][kkb + 2] = b4.z; Bs[mm][kkb + 3] = b4.w;
        __syncthreads();
#pragma unroll
        for (int kk = 0; kk < 16; ++kk) {
            float av[4], bv[4];
#pragma unroll
            for (int i = 0; i < 4; ++i) av[i] = As[ty * 4 + i][kk];
#pragma unroll
            for (int j = 0; j < 4; ++j) bv[j] = Bs[tx * 4 + j][kk];
#pragma unroll
            for (int i = 0; i < 4; ++i)
#pragma unroll
                for (int j = 0; j < 4; ++j) acc[i][j] = fmaf(av[i], bv[j], acc[i][j]);
        }
        __syncthreads();
    }
#pragma unroll
    for (int i = 0; i < 4; ++i) {
        const int m = m0 + ty * 4 + i;
#pragma unroll
        for (int j = 0; j < 4; ++j) {
            const int n = n0 + tx * 4 + j;
            float v = acc[i][j] + bias[n];
            if (Res) v += Res[(size_t)m * N + n];
            if (do_relu) v = fmaxf(v, 0.0f);
            C[(size_t)m * N + n] = v;
        }
    }
}

// ---- attention: one block per (b, g, 16-query tile) ----
__global__ __launch_bounds__(256) void k_attn(
    const float* __restrict__ Q, const float* __restrict__ Kx,
    const float* __restrict__ V, float* __restrict__ Out)
{
    const int nqt = PP / 16;
    int id = blockIdx.x;
    const int qt = id % nqt; id /= nqt;
    const int g = id % 4;
    const int b = id / 4;
    const int q0 = qt * 16;
    const int tid = threadIdx.x;

    __shared__ float Qs[16][129];
    __shared__ float sc[16][769];
    __shared__ float redm[16][17];
    __shared__ float reds[16][17];

    for (int idx = tid; idx < 16 * 128; idx += 256) {
        int r = idx >> 7, d = idx & 127;
        Qs[r][d] = Q[(size_t)(b * PP + q0 + r) * DD + g * 128 + d];
    }
    __syncthreads();
    const float scale = 0.08838834764831845f;  // 1/sqrt(128)
    for (int idx = tid; idx < 16 * PP; idx += 256) {
        int r = idx & 15, key = idx >> 4;
        const float* kp = Kx + (size_t)(b * PP + key) * DD + g * 128;
        const float* qp = Qs[r];
        float dot = 0.0f;
#pragma unroll 8
        for (int d = 0; d < 128; ++d) dot = fmaf(qp[d], kp[d], dot);
        sc[r][key] = dot * scale;
    }
    __syncthreads();
    {
        int r = tid >> 4, c = tid & 15;
        float mx = -3.0e38f;
        for (int key = c; key < PP; key += 16) mx = fmaxf(mx, sc[r][key]);
        redm[r][c] = mx;
    }
    __syncthreads();
    if (tid < 16) {
        float mx = -3.0e38f;
        for (int i = 0; i < 16; ++i) mx = fmaxf(mx, redm[tid][i]);
        redm[tid][16] = mx;
    }
    __syncthreads();
    {
        int r = tid >> 4, c = tid & 15;
        float mx = redm[r][16];
        float sum = 0.0f;
        for (int key = c; key < PP; key += 16) {
            float e = expf(sc[r][key] - mx);
            sc[r][key] = e;
            sum += e;
        }
        reds[r][c] = sum;
    }
    __syncthreads();
    if (tid < 16) {
        float sum = 0.0f;
        for (int i = 0; i < 16; ++i) sum += reds[tid][i];
        reds[tid][16] = 1.0f / sum;
    }
    __syncthreads();
    {
        const int d = tid & 127, h = tid >> 7;  // h in {0,1}: rows h*8..h*8+7
        float acc2[8] = {0.0f};
        for (int key = 0; key < PP; ++key) {
            float vv = V[(size_t)(b * PP + key) * DD + g * 128 + d];
#pragma unroll
            for (int rr = 0; rr < 8; ++rr) acc2[rr] = fmaf(sc[h * 8 + rr][key], vv, acc2[rr]);
        }
#pragma unroll
        for (int rr = 0; rr < 8; ++rr)
            Out[(size_t)(b * PP + q0 + h * 8 + rr) * DD + g * 128 + d]
                = acc2[rr] * reds[h * 8 + rr][16];
    }
}

// ---- final heads: cls (2), coeffs (4, with scale/bias), polynomial sigmoid (72) ----
__global__ __launch_bounds__(64) void k_head(
    const float* __restrict__ clsh, const float* __restrict__ ph,
    const float* __restrict__ cls_w2, const float* __restrict__ cls_b2,
    const float* __restrict__ p_w2, const float* __restrict__ p_b2,
    const float* __restrict__ b_scale, const float* __restrict__ b_bias,
    float* __restrict__ outp)
{
    const int bp = blockIdx.x;
    const int lane = threadIdx.x;
    const float* hr = clsh + (size_t)bp * DD;
    float a0 = 0.0f, a1 = 0.0f;
    for (int i = lane; i < DD; i += 64) {
        float h = hr[i];
        a0 = fmaf(h, cls_w2[i], a0);
        a1 = fmaf(h, cls_w2[DD + i], a1);
    }
    const float* pr = ph + (size_t)bp * 1024;
    float c0 = 0.0f, c1 = 0.0f, c2 = 0.0f, c3 = 0.0f;
    for (int i = lane; i < 1024; i += 64) {
        float h = pr[i];
        c0 = fmaf(h, p_w2[i], c0);
        c1 = fmaf(h, p_w2[1024 + i], c1);
        c2 = fmaf(h, p_w2[2048 + i], c2);
        c3 = fmaf(h, p_w2[3072 + i], c3);
    }
#pragma unroll
    for (int off = 32; off > 0; off >>= 1) {
        a0 += __shfl_down(a0, off);
        a1 += __shfl_down(a1, off);
        c0 += __shfl_down(c0, off);
        c1 += __shfl_down(c1, off);
        c2 += __shfl_down(c2, off);
        c3 += __shfl_down(c3, off);
    }
    a0 = __shfl(a0, 0); a1 = __shfl(a1, 0);
    c0 = __shfl(c0, 0); c1 = __shfl(c1, 0);
    c2 = __shfl(c2, 0); c3 = __shfl(c3, 0);
    const float k0 = c0 + p_b2[0];
    const float k1 = c1 + p_b2[1];
    const float scv = b_scale[0], biv = b_bias[0];
    const float k2 = (c2 + p_b2[2]) * scv + biv;
    const float k3 = (c3 + p_b2[3]) * scv + biv;
    float* orow = outp + (size_t)bp * 78;
    if (lane == 0) {
        orow[0] = a0 + cls_b2[0];
        orow[1] = a1 + cls_b2[1];
        orow[2] = k0; orow[3] = k1; orow[4] = k2; orow[5] = k3;
    }
    for (int o = lane; o < 72; o += 64) {
        float ys = (float)o / 71.0f;
        float tv = k0 + ys * (k1 + ys * (k2 + ys * k3));
        orow[6 + o] = 1.0f / (1.0f + expf(-tv));
    }
}

extern "C" void kernel_launch(void* const* d_in, const int* in_sizes, int n_in,
                              void* d_out, int out_size, void* d_ws, size_t ws_size,
                              hipStream_t stream)
{
    const float* feat0  = (const float*)d_in[0];
    const float* feat1  = (const float*)d_in[1];
    const float* feat2  = (const float*)d_in[2];
    const float* priors = (const float*)d_in[3];
    const float* ca_w   = (const float*)d_in[4];
    const float* ca_b   = (const float*)d_in[5];
    const float* off_w  = (const float*)d_in[6];
    const float* off_b  = (const float*)d_in[7];
    const float* dp_w   = (const float*)d_in[8];
    const float* dp_b   = (const float*)d_in[9];
    const float* z_emb  = (const float*)d_in[10];
    const float* gf_w   = (const float*)d_in[11];
    const float* gf_b   = (const float*)d_in[12];
    const float* wq     = (const float*)d_in[13];
    const float* bq     = (const float*)d_in[14];
    const float* wk     = (const float*)d_in[15];
    const float* bk     = (const float*)d_in[16];
    const float* wv     = (const float*)d_in[17];
    const float* bv     = (const float*)d_in[18];
    const float* wo     = (const float*)d_in[19];
    const float* bo     = (const float*)d_in[20];
    const float* cf_w1  = (const float*)d_in[21];
    const float* cf_b1  = (const float*)d_in[22];
    const float* cf_w2  = (const float*)d_in[23];
    const float* cf_b2  = (const float*)d_in[24];
    const float* cls_w1 = (const float*)d_in[25];
    const float* cls_b1 = (const float*)d_in[26];
    const float* cls_w2 = (const float*)d_in[27];
    const float* cls_b2 = (const float*)d_in[28];
    const float* reg_w1 = (const float*)d_in[29];
    const float* reg_b1 = (const float*)d_in[30];
    const float* p_w1   = (const float*)d_in[31];
    const float* p_b1   = (const float*)d_in[32];
    const float* p_w2   = (const float*)d_in[33];
    const float* p_b2   = (const float*)d_in[34];
    const float* b_scale = (const float*)d_in[35];
    const float* b_bias  = (const float*)d_in[36];
    float* out = (float*)d_out;

    // workspace layout (floats); peak 25,165,824 floats (same as round-1 proven)
    float* ws = (float*)d_ws;
    float* feature = ws;                       // [6144,512]              0 .. 3,145,728
    float* fsb = ws + 3145728;                 // fs [6144,2592]          .. 19,070,976
    float* fe0 = ws + 19070976;                // [8,40,100,72]           .. 21,374,976
    float* fe1 = ws + 21374976;                // [8,20,50,72]            .. 21,950,976
    float* fe2 = ws + 21950976;                // [8,10,25,72]            .. 22,094,976
    float* of0 = ws + 22094976;                //                         .. 24,398,976
    float* of1 = ws + 24398976;                //                         .. 24,974,976
    float* of2 = ws + 24974976;                //                         .. 25,118,976
    // post-gf reuse (fs/fe*/of* dead after k_gemm_gf)
    float* qb = ws + 3145728;                  // [6144,512]
    float* kb = ws + 6291456;
    float* vb = ws + 9437184;
    float* tb = ws + 12582912;
    float* rb = ws + 15728640;
    float* hb = ws + 18874368;                 // [6144,1024]             .. 25,165,824
    float* f2   = qb;                          // reuse after attention
    float* clsh = kb;
    float* regb = vb;
    float* phb  = hb;

    k_adjust<<<(BB * H0 * W0 * CADJ + 255) / 256, 256, 0, stream>>>(feat0, ca_w, ca_b, fe0, H0, W0);
    k_adjust<<<(BB * H1 * W1 * CADJ + 255) / 256, 256, 0, stream>>>(feat1, ca_w, ca_b, fe1, H1, W1);
    k_adjust<<<(BB * H2 * W2 * CADJ + 255) / 256, 256, 0, stream>>>(feat2, ca_w, ca_b, fe2, H2, W2);
    k_off<<<(BB * H0 * W0 * CADJ + 255) / 256, 256, 0, stream>>>(fe0, off_w, off_b, of0);
    k_resize<<<(BB * H1 * W1 * CADJ + 255) / 256, 256, 0, stream>>>(of0, of1, H1, W1);
    k_resize<<<(BB * H2 * W2 * CADJ + 255) / 256, 256, 0, stream>>>(of0, of2, H2, W2);
    k_sample<<<BB * PP, 256, 0, stream>>>(priors, fe0, fe1, fe2, of0, of1, of2,
                                          z_emb, dp_w, dp_b, fsb);
    k_gemm_gf<<<dim3(2, BB * PP / 64, 4), 256, 0, stream>>>(fsb, gf_w, gf_b, feature);

    const int M = BB * PP;
    auto gemm = [&](const float* A, const float* W_, const float* bias,
                    const float* Res, float* Cp, int N, int K, int relu) {
        k_gemm<<<dim3(N / 64, M / 64), 256, 0, stream>>>(A, W_, bias, Res, Cp, M, N, K, relu);
    };

    gemm(feature, wq, bq, nullptr, qb, DD, DD, 0);
    gemm(feature, wk, bk, nullptr, kb, DD, DD, 0);
    gemm(feature, wv, bv, nullptr, vb, DD, DD, 0);
    k_attn<<<BB * 4 * (PP / 16), 256, 0, stream>>>(qb, kb, vb, tb);
    gemm(tb, wo, bo, nullptr, rb, DD, DD, 0);
    gemm(rb, cf_w1, cf_b1, nullptr, hb, 2 * DD, DD, 1);
    gemm(hb, cf_w2, cf_b2, feature, f2, DD, 2 * DD, 0);
    gemm(f2, cls_w1, cls_b1, nullptr, clsh, DD, DD, 1);
    gemm(f2, reg_w1, reg_b1, nullptr, regb, DD, DD, 1);
    gemm(regb, p_w1, p_b1, nullptr, phb, 2 * DD, DD, 1);
    k_head<<<M, 64, 0, stream>>>(clsh, phb, cls_w2, cls_b2, p_w2, p_b2, b_scale, b_bias, out);
}

// Round 3
// 723.143 us; speedup vs baseline: 4.1312x; 2.5877x over previous
//
#include <hip/hip_runtime.h>
#include <hip/hip_bf16.h>
#include <math.h>

#define BB 8
#define PP 768
#define NPRI 76
#define SS 36
#define CIN 64
#define CADJ 72
#define DD 512

#define H0 40
#define W0 100
#define H1 20
#define W1 50
#define H2 10
#define W2 25

typedef __attribute__((ext_vector_type(8))) short bf16x8;
typedef __attribute__((ext_vector_type(4))) float f32x4;
#define MFMA_BF16 __builtin_amdgcn_mfma_f32_16x16x32_bf16

__device__ __forceinline__ __hip_bfloat16 to_bf16(float v) { return __float2bfloat16(v); }
__device__ __forceinline__ float bf2f(__hip_bfloat16 v) { return __bfloat162float(v); }

// ---- bilinear sample, zeros outside ----
__device__ __forceinline__ float bsample(const float* __restrict__ img, int H, int W,
                                         int C, int c, float x, float y)
{
    float x0f = floorf(x), y0f = floorf(y);
    int x0 = (int)x0f, y0 = (int)y0f;
    float wx1 = x - x0f, wy1 = y - y0f;
    float wx0 = 1.0f - wx1, wy0 = 1.0f - wy1;
    int xc0 = min(max(x0, 0), W - 1);
    int xc1 = min(max(x0 + 1, 0), W - 1);
    int yc0 = min(max(y0, 0), H - 1);
    int yc1 = min(max(y0 + 1, 0), H - 1);
    bool vx0 = (x0 >= 0) && (x0 < W);
    bool vx1 = (x0 + 1 >= 0) && (x0 + 1 < W);
    bool vy0 = (y0 >= 0) && (y0 < H);
    bool vy1 = (y0 + 1 >= 0) && (y0 + 1 < H);
    float w00 = (vx0 && vy0) ? wx0 * wy0 : 0.0f;
    float w01 = (vx1 && vy0) ? wx1 * wy0 : 0.0f;
    float w10 = (vx0 && vy1) ? wx0 * wy1 : 0.0f;
    float w11 = (vx1 && vy1) ? wx1 * wy1 : 0.0f;
    return w00 * img[((size_t)yc0 * W + xc0) * C + c]
         + w01 * img[((size_t)yc0 * W + xc1) * C + c]
         + w10 * img[((size_t)yc1 * W + xc0) * C + c]
         + w11 * img[((size_t)yc1 * W + xc1) * C + c];
}

// ---- weight cast: all trunk weights f32 -> bf16 (+ qkv bias concat f32) ----
__global__ __launch_bounds__(256) void k_wcast(
    const float* __restrict__ wq, const float* __restrict__ wk, const float* __restrict__ wv,
    const float* __restrict__ wo, const float* __restrict__ cf_w1, const float* __restrict__ cf_w2,
    const float* __restrict__ cls_w1, const float* __restrict__ reg_w1, const float* __restrict__ p_w1,
    const float* __restrict__ gf_w,
    const float* __restrict__ bq, const float* __restrict__ bk, const float* __restrict__ bv,
    __hip_bfloat16* __restrict__ wqkv, __hip_bfloat16* __restrict__ wo_bf,
    __hip_bfloat16* __restrict__ cf1_bf, __hip_bfloat16* __restrict__ cf2_bf,
    __hip_bfloat16* __restrict__ cls1_bf, __hip_bfloat16* __restrict__ reg1_bf,
    __hip_bfloat16* __restrict__ p1_bf, __hip_bfloat16* __restrict__ gf_bf,
    float* __restrict__ bqkv)
{
    long i = (long)blockIdx.x * 256 + threadIdx.x;
    if (i < 262144) { wqkv[i] = to_bf16(wq[i]); return; }
    i -= 262144;
    if (i < 262144) { wqkv[262144 + i] = to_bf16(wk[i]); return; }
    i -= 262144;
    if (i < 262144) { wqkv[524288 + i] = to_bf16(wv[i]); return; }
    i -= 262144;
    if (i < 262144) { wo_bf[i] = to_bf16(wo[i]); return; }
    i -= 262144;
    if (i < 524288) { cf1_bf[i] = to_bf16(cf_w1[i]); return; }
    i -= 524288;
    if (i < 524288) { cf2_bf[i] = to_bf16(cf_w2[i]); return; }
    i -= 524288;
    if (i < 262144) { cls1_bf[i] = to_bf16(cls_w1[i]); return; }
    i -= 262144;
    if (i < 262144) { reg1_bf[i] = to_bf16(reg_w1[i]); return; }
    i -= 262144;
    if (i < 524288) { p1_bf[i] = to_bf16(p_w1[i]); return; }
    i -= 524288;
    if (i < 344064) {  // gf_w [512][648] -> padded [512][672]
        int r = (int)(i / 672), c = (int)(i % 672);
        gf_bf[i] = (c < 648) ? to_bf16(gf_w[(size_t)r * 648 + c]) : to_bf16(0.0f);
        return;
    }
    i -= 344064;
    if (i < 512) bqkv[i] = bq[i];
    else if (i < 1024) bqkv[i] = bk[i - 512];
    else if (i < 1536) bqkv[i] = bv[i - 1024];
}

// ---- channel adjust: NCHW (B,64,H,W) -> NHWC (B,H,W,72) ----
__global__ __launch_bounds__(256) void k_adjust(const float* __restrict__ f,
    const float* __restrict__ caw, const float* __restrict__ cab,
    float* __restrict__ outp, int H, int W)
{
    int idx = blockIdx.x * 256 + threadIdx.x;
    int total = BB * H * W * CADJ;
    if (idx >= total) return;
    int o = idx % CADJ;
    int pix = idx / CADJ;
    int w = pix % W;
    int h = (pix / W) % H;
    int b = pix / (W * H);
    const float* fb = f + (size_t)b * CIN * H * W + (size_t)h * W + w;
    const float* wr = caw + o * CIN;
    int HW = H * W;
    float acc = cab[o];
#pragma unroll 8
    for (int c = 0; c < CIN; ++c) acc = fmaf(fb[(size_t)c * HW], wr[c], acc);
    outp[idx] = acc;
}

// ---- offset head ----
__global__ __launch_bounds__(256) void k_off(const float* __restrict__ fe,
    const float* __restrict__ ow, const float* __restrict__ ob, float* __restrict__ outp)
{
    int idx = blockIdx.x * 256 + threadIdx.x;
    const int total = BB * H0 * W0 * CADJ;
    if (idx >= total) return;
    int o = idx % CADJ;
    int pix = idx / CADJ;
    const float* fr = fe + (size_t)pix * CADJ;
    const float* wr = ow + o * CADJ;
    float acc = ob[o];
#pragma unroll 8
    for (int c = 0; c < CADJ; ++c) acc = fmaf(fr[c], wr[c], acc);
    outp[idx] = acc;
}

// ---- align-corners resize ----
__global__ __launch_bounds__(256) void k_resize(const float* __restrict__ src,
    float* __restrict__ dst, int Ht, int Wt)
{
    int idx = blockIdx.x * 256 + threadIdx.x;
    int total = BB * Ht * Wt * CADJ;
    if (idx >= total) return;
    int c = idx % CADJ;
    int j = (idx / CADJ) % Wt;
    int i = (idx / (CADJ * Wt)) % Ht;
    int b = idx / (CADJ * Wt * Ht);
    float sy = fminf((float)i * ((float)(H0 - 1) / (float)(Ht - 1)), (float)(H0 - 1));
    float sx = fminf((float)j * ((float)(W0 - 1) / (float)(Wt - 1)), (float)(W0 - 1));
    dst[idx] = bsample(src + (size_t)b * H0 * W0 * CADJ, H0, W0, CADJ, c, sx, sy);
}

// ---- fused sampling + z-fuse + dp; outputs fs bf16 [6144][4*672] (zero-padded) ----
__global__ __launch_bounds__(256) void k_sample(
    const float* __restrict__ priors,
    const float* __restrict__ feats0, const float* __restrict__ feats1, const float* __restrict__ feats2,
    const float* __restrict__ offs0,  const float* __restrict__ offs1,  const float* __restrict__ offs2,
    const float* __restrict__ z_emb,
    const float* __restrict__ dp_w, const float* __restrict__ dp_b,
    __hip_bfloat16* __restrict__ fsout)
{
    const int bp = blockIdx.x;
    const int b = bp / PP;
    const int tid = threadIdx.x;

    __shared__ float dpT[CADJ][CADJ + 1];
    __shared__ float smp[SS][CADJ];
    __shared__ float zw[3][SS];
    __shared__ float wgt[3][SS][4];
    __shared__ int cx0s[3][SS];
    __shared__ int cy0s[3][SS];

    const int Hs[3] = {H0, H1, H2};
    const int Wsz[3] = {W0, W1, W2};
    const float* Fb[3] = { feats0 + (size_t)b * H0 * W0 * CADJ,
                           feats1 + (size_t)b * H1 * W1 * CADJ,
                           feats2 + (size_t)b * H2 * W2 * CADJ };
    const float* Ob[3] = { offs0 + (size_t)b * H0 * W0 * CADJ,
                           offs1 + (size_t)b * H1 * W1 * CADJ,
                           offs2 + (size_t)b * H2 * W2 * CADJ };

    for (int idx = tid; idx < CADJ * CADJ; idx += 256) {
        const int c = idx / CADJ, k = idx % CADJ;
        dpT[k][c] = dp_w[idx];
    }

    if (tid < 3 * SS) {
        const int s = tid % SS;
        const int l = tid / SS;
        const float t = (float)(35 - s) / 35.0f;
        const int m = (int)floorf(t * 71.0f);
        const float pfx = priors[(size_t)bp * NPRI + 4 + m];
        const float gxv = fminf(fmaxf(pfx / 71.0f, 0.0f), 1.0f) * 2.0f - 1.0f;
        const float gyv = (1.0f - (float)m / 71.0f) * 2.0f - 1.0f;
        const float z = z_emb[s];
        const float e0 = expf(-0.5f * z * z);
        const float e1 = expf(-0.5f * (z - 1.0f) * (z - 1.0f));
        const float e2 = expf(-0.5f * (z - 2.0f) * (z - 2.0f));
        const float inv = 1.0f / (e0 + e1 + e2);
        const float ev[3] = {e0, e1, e2};
        zw[l][s] = ev[l] * inv;

        const int Hl = Hs[l], Wl = Wsz[l];
        const float px = (gxv + 1.0f) * 0.5f * (float)(Wl - 1);
        const float py = (gyv + 1.0f) * 0.5f * (float)(Hl - 1);
        const float dy = bsample(Ob[l], Hl, Wl, CADJ, 2 * s,     px, py);
        const float dx = bsample(Ob[l], Hl, Wl, CADJ, 2 * s + 1, px, py);
        const float sx = px + dx, sy = py + dy;
        const float x0f = floorf(sx), y0f = floorf(sy);
        const int x0 = (int)x0f, y0 = (int)y0f;
        const float wx1 = sx - x0f, wy1 = sy - y0f;
        const float wx0 = 1.0f - wx1, wy0 = 1.0f - wy1;
        const bool vx0 = (x0 >= 0) && (x0 < Wl);
        const bool vx1 = (x0 + 1 >= 0) && (x0 + 1 < Wl);
        const bool vy0 = (y0 >= 0) && (y0 < Hl);
        const bool vy1 = (y0 + 1 >= 0) && (y0 + 1 < Hl);
        wgt[l][s][0] = (vx0 && vy0) ? wx0 * wy0 : 0.0f;
        wgt[l][s][1] = (vx1 && vy0) ? wx1 * wy0 : 0.0f;
        wgt[l][s][2] = (vx0 && vy1) ? wx0 * wy1 : 0.0f;
        wgt[l][s][3] = (vx1 && vy1) ? wx1 * wy1 : 0.0f;
        cx0s[l][s] = x0; cy0s[l][s] = y0;
    }
    __syncthreads();

    for (int idx = tid; idx < SS * CADJ; idx += 256) {
        const int s = idx / CADJ, k = idx % CADJ;
        float acc = 0.0f;
#pragma unroll
        for (int l = 0; l < 3; ++l) {
            const int Hl = Hs[l], Wl = Wsz[l];
            const int x0 = cx0s[l][s], y0 = cy0s[l][s];
            const int xc0 = min(max(x0, 0), Wl - 1);
            const int xc1 = min(max(x0 + 1, 0), Wl - 1);
            const int yc0 = min(max(y0, 0), Hl - 1);
            const int yc1 = min(max(y0 + 1, 0), Hl - 1);
            const float* F = Fb[l];
            float v = wgt[l][s][0] * F[((size_t)yc0 * Wl + xc0) * CADJ + k]
                    + wgt[l][s][1] * F[((size_t)yc0 * Wl + xc1) * CADJ + k]
                    + wgt[l][s][2] * F[((size_t)yc1 * Wl + xc0) * CADJ + k]
                    + wgt[l][s][3] * F[((size_t)yc1 * Wl + xc1) * CADJ + k];
            acc = fmaf(zw[l][s], v, acc);
        }
        smp[s][k] = acc;
    }
    __syncthreads();

    // dp 72->72; write bf16 into group-padded layout [4][672]
    for (int idx = tid; idx < SS * CADJ; idx += 256) {
        const int s = idx / CADJ, c = idx % CADJ;
        const float* sr = smp[s];
        float acc = dp_b[c];
#pragma unroll 8
        for (int k = 0; k < CADJ; ++k) acc = fmaf(sr[k], dpT[k][c], acc);
        const int col = (s / 9) * 672 + (s % 9) * 72 + c;
        fsout[(size_t)bp * 2688 + col] = to_bf16(acc);
    }
    if (tid < 96) {  // zero the 24-col tail of each group
        const int g = tid / 24, t = tid % 24;
        fsout[(size_t)bp * 2688 + g * 672 + 648 + t] = to_bf16(0.0f);
    }
}

// ---- bf16 MFMA GEMM: C = act(A @ W^T + bias (+Res)), 64x64 tile, LDS-free ----
// A [M][lda] bf16 (z-offset sAz), W [N][ldw] bf16 (z-offset sWz), bias f32,
// C bf16 [M][ldc] at col offset z*sCz. grid = (N/64, M/64, nz)
__global__ __launch_bounds__(256) void k_bgemm(
    const __hip_bfloat16* __restrict__ A, int lda, long sAz,
    const __hip_bfloat16* __restrict__ W, int ldw, long sWz,
    const float* __restrict__ bias, int sBz,
    const __hip_bfloat16* __restrict__ Res, int ldres,
    __hip_bfloat16* __restrict__ C, int ldc, int sCz,
    int K, int relu)
{
    const int tid = threadIdx.x;
    const int lane = tid & 63, w = tid >> 6;
    const int wr = w >> 1, wc = w & 1;
    const int row16 = lane & 15, kg = lane >> 4;
    const int z = blockIdx.z;
    const int m_base = blockIdx.y * 64 + wr * 32;
    const int n_base = blockIdx.x * 64 + wc * 32;
    const __hip_bfloat16* Ar0 = A + z * sAz + (size_t)(m_base + row16) * lda + kg * 8;
    const __hip_bfloat16* Ar1 = Ar0 + (size_t)16 * lda;
    const __hip_bfloat16* Br0 = W + z * sWz + (size_t)(n_base + row16) * ldw + kg * 8;
    const __hip_bfloat16* Br1 = Br0 + (size_t)16 * ldw;
    f32x4 acc00 = {0.f, 0.f, 0.f, 0.f};
    f32x4 acc01 = acc00, acc10 = acc00, acc11 = acc00;
#pragma unroll 4
    for (int k0 = 0; k0 < K; k0 += 32) {
        bf16x8 a0 = *(const bf16x8*)(Ar0 + k0);
        bf16x8 a1 = *(const bf16x8*)(Ar1 + k0);
        bf16x8 b0 = *(const bf16x8*)(Br0 + k0);
        bf16x8 b1 = *(const bf16x8*)(Br1 + k0);
        acc00 = MFMA_BF16(a0, b0, acc00, 0, 0, 0);
        acc01 = MFMA_BF16(a0, b1, acc01, 0, 0, 0);
        acc10 = MFMA_BF16(a1, b0, acc10, 0, 0, 0);
        acc11 = MFMA_BF16(a1, b1, acc11, 0, 0, 0);
    }
    const float* bz = bias + (size_t)z * sBz;
    __hip_bfloat16* Cz = C + (size_t)z * sCz;
    f32x4 accs[2][2] = {{acc00, acc01}, {acc10, acc11}};
#pragma unroll
    for (int mt = 0; mt < 2; ++mt)
#pragma unroll
        for (int r = 0; r < 4; ++r) {
            const int row = m_base + mt * 16 + kg * 4 + r;
#pragma unroll
            for (int nt = 0; nt < 2; ++nt) {
                const int col = n_base + nt * 16 + row16;
                float v = accs[mt][nt][r] + bz[col];
                if (Res) v += bf2f(Res[(size_t)row * ldres + col]);
                if (relu) v = fmaxf(v, 0.0f);
                Cz[(size_t)row * ldc + col] = to_bf16(v);
            }
        }
}

// ---- flash attention, bf16 MFMA. qkv [6144][1536]; grid (12 qtiles, 32 bg) ----
__global__ __launch_bounds__(256) void k_fattn(
    const __hip_bfloat16* __restrict__ qkv, __hip_bfloat16* __restrict__ Out)
{
    const int qt = blockIdx.x, bg = blockIdx.y;
    const int b = bg >> 2, g = bg & 3;
    const int tid = threadIdx.x, lane = tid & 63, w = tid >> 6;
    const int row16 = lane & 15, kg = lane >> 4;
    const int q0 = qt * 64;

    __shared__ __hip_bfloat16 Klds[32][136];   // keys x dh, padded (2-way free)
    __shared__ __hip_bfloat16 Vtlds[128][40];  // dh x keys, padded
    __shared__ __hip_bfloat16 Plds[4][16][40]; // per-wave P tile

    // Q fragments (held in registers for entire kernel)
    const size_t rowQ = (size_t)(b * PP + q0 + w * 16 + row16) * 1536 + g * 128;
    bf16x8 aq[4];
#pragma unroll
    for (int t = 0; t < 4; ++t)
        aq[t] = *(const bf16x8*)(qkv + rowQ + t * 32 + kg * 8);

    f32x4 oacc[8];
#pragma unroll
    for (int dt = 0; dt < 8; ++dt) oacc[dt] = (f32x4){0.f, 0.f, 0.f, 0.f};
    float mrow[4] = {-INFINITY, -INFINITY, -INFINITY, -INFINITY};
    float lrow[4] = {0.f, 0.f, 0.f, 0.f};

    const __hip_bfloat16* Kbase = qkv + (size_t)(b * PP) * 1536 + 512 + g * 128;
    const __hip_bfloat16* Vbase = qkv + (size_t)(b * PP) * 1536 + 1024 + g * 128;
    const float sc = 0.08838834764831845f;  // 1/sqrt(128)

    for (int kt = 0; kt < 24; ++kt) {
        __syncthreads();  // previous tile's compute done before restage
        if (tid >= 128) {
            // stage K tile: 32 keys x 128
            const int t2 = tid - 128;
            const int r = t2 >> 2;
            const int cp = (t2 & 3) * 32;
            const __hip_bfloat16* src = Kbase + (size_t)(kt * 32 + r) * 1536 + cp;
            *(bf16x8*)&Klds[r][cp]      = *(const bf16x8*)(src);
            *(bf16x8*)&Klds[r][cp + 8]  = *(const bf16x8*)(src + 8);
            *(bf16x8*)&Klds[r][cp + 16] = *(const bf16x8*)(src + 16);
            *(bf16x8*)&Klds[r][cp + 24] = *(const bf16x8*)(src + 24);
        } else {
            // stage V transposed: Vtlds[d][key]
            const int kk = (tid >> 3) * 2;
            const int cp = (tid & 7) * 16;
            const __hip_bfloat16* v0p = Vbase + (size_t)(kt * 32 + kk) * 1536 + cp;
            bf16x8 x0a = *(const bf16x8*)(v0p);
            bf16x8 x0b = *(const bf16x8*)(v0p + 8);
            bf16x8 x1a = *(const bf16x8*)(v0p + 1536);
            bf16x8 x1b = *(const bf16x8*)(v0p + 1536 + 8);
#pragma unroll
            for (int i = 0; i < 8; ++i) {
                unsigned lo = (unsigned short)x0a[i], hi = (unsigned short)x1a[i];
                *(unsigned*)&Vtlds[cp + i][kk] = lo | (hi << 16);
                unsigned lo2 = (unsigned short)x0b[i], hi2 = (unsigned short)x1b[i];
                *(unsigned*)&Vtlds[cp + 8 + i][kk] = lo2 | (hi2 << 16);
            }
        }
        __syncthreads();

        // S = Q @ K^T  (16 q-rows per wave x 32 keys)
        f32x4 s0 = {0.f, 0.f, 0.f, 0.f}, s1 = s0;
#pragma unroll
        for (int t = 0; t < 4; ++t) {
            bf16x8 bk0 = *(const bf16x8*)&Klds[row16][t * 32 + kg * 8];
            bf16x8 bk1 = *(const bf16x8*)&Klds[16 + row16][t * 32 + kg * 8];
            s0 = MFMA_BF16(aq[t], bk0, s0, 0, 0, 0);
            s1 = MFMA_BF16(aq[t], bk1, s1, 0, 0, 0);
        }

        // online softmax; lane holds rows kg*4+r, cols row16 / 16+row16
#pragma unroll
        for (int r = 0; r < 4; ++r) {
            float v0 = s0[r] * sc, v1 = s1[r] * sc;
            float mx = fmaxf(v0, v1);
            mx = fmaxf(mx, __shfl_xor(mx, 1));
            mx = fmaxf(mx, __shfl_xor(mx, 2));
            mx = fmaxf(mx, __shfl_xor(mx, 4));
            mx = fmaxf(mx, __shfl_xor(mx, 8));
            const float mnew = fmaxf(mrow[r], mx);
            const float scale_old = __expf(mrow[r] - mnew);
            const float p0 = __expf(v0 - mnew);
            const float p1 = __expf(v1 - mnew);
            float rs = p0 + p1;
            rs += __shfl_xor(rs, 1);
            rs += __shfl_xor(rs, 2);
            rs += __shfl_xor(rs, 4);
            rs += __shfl_xor(rs, 8);
            lrow[r] = lrow[r] * scale_old + rs;
            mrow[r] = mnew;
#pragma unroll
            for (int dt = 0; dt < 8; ++dt) oacc[dt][r] *= scale_old;
            Plds[w][kg * 4 + r][row16]      = to_bf16(p0);
            Plds[w][kg * 4 + r][16 + row16] = to_bf16(p1);
        }

        // O += P @ V
        bf16x8 ap = *(const bf16x8*)&Plds[w][row16][kg * 8];
#pragma unroll
        for (int dt = 0; dt < 8; ++dt) {
            bf16x8 bv = *(const bf16x8*)&Vtlds[dt * 16 + row16][kg * 8];
            oacc[dt] = MFMA_BF16(ap, bv, oacc[dt], 0, 0, 0);
        }
    }

    // epilogue: normalize, write bf16
    const size_t obase = (size_t)(b * PP + q0 + w * 16 + kg * 4) * DD + g * 128;
#pragma unroll
    for (int r = 0; r < 4; ++r) {
        const float inv = 1.0f / lrow[r];
#pragma unroll
        for (int dt = 0; dt < 8; ++dt)
            Out[obase + (size_t)r * DD + dt * 16 + row16] = to_bf16(oacc[dt][r] * inv);
    }
}

// ---- final heads (bf16 inputs) ----
__global__ __launch_bounds__(64) void k_head(
    const __hip_bfloat16* __restrict__ clsh, const __hip_bfloat16* __restrict__ ph,
    const float* __restrict__ cls_w2, const float* __restrict__ cls_b2,
    const float* __restrict__ p_w2, const float* __restrict__ p_b2,
    const float* __restrict__ b_scale, const float* __restrict__ b_bias,
    float* __restrict__ outp)
{
    const int bp = blockIdx.x;
    const int lane = threadIdx.x;
    const __hip_bfloat16* hr = clsh + (size_t)bp * DD;
    float a0 = 0.0f, a1 = 0.0f;
    for (int i = lane; i < DD; i += 64) {
        float h = bf2f(hr[i]);
        a0 = fmaf(h, cls_w2[i], a0);
        a1 = fmaf(h, cls_w2[DD + i], a1);
    }
    const __hip_bfloat16* pr = ph + (size_t)bp * 1024;
    float c0 = 0.0f, c1 = 0.0f, c2 = 0.0f, c3 = 0.0f;
    for (int i = lane; i < 1024; i += 64) {
        float h = bf2f(pr[i]);
        c0 = fmaf(h, p_w2[i], c0);
        c1 = fmaf(h, p_w2[1024 + i], c1);
        c2 = fmaf(h, p_w2[2048 + i], c2);
        c3 = fmaf(h, p_w2[3072 + i], c3);
    }
#pragma unroll
    for (int off = 32; off > 0; off >>= 1) {
        a0 += __shfl_down(a0, off);
        a1 += __shfl_down(a1, off);
        c0 += __shfl_down(c0, off);
        c1 += __shfl_down(c1, off);
        c2 += __shfl_down(c2, off);
        c3 += __shfl_down(c3, off);
    }
    a0 = __shfl(a0, 0); a1 = __shfl(a1, 0);
    c0 = __shfl(c0, 0); c1 = __shfl(c1, 0);
    c2 = __shfl(c2, 0); c3 = __shfl(c3, 0);
    const float k0 = c0 + p_b2[0];
    const float k1 = c1 + p_b2[1];
    const float scv = b_scale[0], biv = b_bias[0];
    const float k2 = (c2 + p_b2[2]) * scv + biv;
    const float k3 = (c3 + p_b2[3]) * scv + biv;
    float* orow = outp + (size_t)bp * 78;
    if (lane == 0) {
        orow[0] = a0 + cls_b2[0];
        orow[1] = a1 + cls_b2[1];
        orow[2] = k0; orow[3] = k1; orow[4] = k2; orow[5] = k3;
    }
    for (int o = lane; o < 72; o += 64) {
        float ys = (float)o / 71.0f;
        float tv = k0 + ys * (k1 + ys * (k2 + ys * k3));
        orow[6 + o] = 1.0f / (1.0f + expf(-tv));
    }
}

extern "C" void kernel_launch(void* const* d_in, const int* in_sizes, int n_in,
                              void* d_out, int out_size, void* d_ws, size_t ws_size,
                              hipStream_t stream)
{
    const float* feat0  = (const float*)d_in[0];
    const float* feat1  = (const float*)d_in[1];
    const float* feat2  = (const float*)d_in[2];
    const float* priors = (const float*)d_in[3];
    const float* ca_w   = (const float*)d_in[4];
    const float* ca_b   = (const float*)d_in[5];
    const float* off_w  = (const float*)d_in[6];
    const float* off_b  = (const float*)d_in[7];
    const float* dp_w   = (const float*)d_in[8];
    const float* dp_b   = (const float*)d_in[9];
    const float* z_emb  = (const float*)d_in[10];
    const float* gf_w   = (const float*)d_in[11];
    const float* gf_b   = (const float*)d_in[12];
    const float* wq     = (const float*)d_in[13];
    const float* bq     = (const float*)d_in[14];
    const float* wk     = (const float*)d_in[15];
    const float* bk     = (const float*)d_in[16];
    const float* wv     = (const float*)d_in[17];
    const float* bv     = (const float*)d_in[18];
    const float* wo     = (const float*)d_in[19];
    const float* bo     = (const float*)d_in[20];
    const float* cf_w1  = (const float*)d_in[21];
    const float* cf_b1  = (const float*)d_in[22];
    const float* cf_w2  = (const float*)d_in[23];
    const float* cf_b2  = (const float*)d_in[24];
    const float* cls_w1 = (const float*)d_in[25];
    const float* cls_b1 = (const float*)d_in[26];
    const float* cls_w2 = (const float*)d_in[27];
    const float* cls_b2 = (const float*)d_in[28];
    const float* reg_w1 = (const float*)d_in[29];
    const float* reg_b1 = (const float*)d_in[30];
    const float* p_w1   = (const float*)d_in[31];
    const float* p_b1   = (const float*)d_in[32];
    const float* p_w2   = (const float*)d_in[33];
    const float* p_b2   = (const float*)d_in[34];
    const float* b_scale = (const float*)d_in[35];
    const float* b_bias  = (const float*)d_in[36];
    float* out = (float*)d_out;

    char* wsb = (char*)d_ws;
    // persistent bf16 activations
    __hip_bfloat16* feature = (__hip_bfloat16*)(wsb + 0);          // [6144][512]
    __hip_bfloat16* qkvb    = (__hip_bfloat16*)(wsb + 6291456);    // [6144][1536]
    __hip_bfloat16* tb      = (__hip_bfloat16*)(wsb + 25165824);   // [6144][512]
    __hip_bfloat16* rb      = (__hip_bfloat16*)(wsb + 31457280);
    __hip_bfloat16* hb      = (__hip_bfloat16*)(wsb + 37748736);   // [6144][1024]
    __hip_bfloat16* f2      = (__hip_bfloat16*)(wsb + 50331648);
    __hip_bfloat16* clsh    = (__hip_bfloat16*)(wsb + 56623104);
    __hip_bfloat16* regb    = (__hip_bfloat16*)(wsb + 62914560);
    __hip_bfloat16* phb     = (__hip_bfloat16*)(wsb + 69206016);   // [6144][1024]
    // early-phase f32 buffers (dead before the overlapping late users are written)
    float* of1 = (float*)(wsb + 6291456);
    float* of2 = (float*)(wsb + 8595456);
    float* fe1 = (float*)(wsb + 9171456);
    float* fe2 = (float*)(wsb + 11475456);
    __hip_bfloat16* fsb = (__hip_bfloat16*)(wsb + 25165824);       // [6144][2688]
    float* fe0 = (float*)(wsb + 58195968);
    float* of0 = (float*)(wsb + 67411968);
    // bf16 weights
    __hip_bfloat16* wqkv_bf = (__hip_bfloat16*)(wsb + 81788928);   // [1536][512]
    __hip_bfloat16* wo_bf   = (__hip_bfloat16*)(wsb + 83361792);
    __hip_bfloat16* cf1_bf  = (__hip_bfloat16*)(wsb + 83886080);
    __hip_bfloat16* cf2_bf  = (__hip_bfloat16*)(wsb + 84934656);
    __hip_bfloat16* cls1_bf = (__hip_bfloat16*)(wsb + 85983232);
    __hip_bfloat16* reg1_bf = (__hip_bfloat16*)(wsb + 86507520);
    __hip_bfloat16* p1_bf   = (__hip_bfloat16*)(wsb + 87031808);
    __hip_bfloat16* gf_bf   = (__hip_bfloat16*)(wsb + 88080384);   // [512][672]
    float* bqkv             = (float*)(wsb + 88768512);            // [1536]

    k_wcast<<<(3491328 + 255) / 256, 256, 0, stream>>>(
        wq, wk, wv, wo, cf_w1, cf_w2, cls_w1, reg_w1, p_w1, gf_w, bq, bk, bv,
        wqkv_bf, wo_bf, cf1_bf, cf2_bf, cls1_bf, reg1_bf, p1_bf, gf_bf, bqkv);

    k_adjust<<<(BB * H0 * W0 * CADJ + 255) / 256, 256, 0, stream>>>(feat0, ca_w, ca_b, fe0, H0, W0);
    k_adjust<<<(BB * H1 * W1 * CADJ + 255) / 256, 256, 0, stream>>>(feat1, ca_w, ca_b, fe1, H1, W1);
    k_adjust<<<(BB * H2 * W2 * CADJ + 255) / 256, 256, 0, stream>>>(feat2, ca_w, ca_b, fe2, H2, W2);
    k_off<<<(BB * H0 * W0 * CADJ + 255) / 256, 256, 0, stream>>>(fe0, off_w, off_b, of0);
    k_resize<<<(BB * H1 * W1 * CADJ + 255) / 256, 256, 0, stream>>>(of0, of1, H1, W1);
    k_resize<<<(BB * H2 * W2 * CADJ + 255) / 256, 256, 0, stream>>>(of0, of2, H2, W2);
    k_sample<<<BB * PP, 256, 0, stream>>>(priors, fe0, fe1, fe2, of0, of1, of2,
                                          z_emb, dp_w, dp_b, fsb);

    const int M = BB * PP;
    // grouped gather-fc: 4 group-GEMMs via grid.z
    k_bgemm<<<dim3(2, M / 64, 4), 256, 0, stream>>>(
        fsb, 2688, 672, gf_bf, 672, 128 * 672, gf_b, 128,
        nullptr, 0, feature, DD, 128, 672, 0);
    // QKV fused
    k_bgemm<<<dim3(24, M / 64, 1), 256, 0, stream>>>(
        feature, DD, 0, wqkv_bf, DD, 0, bqkv, 0,
        nullptr, 0, qkvb, 1536, 0, DD, 0);
    k_fattn<<<dim3(12, 32), 256, 0, stream>>>(qkvb, tb);
    k_bgemm<<<dim3(8, M / 64, 1), 256, 0, stream>>>(
        tb, DD, 0, wo_bf, DD, 0, bo, 0, nullptr, 0, rb, DD, 0, DD, 0);
    k_bgemm<<<dim3(16, M / 64, 1), 256, 0, stream>>>(
        rb, DD, 0, cf1_bf, DD, 0, cf_b1, 0, nullptr, 0, hb, 1024, 0, DD, 1);
    k_bgemm<<<dim3(8, M / 64, 1), 256, 0, stream>>>(
        hb, 1024, 0, cf2_bf, 1024, 0, cf_b2, 0, feature, DD, f2, DD, 0, 1024, 0);
    k_bgemm<<<dim3(8, M / 64, 1), 256, 0, stream>>>(
        f2, DD, 0, cls1_bf, DD, 0, cls_b1, 0, nullptr, 0, clsh, DD, 0, DD, 1);
    k_bgemm<<<dim3(8, M / 64, 1), 256, 0, stream>>>(
        f2, DD, 0, reg1_bf, DD, 0, reg_b1, 0, nullptr, 0, regb, DD, 0, DD, 1);
    k_bgemm<<<dim3(16, M / 64, 1), 256, 0, stream>>>(
        regb, DD, 0, p1_bf, DD, 0, p_b1, 0, nullptr, 0, phb, 1024, 0, DD, 1);

    k_head<<<M, 64, 0, stream>>>(clsh, phb, cls_w2, cls_b2, p_w2, p_b2, b_scale, b_bias, out);
}

// Round 5
// 514.457 us; speedup vs baseline: 5.8069x; 1.4056x over previous
//
#include <hip/hip_runtime.h>
#include <hip/hip_bf16.h>
#include <math.h>

#define BB 8
#define PP 768
#define NPRI 76
#define SS 36
#define CIN 64
#define CADJ 72
#define DD 512

#define H0 40
#define W0 100
#define H1 20
#define W1 50
#define H2 10
#define W2 25

typedef __attribute__((ext_vector_type(8))) short bf16x8;
typedef __attribute__((ext_vector_type(4))) float f32x4;
#define MFMA_BF16 __builtin_amdgcn_mfma_f32_16x16x32_bf16

__device__ __forceinline__ __hip_bfloat16 to_bf16(float v) { return __float2bfloat16(v); }
__device__ __forceinline__ float bf2f(__hip_bfloat16 v) { return __bfloat162float(v); }

// ---- bilinear sample, zeros outside ----
__device__ __forceinline__ float bsample(const float* __restrict__ img, int H, int W,
                                         int C, int c, float x, float y)
{
    float x0f = floorf(x), y0f = floorf(y);
    int x0 = (int)x0f, y0 = (int)y0f;
    float wx1 = x - x0f, wy1 = y - y0f;
    float wx0 = 1.0f - wx1, wy0 = 1.0f - wy1;
    int xc0 = min(max(x0, 0), W - 1);
    int xc1 = min(max(x0 + 1, 0), W - 1);
    int yc0 = min(max(y0, 0), H - 1);
    int yc1 = min(max(y0 + 1, 0), H - 1);
    bool vx0 = (x0 >= 0) && (x0 < W);
    bool vx1 = (x0 + 1 >= 0) && (x0 + 1 < W);
    bool vy0 = (y0 >= 0) && (y0 < H);
    bool vy1 = (y0 + 1 >= 0) && (y0 + 1 < H);
    float w00 = (vx0 && vy0) ? wx0 * wy0 : 0.0f;
    float w01 = (vx1 && vy0) ? wx1 * wy0 : 0.0f;
    float w10 = (vx0 && vy1) ? wx0 * wy1 : 0.0f;
    float w11 = (vx1 && vy1) ? wx1 * wy1 : 0.0f;
    return w00 * img[((size_t)yc0 * W + xc0) * C + c]
         + w01 * img[((size_t)yc0 * W + xc1) * C + c]
         + w10 * img[((size_t)yc1 * W + xc0) * C + c]
         + w11 * img[((size_t)yc1 * W + xc1) * C + c];
}

// ---- weight cast f32 -> bf16 (+ bias concats) ----
__global__ __launch_bounds__(256) void k_wcast(
    const float* __restrict__ wq, const float* __restrict__ wk, const float* __restrict__ wv,
    const float* __restrict__ wo, const float* __restrict__ cf_w1, const float* __restrict__ cf_w2,
    const float* __restrict__ cls_w1, const float* __restrict__ reg_w1, const float* __restrict__ p_w1,
    const float* __restrict__ bq, const float* __restrict__ bk, const float* __restrict__ bv,
    const float* __restrict__ cls_b1, const float* __restrict__ reg_b1,
    __hip_bfloat16* __restrict__ wqkv, __hip_bfloat16* __restrict__ wo_bf,
    __hip_bfloat16* __restrict__ cf1_bf, __hip_bfloat16* __restrict__ cf2_bf,
    __hip_bfloat16* __restrict__ clsreg_bf, __hip_bfloat16* __restrict__ p1_bf,
    float* __restrict__ bqkv, float* __restrict__ bclsreg)
{
    long i = (long)blockIdx.x * 256 + threadIdx.x;
    if (i < 262144) { wqkv[i] = to_bf16(wq[i]); return; }
    i -= 262144;
    if (i < 262144) { wqkv[262144 + i] = to_bf16(wk[i]); return; }
    i -= 262144;
    if (i < 262144) { wqkv[524288 + i] = to_bf16(wv[i]); return; }
    i -= 262144;
    if (i < 262144) { wo_bf[i] = to_bf16(wo[i]); return; }
    i -= 262144;
    if (i < 524288) { cf1_bf[i] = to_bf16(cf_w1[i]); return; }
    i -= 524288;
    if (i < 524288) { cf2_bf[i] = to_bf16(cf_w2[i]); return; }
    i -= 524288;
    if (i < 262144) { clsreg_bf[i] = to_bf16(cls_w1[i]); return; }
    i -= 262144;
    if (i < 262144) { clsreg_bf[262144 + i] = to_bf16(reg_w1[i]); return; }
    i -= 262144;
    if (i < 524288) { p1_bf[i] = to_bf16(p_w1[i]); return; }
    i -= 524288;
    if (i < 512) { bqkv[i] = bq[i]; return; }
    if (i < 1024) { bqkv[i] = bk[i - 512]; return; }
    if (i < 1536) { bqkv[i] = bv[i - 1024]; return; }
    i -= 1536;
    if (i < 512) { bclsreg[i] = cls_b1[i]; return; }
    if (i < 1024) { bclsreg[i] = reg_b1[i - 512]; return; }
}

// ---- fuse dp into gf: Wout[o][i*72+m] = sum_k gf_w[o][i*72+k] * dp_w[k][m]; pad to 672 ----
__global__ __launch_bounds__(256) void k_wfuse(
    const float* __restrict__ gf_w, const float* __restrict__ dp_w,
    __hip_bfloat16* __restrict__ Wout)
{
    const int o = blockIdx.x;
    const int tid = threadIdx.x;
    __shared__ float dpS[CADJ][CADJ + 1];
    __shared__ float gfr[648];
    for (int i = tid; i < CADJ * CADJ; i += 256) dpS[i / CADJ][i % CADJ] = dp_w[i];
    for (int i = tid; i < 648; i += 256) gfr[i] = gf_w[(size_t)o * 648 + i];
    __syncthreads();
    for (int t = tid; t < 672; t += 256) {
        float acc = 0.0f;
        if (t < 648) {
            const int i = t / 72, m = t % 72;
            const float* gr = gfr + i * 72;
#pragma unroll 8
            for (int k = 0; k < 72; ++k) acc = fmaf(gr[k], dpS[k][m], acc);
        }
        Wout[(size_t)o * 672 + t] = to_bf16(acc);
    }
}

// ---- fused bias: b2[o] = gf_b[o] + sum_{i,k} gf_w[o][i*72+k] * dp_b[k] ----
__global__ __launch_bounds__(256) void k_wfuseb(
    const float* __restrict__ gf_w, const float* __restrict__ dp_b,
    const float* __restrict__ gf_b, float* __restrict__ b2)
{
    const int o = blockIdx.x * 256 + threadIdx.x;
    if (o >= DD) return;
    const float* gr = gf_w + (size_t)o * 648;
    float acc = gf_b[o];
    for (int j = 0; j < 648; ++j) acc = fmaf(gr[j], dp_b[j % 72], acc);
    b2[o] = acc;
}

// ---- channel adjust: NCHW (B,64,H,W) -> NHWC (B,H,W,72) ----
__global__ __launch_bounds__(256) void k_adjust(const float* __restrict__ f,
    const float* __restrict__ caw, const float* __restrict__ cab,
    float* __restrict__ outp, int H, int W)
{
    int idx = blockIdx.x * 256 + threadIdx.x;
    int total = BB * H * W * CADJ;
    if (idx >= total) return;
    int o = idx % CADJ;
    int pix = idx / CADJ;
    int w = pix % W;
    int h = (pix / W) % H;
    int b = pix / (W * H);
    const float* fb = f + (size_t)b * CIN * H * W + (size_t)h * W + w;
    const float* wr = caw + o * CIN;
    int HW = H * W;
    float acc = cab[o];
#pragma unroll 8
    for (int c = 0; c < CIN; ++c) acc = fmaf(fb[(size_t)c * HW], wr[c], acc);
    outp[idx] = acc;
}

// ---- offset head ----
__global__ __launch_bounds__(256) void k_off(const float* __restrict__ fe,
    const float* __restrict__ ow, const float* __restrict__ ob, float* __restrict__ outp)
{
    int idx = blockIdx.x * 256 + threadIdx.x;
    const int total = BB * H0 * W0 * CADJ;
    if (idx >= total) return;
    int o = idx % CADJ;
    int pix = idx / CADJ;
    const float* fr = fe + (size_t)pix * CADJ;
    const float* wr = ow + o * CADJ;
    float acc = ob[o];
#pragma unroll 8
    for (int c = 0; c < CADJ; ++c) acc = fmaf(fr[c], wr[c], acc);
    outp[idx] = acc;
}

// ---- align-corners resize ----
__global__ __launch_bounds__(256) void k_resize(const float* __restrict__ src,
    float* __restrict__ dst, int Ht, int Wt)
{
    int idx = blockIdx.x * 256 + threadIdx.x;
    int total = BB * Ht * Wt * CADJ;
    if (idx >= total) return;
    int c = idx % CADJ;
    int j = (idx / CADJ) % Wt;
    int i = (idx / (CADJ * Wt)) % Ht;
    int b = idx / (CADJ * Wt * Ht);
    float sy = fminf((float)i * ((float)(H0 - 1) / (float)(Ht - 1)), (float)(H0 - 1));
    float sx = fminf((float)j * ((float)(W0 - 1) / (float)(Wt - 1)), (float)(W0 - 1));
    dst[idx] = bsample(src + (size_t)b * H0 * W0 * CADJ, H0, W0, CADJ, c, sx, sy);
}

// ---- sampling + z-fuse only (dp folded into gf weights); smp bf16 [6144][4*672] ----
__global__ __launch_bounds__(256) void k_sample(
    const float* __restrict__ priors,
    const float* __restrict__ feats0, const float* __restrict__ feats1, const float* __restrict__ feats2,
    const float* __restrict__ offs0,  const float* __restrict__ offs1,  const float* __restrict__ offs2,
    const float* __restrict__ z_emb,
    __hip_bfloat16* __restrict__ fsout)
{
    const int bp = blockIdx.x;
    const int b = bp / PP;
    const int tid = threadIdx.x;

    __shared__ float zw[3][SS];
    __shared__ float wgt[3][SS][4];
    __shared__ int cx0s[3][SS];
    __shared__ int cy0s[3][SS];

    const int Hs[3] = {H0, H1, H2};
    const int Wsz[3] = {W0, W1, W2};
    const float* Fb[3] = { feats0 + (size_t)b * H0 * W0 * CADJ,
                           feats1 + (size_t)b * H1 * W1 * CADJ,
                           feats2 + (size_t)b * H2 * W2 * CADJ };
    const float* Ob[3] = { offs0 + (size_t)b * H0 * W0 * CADJ,
                           offs1 + (size_t)b * H1 * W1 * CADJ,
                           offs2 + (size_t)b * H2 * W2 * CADJ };

    if (tid < 3 * SS) {
        const int s = tid % SS;
        const int l = tid / SS;
        const float t = (float)(35 - s) / 35.0f;
        const int m = (int)floorf(t * 71.0f);
        const float pfx = priors[(size_t)bp * NPRI + 4 + m];
        const float gxv = fminf(fmaxf(pfx / 71.0f, 0.0f), 1.0f) * 2.0f - 1.0f;
        const float gyv = (1.0f - (float)m / 71.0f) * 2.0f - 1.0f;
        const float z = z_emb[s];
        const float e0 = expf(-0.5f * z * z);
        const float e1 = expf(-0.5f * (z - 1.0f) * (z - 1.0f));
        const float e2 = expf(-0.5f * (z - 2.0f) * (z - 2.0f));
        const float inv = 1.0f / (e0 + e1 + e2);
        const float ev[3] = {e0, e1, e2};
        zw[l][s] = ev[l] * inv;

        const int Hl = Hs[l], Wl = Wsz[l];
        const float px = (gxv + 1.0f) * 0.5f * (float)(Wl - 1);
        const float py = (gyv + 1.0f) * 0.5f * (float)(Hl - 1);
        const float dy = bsample(Ob[l], Hl, Wl, CADJ, 2 * s,     px, py);
        const float dx = bsample(Ob[l], Hl, Wl, CADJ, 2 * s + 1, px, py);
        const float sx = px + dx, sy = py + dy;
        const float x0f = floorf(sx), y0f = floorf(sy);
        const int x0 = (int)x0f, y0 = (int)y0f;
        const float wx1 = sx - x0f, wy1 = sy - y0f;
        const float wx0 = 1.0f - wx1, wy0 = 1.0f - wy1;
        const bool vx0 = (x0 >= 0) && (x0 < Wl);
        const bool vx1 = (x0 + 1 >= 0) && (x0 + 1 < Wl);
        const bool vy0 = (y0 >= 0) && (y0 < Hl);
        const bool vy1 = (y0 + 1 >= 0) && (y0 + 1 < Hl);
        wgt[l][s][0] = (vx0 && vy0) ? wx0 * wy0 : 0.0f;
        wgt[l][s][1] = (vx1 && vy0) ? wx1 * wy0 : 0.0f;
        wgt[l][s][2] = (vx0 && vy1) ? wx0 * wy1 : 0.0f;
        wgt[l][s][3] = (vx1 && vy1) ? wx1 * wy1 : 0.0f;
        cx0s[l][s] = x0; cy0s[l][s] = y0;
    }
    __syncthreads();

    __hip_bfloat16* orow = fsout + (size_t)bp * 2688;
    for (int idx = tid; idx < SS * CADJ; idx += 256) {
        const int s = idx / CADJ, k = idx % CADJ;
        float acc = 0.0f;
#pragma unroll
        for (int l = 0; l < 3; ++l) {
            const int Hl = Hs[l], Wl = Wsz[l];
            const int x0 = cx0s[l][s], y0 = cy0s[l][s];
            const int xc0 = min(max(x0, 0), Wl - 1);
            const int xc1 = min(max(x0 + 1, 0), Wl - 1);
            const int yc0 = min(max(y0, 0), Hl - 1);
            const int yc1 = min(max(y0 + 1, 0), Hl - 1);
            const float* F = Fb[l];
            float v = wgt[l][s][0] * F[((size_t)yc0 * Wl + xc0) * CADJ + k]
                    + wgt[l][s][1] * F[((size_t)yc0 * Wl + xc1) * CADJ + k]
                    + wgt[l][s][2] * F[((size_t)yc1 * Wl + xc0) * CADJ + k]
                    + wgt[l][s][3] * F[((size_t)yc1 * Wl + xc1) * CADJ + k];
            acc = fmaf(zw[l][s], v, acc);
        }
        orow[(s / 9) * 672 + (s % 9) * 72 + k] = to_bf16(acc);
    }
    if (tid < 96) {  // zero the 24-col tail of each group
        const int g = tid / 24, t = tid % 24;
        orow[g * 672 + 648 + t] = to_bf16(0.0f);
    }
}

// ---- bf16 MFMA GEMM, 128x128 tile, LDS-staged: C = act(A @ W^T + bias (+Res)) ----
// grid = (N/128, M/128, nz); 256 threads = 4 waves in 2x2, each wave 64x64 out
__global__ __launch_bounds__(256) void k_bgemm(
    const __hip_bfloat16* __restrict__ A, int lda, long sAz,
    const __hip_bfloat16* __restrict__ W, int ldw, long sWz,
    const float* __restrict__ bias, int sBz,
    const __hip_bfloat16* __restrict__ Res, int ldres,
    __hip_bfloat16* __restrict__ C, int ldc, int sCz,
    int K, int relu)
{
    __shared__ __hip_bfloat16 As[128][40];   // 32-col tile padded to 40 (80B rows)
    __shared__ __hip_bfloat16 Bs[128][40];
    const int tid = threadIdx.x;
    const int lane = tid & 63, w = tid >> 6;
    const int wr = w >> 1, wc = w & 1;
    const int row16 = lane & 15, kg = lane >> 4;
    const int z = blockIdx.z;
    const int m0 = blockIdx.y * 128, n0 = blockIdx.x * 128;
    const __hip_bfloat16* Ab = A + (size_t)z * sAz;
    const __hip_bfloat16* Wb = W + (size_t)z * sWz;
    const int r0 = tid >> 2, c0 = (tid & 3) * 8;   // staging: 4 chunks of 8 bf16 per row

    f32x4 acc[4][4];
#pragma unroll
    for (int i = 0; i < 4; ++i)
#pragma unroll
        for (int j = 0; j < 4; ++j) acc[i][j] = (f32x4){0.f, 0.f, 0.f, 0.f};

    for (int k0 = 0; k0 < K; k0 += 32) {
        __syncthreads();
        *(bf16x8*)&As[r0][c0]      = *(const bf16x8*)(Ab + (size_t)(m0 + r0) * lda + k0 + c0);
        *(bf16x8*)&As[r0 + 64][c0] = *(const bf16x8*)(Ab + (size_t)(m0 + r0 + 64) * lda + k0 + c0);
        *(bf16x8*)&Bs[r0][c0]      = *(const bf16x8*)(Wb + (size_t)(n0 + r0) * ldw + k0 + c0);
        *(bf16x8*)&Bs[r0 + 64][c0] = *(const bf16x8*)(Wb + (size_t)(n0 + r0 + 64) * ldw + k0 + c0);
        __syncthreads();
        bf16x8 af[4], bfr[4];
#pragma unroll
        for (int i = 0; i < 4; ++i) af[i]  = *(const bf16x8*)&As[wr * 64 + i * 16 + row16][kg * 8];
#pragma unroll
        for (int j = 0; j < 4; ++j) bfr[j] = *(const bf16x8*)&Bs[wc * 64 + j * 16 + row16][kg * 8];
#pragma unroll
        for (int i = 0; i < 4; ++i)
#pragma unroll
            for (int j = 0; j < 4; ++j)
                acc[i][j] = MFMA_BF16(af[i], bfr[j], acc[i][j], 0, 0, 0);
    }

    const float* bz = bias + (size_t)z * sBz;
    __hip_bfloat16* Cz = C + (size_t)z * sCz;
#pragma unroll
    for (int i = 0; i < 4; ++i) {
#pragma unroll
        for (int r = 0; r < 4; ++r) {
            const int row = m0 + wr * 64 + i * 16 + kg * 4 + r;
#pragma unroll
            for (int j = 0; j < 4; ++j) {
                const int col = n0 + wc * 64 + j * 16 + row16;
                float v = acc[i][j][r] + bz[col];
                if (Res) v += bf2f(Res[(size_t)row * ldres + col]);
                if (relu) v = fmaxf(v, 0.0f);
                Cz[(size_t)row * ldc + col] = to_bf16(v);
            }
        }
    }
}

// ---- flash attention, bf16 MFMA. qkv [6144][1536]; grid (12 qtiles, 32 bg) ----
__global__ __launch_bounds__(256) void k_fattn(
    const __hip_bfloat16* __restrict__ qkv, __hip_bfloat16* __restrict__ Out)
{
    const int qt = blockIdx.x, bg = blockIdx.y;
    const int b = bg >> 2, g = bg & 3;
    const int tid = threadIdx.x, lane = tid & 63, w = tid >> 6;
    const int row16 = lane & 15, kg = lane >> 4;
    const int q0 = qt * 64;

    __shared__ __hip_bfloat16 Klds[32][136];
    __shared__ __hip_bfloat16 Vtlds[128][40];
    __shared__ __hip_bfloat16 Plds[4][16][40];

    const size_t rowQ = (size_t)(b * PP + q0 + w * 16 + row16) * 1536 + g * 128;
    bf16x8 aq[4];
#pragma unroll
    for (int t = 0; t < 4; ++t)
        aq[t] = *(const bf16x8*)(qkv + rowQ + t * 32 + kg * 8);

    f32x4 oacc[8];
#pragma unroll
    for (int dt = 0; dt < 8; ++dt) oacc[dt] = (f32x4){0.f, 0.f, 0.f, 0.f};
    float mrow[4] = {-INFINITY, -INFINITY, -INFINITY, -INFINITY};
    float lrow[4] = {0.f, 0.f, 0.f, 0.f};

    const __hip_bfloat16* Kbase = qkv + (size_t)(b * PP) * 1536 + 512 + g * 128;
    const __hip_bfloat16* Vbase = qkv + (size_t)(b * PP) * 1536 + 1024 + g * 128;
    const float sc = 0.08838834764831845f;

    for (int kt = 0; kt < 24; ++kt) {
        __syncthreads();
        if (tid >= 128) {
            const int t2 = tid - 128;
            const int r = t2 >> 2;
            const int cp = (t2 & 3) * 32;
            const __hip_bfloat16* src = Kbase + (size_t)(kt * 32 + r) * 1536 + cp;
            *(bf16x8*)&Klds[r][cp]      = *(const bf16x8*)(src);
            *(bf16x8*)&Klds[r][cp + 8]  = *(const bf16x8*)(src + 8);
            *(bf16x8*)&Klds[r][cp + 16] = *(const bf16x8*)(src + 16);
            *(bf16x8*)&Klds[r][cp + 24] = *(const bf16x8*)(src + 24);
        } else {
            const int kk = (tid >> 3) * 2;
            const int cp = (tid & 7) * 16;
            const __hip_bfloat16* v0p = Vbase + (size_t)(kt * 32 + kk) * 1536 + cp;
            bf16x8 x0a = *(const bf16x8*)(v0p);
            bf16x8 x0b = *(const bf16x8*)(v0p + 8);
            bf16x8 x1a = *(const bf16x8*)(v0p + 1536);
            bf16x8 x1b = *(const bf16x8*)(v0p + 1536 + 8);
#pragma unroll
            for (int i = 0; i < 8; ++i) {
                unsigned lo = (unsigned short)x0a[i], hi = (unsigned short)x1a[i];
                *(unsigned*)&Vtlds[cp + i][kk] = lo | (hi << 16);
                unsigned lo2 = (unsigned short)x0b[i], hi2 = (unsigned short)x1b[i];
                *(unsigned*)&Vtlds[cp + 8 + i][kk] = lo2 | (hi2 << 16);
            }
        }
        __syncthreads();

        f32x4 s0 = {0.f, 0.f, 0.f, 0.f}, s1 = s0;
#pragma unroll
        for (int t = 0; t < 4; ++t) {
            bf16x8 bk0 = *(const bf16x8*)&Klds[row16][t * 32 + kg * 8];
            bf16x8 bk1 = *(const bf16x8*)&Klds[16 + row16][t * 32 + kg * 8];
            s0 = MFMA_BF16(aq[t], bk0, s0, 0, 0, 0);
            s1 = MFMA_BF16(aq[t], bk1, s1, 0, 0, 0);
        }

#pragma unroll
        for (int r = 0; r < 4; ++r) {
            float v0 = s0[r] * sc, v1 = s1[r] * sc;
            float mx = fmaxf(v0, v1);
            mx = fmaxf(mx, __shfl_xor(mx, 1));
            mx = fmaxf(mx, __shfl_xor(mx, 2));
            mx = fmaxf(mx, __shfl_xor(mx, 4));
            mx = fmaxf(mx, __shfl_xor(mx, 8));
            const float mnew = fmaxf(mrow[r], mx);
            const float scale_old = __expf(mrow[r] - mnew);
            const float p0 = __expf(v0 - mnew);
            const float p1 = __expf(v1 - mnew);
            float rs = p0 + p1;
            rs += __shfl_xor(rs, 1);
            rs += __shfl_xor(rs, 2);
            rs += __shfl_xor(rs, 4);
            rs += __shfl_xor(rs, 8);
            lrow[r] = lrow[r] * scale_old + rs;
            mrow[r] = mnew;
#pragma unroll
            for (int dt = 0; dt < 8; ++dt) oacc[dt][r] *= scale_old;
            Plds[w][kg * 4 + r][row16]      = to_bf16(p0);
            Plds[w][kg * 4 + r][16 + row16] = to_bf16(p1);
        }

        bf16x8 ap = *(const bf16x8*)&Plds[w][row16][kg * 8];
#pragma unroll
        for (int dt = 0; dt < 8; ++dt) {
            bf16x8 bv = *(const bf16x8*)&Vtlds[dt * 16 + row16][kg * 8];
            oacc[dt] = MFMA_BF16(ap, bv, oacc[dt], 0, 0, 0);
        }
    }

    const size_t obase = (size_t)(b * PP + q0 + w * 16 + kg * 4) * DD + g * 128;
#pragma unroll
    for (int r = 0; r < 4; ++r) {
        const float inv = 1.0f / lrow[r];
#pragma unroll
        for (int dt = 0; dt < 8; ++dt)
            Out[obase + (size_t)r * DD + dt * 16 + row16] = to_bf16(oacc[dt][r] * inv);
    }
}

// ---- final heads (bf16 inputs; clsh rows have ld=1024: [cls|reg] fused buffer) ----
__global__ __launch_bounds__(64) void k_head(
    const __hip_bfloat16* __restrict__ clsreg, const __hip_bfloat16* __restrict__ ph,
    const float* __restrict__ cls_w2, const float* __restrict__ cls_b2,
    const float* __restrict__ p_w2, const float* __restrict__ p_b2,
    const float* __restrict__ b_scale, const float* __restrict__ b_bias,
    float* __restrict__ outp)
{
    const int bp = blockIdx.x;
    const int lane = threadIdx.x;
    const __hip_bfloat16* hr = clsreg + (size_t)bp * 1024;
    float a0 = 0.0f, a1 = 0.0f;
    for (int i = lane; i < DD; i += 64) {
        float h = bf2f(hr[i]);
        a0 = fmaf(h, cls_w2[i], a0);
        a1 = fmaf(h, cls_w2[DD + i], a1);
    }
    const __hip_bfloat16* pr = ph + (size_t)bp * 1024;
    float c0 = 0.0f, c1 = 0.0f, c2 = 0.0f, c3 = 0.0f;
    for (int i = lane; i < 1024; i += 64) {
        float h = bf2f(pr[i]);
        c0 = fmaf(h, p_w2[i], c0);
        c1 = fmaf(h, p_w2[1024 + i], c1);
        c2 = fmaf(h, p_w2[2048 + i], c2);
        c3 = fmaf(h, p_w2[3072 + i], c3);
    }
#pragma unroll
    for (int off = 32; off > 0; off >>= 1) {
        a0 += __shfl_down(a0, off);
        a1 += __shfl_down(a1, off);
        c0 += __shfl_down(c0, off);
        c1 += __shfl_down(c1, off);
        c2 += __shfl_down(c2, off);
        c3 += __shfl_down(c3, off);
    }
    a0 = __shfl(a0, 0); a1 = __shfl(a1, 0);
    c0 = __shfl(c0, 0); c1 = __shfl(c1, 0);
    c2 = __shfl(c2, 0); c3 = __shfl(c3, 0);
    const float k0 = c0 + p_b2[0];
    const float k1 = c1 + p_b2[1];
    const float scv = b_scale[0], biv = b_bias[0];
    const float k2 = (c2 + p_b2[2]) * scv + biv;
    const float k3 = (c3 + p_b2[3]) * scv + biv;
    float* orow = outp + (size_t)bp * 78;
    if (lane == 0) {
        orow[0] = a0 + cls_b2[0];
        orow[1] = a1 + cls_b2[1];
        orow[2] = k0; orow[3] = k1; orow[4] = k2; orow[5] = k3;
    }
    for (int o = lane; o < 72; o += 64) {
        float ys = (float)o / 71.0f;
        float tv = k0 + ys * (k1 + ys * (k2 + ys * k3));
        orow[6 + o] = 1.0f / (1.0f + expf(-tv));
    }
}

extern "C" void kernel_launch(void* const* d_in, const int* in_sizes, int n_in,
                              void* d_out, int out_size, void* d_ws, size_t ws_size,
                              hipStream_t stream)
{
    const float* feat0  = (const float*)d_in[0];
    const float* feat1  = (const float*)d_in[1];
    const float* feat2  = (const float*)d_in[2];
    const float* priors = (const float*)d_in[3];
    const float* ca_w   = (const float*)d_in[4];
    const float* ca_b   = (const float*)d_in[5];
    const float* off_w  = (const float*)d_in[6];
    const float* off_b  = (const float*)d_in[7];
    const float* dp_w   = (const float*)d_in[8];
    const float* dp_b   = (const float*)d_in[9];
    const float* z_emb  = (const float*)d_in[10];
    const float* gf_w   = (const float*)d_in[11];
    const float* gf_b   = (const float*)d_in[12];
    const float* wq     = (const float*)d_in[13];
    const float* bq     = (const float*)d_in[14];
    const float* wk     = (const float*)d_in[15];
    const float* bk     = (const float*)d_in[16];
    const float* wv     = (const float*)d_in[17];
    const float* bv     = (const float*)d_in[18];
    const float* wo     = (const float*)d_in[19];
    const float* bo     = (const float*)d_in[20];
    const float* cf_w1  = (const float*)d_in[21];
    const float* cf_b1  = (const float*)d_in[22];
    const float* cf_w2  = (const float*)d_in[23];
    const float* cf_b2  = (const float*)d_in[24];
    const float* cls_w1 = (const float*)d_in[25];
    const float* cls_b1 = (const float*)d_in[26];
    const float* cls_w2 = (const float*)d_in[27];
    const float* cls_b2 = (const float*)d_in[28];
    const float* reg_w1 = (const float*)d_in[29];
    const float* reg_b1 = (const float*)d_in[30];
    const float* p_w1   = (const float*)d_in[31];
    const float* p_b1   = (const float*)d_in[32];
    const float* p_w2   = (const float*)d_in[33];
    const float* p_b2   = (const float*)d_in[34];
    const float* b_scale = (const float*)d_in[35];
    const float* b_bias  = (const float*)d_in[36];
    float* out = (float*)d_out;

    char* wsb = (char*)d_ws;
    // persistent bf16 activations
    __hip_bfloat16* feature = (__hip_bfloat16*)(wsb + 0);          // [6144][512]
    __hip_bfloat16* qkvb    = (__hip_bfloat16*)(wsb + 6291456);    // [6144][1536]
    __hip_bfloat16* tb      = (__hip_bfloat16*)(wsb + 25165824);   // [6144][512]
    __hip_bfloat16* rb      = (__hip_bfloat16*)(wsb + 31457280);
    __hip_bfloat16* hb      = (__hip_bfloat16*)(wsb + 37748736);   // [6144][1024]
    __hip_bfloat16* f2      = (__hip_bfloat16*)(wsb + 50331648);   // [6144][512]
    __hip_bfloat16* clsregb = (__hip_bfloat16*)(wsb + 56623104);   // [6144][1024]
    __hip_bfloat16* phb     = (__hip_bfloat16*)(wsb + 69206016);   // [6144][1024]
    // early-phase f32 buffers (dead before the overlapping late users are written)
    float* of1 = (float*)(wsb + 6291456);
    float* of2 = (float*)(wsb + 8595456);
    float* fe1 = (float*)(wsb + 9171456);
    float* fe2 = (float*)(wsb + 11475456);
    __hip_bfloat16* fsb = (__hip_bfloat16*)(wsb + 25165824);       // smp [6144][2688]
    float* fe0 = (float*)(wsb + 58195968);
    float* of0 = (float*)(wsb + 67411968);
    // bf16 weights
    __hip_bfloat16* wqkv_bf   = (__hip_bfloat16*)(wsb + 81788928); // [1536][512]
    __hip_bfloat16* wo_bf     = (__hip_bfloat16*)(wsb + 83361792);
    __hip_bfloat16* cf1_bf    = (__hip_bfloat16*)(wsb + 83886080);
    __hip_bfloat16* cf2_bf    = (__hip_bfloat16*)(wsb + 84934656);
    __hip_bfloat16* clsreg_bf = (__hip_bfloat16*)(wsb + 85983232); // [1024][512]
    __hip_bfloat16* p1_bf     = (__hip_bfloat16*)(wsb + 87031808);
    __hip_bfloat16* gfw2_bf   = (__hip_bfloat16*)(wsb + 88080384); // [512][672] dp-fused gf
    float* bqkv    = (float*)(wsb + 88768512);                     // [1536]
    float* bclsreg = (float*)(wsb + 88774656);                     // [1024]
    float* b2      = (float*)(wsb + 88778752);                     // [512]

    k_wcast<<<(3148288 + 255) / 256, 256, 0, stream>>>(
        wq, wk, wv, wo, cf_w1, cf_w2, cls_w1, reg_w1, p_w1, bq, bk, bv, cls_b1, reg_b1,
        wqkv_bf, wo_bf, cf1_bf, cf2_bf, clsreg_bf, p1_bf, bqkv, bclsreg);
    k_wfuse<<<512, 256, 0, stream>>>(gf_w, dp_w, gfw2_bf);
    k_wfuseb<<<2, 256, 0, stream>>>(gf_w, dp_b, gf_b, b2);

    k_adjust<<<(BB * H0 * W0 * CADJ + 255) / 256, 256, 0, stream>>>(feat0, ca_w, ca_b, fe0, H0, W0);
    k_adjust<<<(BB * H1 * W1 * CADJ + 255) / 256, 256, 0, stream>>>(feat1, ca_w, ca_b, fe1, H1, W1);
    k_adjust<<<(BB * H2 * W2 * CADJ + 255) / 256, 256, 0, stream>>>(feat2, ca_w, ca_b, fe2, H2, W2);
    k_off<<<(BB * H0 * W0 * CADJ + 255) / 256, 256, 0, stream>>>(fe0, off_w, off_b, of0);
    k_resize<<<(BB * H1 * W1 * CADJ + 255) / 256, 256, 0, stream>>>(of0, of1, H1, W1);
    k_resize<<<(BB * H2 * W2 * CADJ + 255) / 256, 256, 0, stream>>>(of0, of2, H2, W2);
    k_sample<<<BB * PP, 256, 0, stream>>>(priors, fe0, fe1, fe2, of0, of1, of2, z_emb, fsb);

    const int M = BB * PP;
    // grouped gather-fc (dp folded in): per group N=128, K=672
    k_bgemm<<<dim3(1, M / 128, 4), 256, 0, stream>>>(
        fsb, 2688, 672, gfw2_bf, 672, 128 * 672, b2, 128,
        nullptr, 0, feature, DD, 128, 672, 0);
    // QKV fused
    k_bgemm<<<dim3(12, M / 128, 1), 256, 0, stream>>>(
        feature, DD, 0, wqkv_bf, DD, 0, bqkv, 0,
        nullptr, 0, qkvb, 1536, 0, DD, 0);
    k_fattn<<<dim3(12, 32), 256, 0, stream>>>(qkvb, tb);
    k_bgemm<<<dim3(4, M / 128, 1), 256, 0, stream>>>(
        tb, DD, 0, wo_bf, DD, 0, bo, 0, nullptr, 0, rb, DD, 0, DD, 0);
    k_bgemm<<<dim3(8, M / 128, 1), 256, 0, stream>>>(
        rb, DD, 0, cf1_bf, DD, 0, cf_b1, 0, nullptr, 0, hb, 1024, 0, DD, 1);
    k_bgemm<<<dim3(4, M / 128, 1), 256, 0, stream>>>(
        hb, 1024, 0, cf2_bf, 1024, 0, cf_b2, 0, feature, DD, f2, DD, 0, 1024, 0);
    // cls+reg fused: N=1024 ([cls|reg]), relu
    k_bgemm<<<dim3(8, M / 128, 1), 256, 0, stream>>>(
        f2, DD, 0, clsreg_bf, DD, 0, bclsreg, 0, nullptr, 0, clsregb, 1024, 0, DD, 1);
    // p1 on reg half (cols 512..1023 of clsregb)
    k_bgemm<<<dim3(8, M / 128, 1), 256, 0, stream>>>(
        clsregb + 512, 1024, 0, p1_bf, DD, 0, p_b1, 0, nullptr, 0, phb, 1024, 0, DD, 1);

    k_head<<<M, 64, 0, stream>>>(clsregb, phb, cls_w2, cls_b2, p_w2, p_b2, b_scale, b_bias, out);
}

// Round 6
// 402.469 us; speedup vs baseline: 7.4227x; 1.2783x over previous
//
#include <hip/hip_runtime.h>
#include <hip/hip_bf16.h>
#include <math.h>

#define BB 8
#define PP 768
#define NPRI 76
#define SS 36
#define CIN 64
#define CADJ 72
#define DD 512

#define H0 40
#define W0 100
#define H1 20
#define W1 50
#define H2 10
#define W2 25

typedef __attribute__((ext_vector_type(8))) short bf16x8;
typedef __attribute__((ext_vector_type(4))) float f32x4;
#define MFMA_BF16 __builtin_amdgcn_mfma_f32_16x16x32_bf16

__device__ __forceinline__ __hip_bfloat16 to_bf16(float v) { return __float2bfloat16(v); }
__device__ __forceinline__ float bf2f(__hip_bfloat16 v) { return __bfloat162float(v); }

// ---- bilinear sample, zeros outside ----
__device__ __forceinline__ float bsample(const float* __restrict__ img, int H, int W,
                                         int C, int c, float x, float y)
{
    float x0f = floorf(x), y0f = floorf(y);
    int x0 = (int)x0f, y0 = (int)y0f;
    float wx1 = x - x0f, wy1 = y - y0f;
    float wx0 = 1.0f - wx1, wy0 = 1.0f - wy1;
    int xc0 = min(max(x0, 0), W - 1);
    int xc1 = min(max(x0 + 1, 0), W - 1);
    int yc0 = min(max(y0, 0), H - 1);
    int yc1 = min(max(y0 + 1, 0), H - 1);
    bool vx0 = (x0 >= 0) && (x0 < W);
    bool vx1 = (x0 + 1 >= 0) && (x0 + 1 < W);
    bool vy0 = (y0 >= 0) && (y0 < H);
    bool vy1 = (y0 + 1 >= 0) && (y0 + 1 < H);
    float w00 = (vx0 && vy0) ? wx0 * wy0 : 0.0f;
    float w01 = (vx1 && vy0) ? wx1 * wy0 : 0.0f;
    float w10 = (vx0 && vy1) ? wx0 * wy1 : 0.0f;
    float w11 = (vx1 && vy1) ? wx1 * wy1 : 0.0f;
    return w00 * img[((size_t)yc0 * W + xc0) * C + c]
         + w01 * img[((size_t)yc0 * W + xc1) * C + c]
         + w10 * img[((size_t)yc1 * W + xc0) * C + c]
         + w11 * img[((size_t)yc1 * W + xc1) * C + c];
}

// ---- weight cast f32 -> bf16 (+ bias concats) ----
__global__ __launch_bounds__(256) void k_wcast(
    const float* __restrict__ wq, const float* __restrict__ wk, const float* __restrict__ wv,
    const float* __restrict__ wo, const float* __restrict__ cf_w1, const float* __restrict__ cf_w2,
    const float* __restrict__ cls_w1, const float* __restrict__ reg_w1, const float* __restrict__ p_w1,
    const float* __restrict__ bq, const float* __restrict__ bk, const float* __restrict__ bv,
    const float* __restrict__ cls_b1, const float* __restrict__ reg_b1,
    __hip_bfloat16* __restrict__ wqkv, __hip_bfloat16* __restrict__ wo_bf,
    __hip_bfloat16* __restrict__ cf1_bf, __hip_bfloat16* __restrict__ cf2_bf,
    __hip_bfloat16* __restrict__ clsreg_bf, __hip_bfloat16* __restrict__ p1_bf,
    float* __restrict__ bqkv, float* __restrict__ bclsreg)
{
    long i = (long)blockIdx.x * 256 + threadIdx.x;
    if (i < 262144) { wqkv[i] = to_bf16(wq[i]); return; }
    i -= 262144;
    if (i < 262144) { wqkv[262144 + i] = to_bf16(wk[i]); return; }
    i -= 262144;
    if (i < 262144) { wqkv[524288 + i] = to_bf16(wv[i]); return; }
    i -= 262144;
    if (i < 262144) { wo_bf[i] = to_bf16(wo[i]); return; }
    i -= 262144;
    if (i < 524288) { cf1_bf[i] = to_bf16(cf_w1[i]); return; }
    i -= 524288;
    if (i < 524288) { cf2_bf[i] = to_bf16(cf_w2[i]); return; }
    i -= 524288;
    if (i < 262144) { clsreg_bf[i] = to_bf16(cls_w1[i]); return; }
    i -= 262144;
    if (i < 262144) { clsreg_bf[262144 + i] = to_bf16(reg_w1[i]); return; }
    i -= 262144;
    if (i < 524288) { p1_bf[i] = to_bf16(p_w1[i]); return; }
    i -= 524288;
    if (i < 512) { bqkv[i] = bq[i]; return; }
    if (i < 1024) { bqkv[i] = bk[i - 512]; return; }
    if (i < 1536) { bqkv[i] = bv[i - 1024]; return; }
    i -= 1536;
    if (i < 512) { bclsreg[i] = cls_b1[i]; return; }
    if (i < 1024) { bclsreg[i] = reg_b1[i - 512]; return; }
}

// ---- fuse dp into gf: Wout[o][i*72+m] = sum_k gf_w[o][i*72+k] * dp_w[k][m]; pad to 672 ----
__global__ __launch_bounds__(256) void k_wfuse(
    const float* __restrict__ gf_w, const float* __restrict__ dp_w,
    __hip_bfloat16* __restrict__ Wout)
{
    const int o = blockIdx.x;
    const int tid = threadIdx.x;
    __shared__ float dpS[CADJ][CADJ + 1];
    __shared__ float gfr[648];
    for (int i = tid; i < CADJ * CADJ; i += 256) dpS[i / CADJ][i % CADJ] = dp_w[i];
    for (int i = tid; i < 648; i += 256) gfr[i] = gf_w[(size_t)o * 648 + i];
    __syncthreads();
    for (int t = tid; t < 672; t += 256) {
        float acc = 0.0f;
        if (t < 648) {
            const int i = t / 72, m = t % 72;
            const float* gr = gfr + i * 72;
#pragma unroll 8
            for (int k = 0; k < 72; ++k) acc = fmaf(gr[k], dpS[k][m], acc);
        }
        Wout[(size_t)o * 672 + t] = to_bf16(acc);
    }
}

// ---- fused bias: b2[o] = gf_b[o] + sum_{i,k} gf_w[o][i*72+k] * dp_b[k] ----
__global__ __launch_bounds__(256) void k_wfuseb(
    const float* __restrict__ gf_w, const float* __restrict__ dp_b,
    const float* __restrict__ gf_b, float* __restrict__ b2)
{
    const int o = blockIdx.x * 256 + threadIdx.x;
    if (o >= DD) return;
    const float* gr = gf_w + (size_t)o * 648;
    float acc = gf_b[o];
    for (int j = 0; j < 648; ++j) acc = fmaf(gr[j], dp_b[j % 72], acc);
    b2[o] = acc;
}

// ---- fused tiled channel-adjust (+ optional offset head), 64 pixels/block ----
// input NCHW staged coalesced into LDS; fe (and offs for level 0) written NHWC coalesced
__global__ __launch_bounds__(256) void k_adjoff(
    const float* __restrict__ f, const float* __restrict__ caw, const float* __restrict__ cab,
    const float* __restrict__ offw, const float* __restrict__ offb,
    float* __restrict__ feout, float* __restrict__ offout, int HW, int do_off)
{
    __shared__ float inS[64][65];    // [c][px]
    __shared__ float wS[72][64];     // ca_w
    __shared__ float owS[72][73];    // off_w padded
    __shared__ float feS[64][73];    // fe tile [px][o] padded
    __shared__ float cabS[72], obS[72];

    const int tid = threadIdx.x;
    const int b = blockIdx.y;
    const int pix0 = blockIdx.x * 64;
    const int cnt = min(64, HW - pix0);
    const int px = tid & 63, og = tid >> 6, o0 = og * 18;

    const float* fb = f + (size_t)b * CIN * HW + pix0;
    for (int i = tid; i < 72 * 64; i += 256) wS[i >> 6][i & 63] = caw[i];
    if (do_off)
        for (int i = tid; i < 72 * 72; i += 256) owS[i / 72][i % 72] = offw[i];
    if (tid < 72) { cabS[tid] = cab[tid]; obS[tid] = do_off ? offb[tid] : 0.f; }
    for (int i = tid; i < 64 * 64; i += 256) {
        const int c = i >> 6, p = i & 63;
        inS[c][p] = (p < cnt) ? fb[(size_t)c * HW + p] : 0.f;
    }
    __syncthreads();

    // phase 1: fe = in @ ca_w^T + ca_b  (each thread: 1 pixel x 18 out-ch)
    float acc[18];
#pragma unroll
    for (int j = 0; j < 18; ++j) acc[j] = cabS[o0 + j];
#pragma unroll 4
    for (int c = 0; c < 64; ++c) {
        const float v = inS[c][px];
#pragma unroll
        for (int j = 0; j < 18; ++j) acc[j] = fmaf(v, wS[o0 + j][c], acc[j]);
    }
#pragma unroll
    for (int j = 0; j < 18; ++j) feS[px][o0 + j] = acc[j];
    __syncthreads();

    float* feg = feout + ((size_t)b * HW + pix0) * CADJ;
    for (int i = tid; i < cnt * CADJ; i += 256) feg[i] = feS[i / CADJ][i % CADJ];

    if (!do_off) return;

    // phase 2: offs = fe @ off_w^T + off_b (tile-local)
    float acc2[18];
#pragma unroll
    for (int j = 0; j < 18; ++j) acc2[j] = obS[o0 + j];
#pragma unroll 4
    for (int c = 0; c < 72; ++c) {
        const float v = feS[px][c];
#pragma unroll
        for (int j = 0; j < 18; ++j) acc2[j] = fmaf(v, owS[o0 + j][c], acc2[j]);
    }
    __syncthreads();   // all feS reads (copy + phase2) complete
#pragma unroll
    for (int j = 0; j < 18; ++j) feS[px][o0 + j] = acc2[j];
    __syncthreads();
    float* ofg = offout + ((size_t)b * HW + pix0) * CADJ;
    for (int i = tid; i < cnt * CADJ; i += 256) ofg[i] = feS[i / CADJ][i % CADJ];
}

// ---- align-corners resize ----
__global__ __launch_bounds__(256) void k_resize(const float* __restrict__ src,
    float* __restrict__ dst, int Ht, int Wt)
{
    int idx = blockIdx.x * 256 + threadIdx.x;
    int total = BB * Ht * Wt * CADJ;
    if (idx >= total) return;
    int c = idx % CADJ;
    int j = (idx / CADJ) % Wt;
    int i = (idx / (CADJ * Wt)) % Ht;
    int b = idx / (CADJ * Wt * Ht);
    float sy = fminf((float)i * ((float)(H0 - 1) / (float)(Ht - 1)), (float)(H0 - 1));
    float sx = fminf((float)j * ((float)(W0 - 1) / (float)(Wt - 1)), (float)(W0 - 1));
    dst[idx] = bsample(src + (size_t)b * H0 * W0 * CADJ, H0, W0, CADJ, c, sx, sy);
}

// ---- sampling + z-fuse only (dp folded into gf weights); smp bf16 [6144][4*672] ----
__global__ __launch_bounds__(256) void k_sample(
    const float* __restrict__ priors,
    const float* __restrict__ feats0, const float* __restrict__ feats1, const float* __restrict__ feats2,
    const float* __restrict__ offs0,  const float* __restrict__ offs1,  const float* __restrict__ offs2,
    const float* __restrict__ z_emb,
    __hip_bfloat16* __restrict__ fsout)
{
    const int bp = blockIdx.x;
    const int b = bp / PP;
    const int tid = threadIdx.x;

    __shared__ float zw[3][SS];
    __shared__ float wgt[3][SS][4];
    __shared__ int cx0s[3][SS];
    __shared__ int cy0s[3][SS];

    const int Hs[3] = {H0, H1, H2};
    const int Wsz[3] = {W0, W1, W2};
    const float* Fb[3] = { feats0 + (size_t)b * H0 * W0 * CADJ,
                           feats1 + (size_t)b * H1 * W1 * CADJ,
                           feats2 + (size_t)b * H2 * W2 * CADJ };
    const float* Ob[3] = { offs0 + (size_t)b * H0 * W0 * CADJ,
                           offs1 + (size_t)b * H1 * W1 * CADJ,
                           offs2 + (size_t)b * H2 * W2 * CADJ };

    if (tid < 3 * SS) {
        const int s = tid % SS;
        const int l = tid / SS;
        const float t = (float)(35 - s) / 35.0f;
        const int m = (int)floorf(t * 71.0f);
        const float pfx = priors[(size_t)bp * NPRI + 4 + m];
        const float gxv = fminf(fmaxf(pfx / 71.0f, 0.0f), 1.0f) * 2.0f - 1.0f;
        const float gyv = (1.0f - (float)m / 71.0f) * 2.0f - 1.0f;
        const float z = z_emb[s];
        const float e0 = expf(-0.5f * z * z);
        const float e1 = expf(-0.5f * (z - 1.0f) * (z - 1.0f));
        const float e2 = expf(-0.5f * (z - 2.0f) * (z - 2.0f));
        const float inv = 1.0f / (e0 + e1 + e2);
        const float ev[3] = {e0, e1, e2};
        zw[l][s] = ev[l] * inv;

        const int Hl = Hs[l], Wl = Wsz[l];
        const float px = (gxv + 1.0f) * 0.5f * (float)(Wl - 1);
        const float py = (gyv + 1.0f) * 0.5f * (float)(Hl - 1);
        const float dy = bsample(Ob[l], Hl, Wl, CADJ, 2 * s,     px, py);
        const float dx = bsample(Ob[l], Hl, Wl, CADJ, 2 * s + 1, px, py);
        const float sx = px + dx, sy = py + dy;
        const float x0f = floorf(sx), y0f = floorf(sy);
        const int x0 = (int)x0f, y0 = (int)y0f;
        const float wx1 = sx - x0f, wy1 = sy - y0f;
        const float wx0 = 1.0f - wx1, wy0 = 1.0f - wy1;
        const bool vx0 = (x0 >= 0) && (x0 < Wl);
        const bool vx1 = (x0 + 1 >= 0) && (x0 + 1 < Wl);
        const bool vy0 = (y0 >= 0) && (y0 < Hl);
        const bool vy1 = (y0 + 1 >= 0) && (y0 + 1 < Hl);
        wgt[l][s][0] = (vx0 && vy0) ? wx0 * wy0 : 0.0f;
        wgt[l][s][1] = (vx1 && vy0) ? wx1 * wy0 : 0.0f;
        wgt[l][s][2] = (vx0 && vy1) ? wx0 * wy1 : 0.0f;
        wgt[l][s][3] = (vx1 && vy1) ? wx1 * wy1 : 0.0f;
        cx0s[l][s] = x0; cy0s[l][s] = y0;
    }
    __syncthreads();

    __hip_bfloat16* orow = fsout + (size_t)bp * 2688;
    for (int idx = tid; idx < SS * CADJ; idx += 256) {
        const int s = idx / CADJ, k = idx % CADJ;
        float acc = 0.0f;
#pragma unroll
        for (int l = 0; l < 3; ++l) {
            const int Hl = Hs[l], Wl = Wsz[l];
            const int x0 = cx0s[l][s], y0 = cy0s[l][s];
            const int xc0 = min(max(x0, 0), Wl - 1);
            const int xc1 = min(max(x0 + 1, 0), Wl - 1);
            const int yc0 = min(max(y0, 0), Hl - 1);
            const int yc1 = min(max(y0 + 1, 0), Hl - 1);
            const float* F = Fb[l];
            float v = wgt[l][s][0] * F[((size_t)yc0 * Wl + xc0) * CADJ + k]
                    + wgt[l][s][1] * F[((size_t)yc0 * Wl + xc1) * CADJ + k]
                    + wgt[l][s][2] * F[((size_t)yc1 * Wl + xc0) * CADJ + k]
                    + wgt[l][s][3] * F[((size_t)yc1 * Wl + xc1) * CADJ + k];
            acc = fmaf(zw[l][s], v, acc);
        }
        orow[(s / 9) * 672 + (s % 9) * 72 + k] = to_bf16(acc);
    }
    if (tid < 96) {  // zero the 24-col tail of each group
        const int g = tid / 24, t = tid % 24;
        orow[g * 672 + 648 + t] = to_bf16(0.0f);
    }
}

// ---- bf16 MFMA GEMM, 128x128 tile, LDS-staged: C = act(A @ W^T + bias (+Res)) ----
// grid = (N/128, M/128, nz); 256 threads = 4 waves in 2x2, each wave 64x64 out
__global__ __launch_bounds__(256) void k_bgemm(
    const __hip_bfloat16* __restrict__ A, int lda, long sAz,
    const __hip_bfloat16* __restrict__ W, int ldw, long sWz,
    const float* __restrict__ bias, int sBz,
    const __hip_bfloat16* __restrict__ Res, int ldres,
    __hip_bfloat16* __restrict__ C, int ldc, int sCz,
    int K, int relu)
{
    __shared__ __hip_bfloat16 As[128][40];   // 32-col tile padded to 40 (80B rows)
    __shared__ __hip_bfloat16 Bs[128][40];
    const int tid = threadIdx.x;
    const int lane = tid & 63, w = tid >> 6;
    const int wr = w >> 1, wc = w & 1;
    const int row16 = lane & 15, kg = lane >> 4;
    const int z = blockIdx.z;
    const int m0 = blockIdx.y * 128, n0 = blockIdx.x * 128;
    const __hip_bfloat16* Ab = A + (size_t)z * sAz;
    const __hip_bfloat16* Wb = W + (size_t)z * sWz;
    const int r0 = tid >> 2, c0 = (tid & 3) * 8;   // staging: 4 chunks of 8 bf16 per row

    f32x4 acc[4][4];
#pragma unroll
    for (int i = 0; i < 4; ++i)
#pragma unroll
        for (int j = 0; j < 4; ++j) acc[i][j] = (f32x4){0.f, 0.f, 0.f, 0.f};

    for (int k0 = 0; k0 < K; k0 += 32) {
        __syncthreads();
        *(bf16x8*)&As[r0][c0]      = *(const bf16x8*)(Ab + (size_t)(m0 + r0) * lda + k0 + c0);
        *(bf16x8*)&As[r0 + 64][c0] = *(const bf16x8*)(Ab + (size_t)(m0 + r0 + 64) * lda + k0 + c0);
        *(bf16x8*)&Bs[r0][c0]      = *(const bf16x8*)(Wb + (size_t)(n0 + r0) * ldw + k0 + c0);
        *(bf16x8*)&Bs[r0 + 64][c0] = *(const bf16x8*)(Wb + (size_t)(n0 + r0 + 64) * ldw + k0 + c0);
        __syncthreads();
        bf16x8 af[4], bfr[4];
#pragma unroll
        for (int i = 0; i < 4; ++i) af[i]  = *(const bf16x8*)&As[wr * 64 + i * 16 + row16][kg * 8];
#pragma unroll
        for (int j = 0; j < 4; ++j) bfr[j] = *(const bf16x8*)&Bs[wc * 64 + j * 16 + row16][kg * 8];
#pragma unroll
        for (int i = 0; i < 4; ++i)
#pragma unroll
            for (int j = 0; j < 4; ++j)
                acc[i][j] = MFMA_BF16(af[i], bfr[j], acc[i][j], 0, 0, 0);
    }

    const float* bz = bias + (size_t)z * sBz;
    __hip_bfloat16* Cz = C + (size_t)z * sCz;
#pragma unroll
    for (int i = 0; i < 4; ++i) {
#pragma unroll
        for (int r = 0; r < 4; ++r) {
            const int row = m0 + wr * 64 + i * 16 + kg * 4 + r;
#pragma unroll
            for (int j = 0; j < 4; ++j) {
                const int col = n0 + wc * 64 + j * 16 + row16;
                float v = acc[i][j][r] + bz[col];
                if (Res) v += bf2f(Res[(size_t)row * ldres + col]);
                if (relu) v = fmaxf(v, 0.0f);
                Cz[(size_t)row * ldc + col] = to_bf16(v);
            }
        }
    }
}

// ---- flash attention, bf16 MFMA. qkv [6144][1536]; grid (12 qtiles, 32 bg) ----
__global__ __launch_bounds__(256) void k_fattn(
    const __hip_bfloat16* __restrict__ qkv, __hip_bfloat16* __restrict__ Out)
{
    const int qt = blockIdx.x, bg = blockIdx.y;
    const int b = bg >> 2, g = bg & 3;
    const int tid = threadIdx.x, lane = tid & 63, w = tid >> 6;
    const int row16 = lane & 15, kg = lane >> 4;
    const int q0 = qt * 64;

    __shared__ __hip_bfloat16 Klds[32][136];
    __shared__ __hip_bfloat16 Vtlds[128][40];
    __shared__ __hip_bfloat16 Plds[4][16][40];

    const size_t rowQ = (size_t)(b * PP + q0 + w * 16 + row16) * 1536 + g * 128;
    bf16x8 aq[4];
#pragma unroll
    for (int t = 0; t < 4; ++t)
        aq[t] = *(const bf16x8*)(qkv + rowQ + t * 32 + kg * 8);

    f32x4 oacc[8];
#pragma unroll
    for (int dt = 0; dt < 8; ++dt) oacc[dt] = (f32x4){0.f, 0.f, 0.f, 0.f};
    float mrow[4] = {-INFINITY, -INFINITY, -INFINITY, -INFINITY};
    float lrow[4] = {0.f, 0.f, 0.f, 0.f};

    const __hip_bfloat16* Kbase = qkv + (size_t)(b * PP) * 1536 + 512 + g * 128;
    const __hip_bfloat16* Vbase = qkv + (size_t)(b * PP) * 1536 + 1024 + g * 128;
    const float sc = 0.08838834764831845f;

    for (int kt = 0; kt < 24; ++kt) {
        __syncthreads();
        if (tid >= 128) {
            const int t2 = tid - 128;
            const int r = t2 >> 2;
            const int cp = (t2 & 3) * 32;
            const __hip_bfloat16* src = Kbase + (size_t)(kt * 32 + r) * 1536 + cp;
            *(bf16x8*)&Klds[r][cp]      = *(const bf16x8*)(src);
            *(bf16x8*)&Klds[r][cp + 8]  = *(const bf16x8*)(src + 8);
            *(bf16x8*)&Klds[r][cp + 16] = *(const bf16x8*)(src + 16);
            *(bf16x8*)&Klds[r][cp + 24] = *(const bf16x8*)(src + 24);
        } else {
            const int kk = (tid >> 3) * 2;
            const int cp = (tid & 7) * 16;
            const __hip_bfloat16* v0p = Vbase + (size_t)(kt * 32 + kk) * 1536 + cp;
            bf16x8 x0a = *(const bf16x8*)(v0p);
            bf16x8 x0b = *(const bf16x8*)(v0p + 8);
            bf16x8 x1a = *(const bf16x8*)(v0p + 1536);
            bf16x8 x1b = *(const bf16x8*)(v0p + 1536 + 8);
#pragma unroll
            for (int i = 0; i < 8; ++i) {
                unsigned lo = (unsigned short)x0a[i], hi = (unsigned short)x1a[i];
                *(unsigned*)&Vtlds[cp + i][kk] = lo | (hi << 16);
                unsigned lo2 = (unsigned short)x0b[i], hi2 = (unsigned short)x1b[i];
                *(unsigned*)&Vtlds[cp + 8 + i][kk] = lo2 | (hi2 << 16);
            }
        }
        __syncthreads();

        f32x4 s0 = {0.f, 0.f, 0.f, 0.f}, s1 = s0;
#pragma unroll
        for (int t = 0; t < 4; ++t) {
            bf16x8 bk0 = *(const bf16x8*)&Klds[row16][t * 32 + kg * 8];
            bf16x8 bk1 = *(const bf16x8*)&Klds[16 + row16][t * 32 + kg * 8];
            s0 = MFMA_BF16(aq[t], bk0, s0, 0, 0, 0);
            s1 = MFMA_BF16(aq[t], bk1, s1, 0, 0, 0);
        }

#pragma unroll
        for (int r = 0; r < 4; ++r) {
            float v0 = s0[r] * sc, v1 = s1[r] * sc;
            float mx = fmaxf(v0, v1);
            mx = fmaxf(mx, __shfl_xor(mx, 1));
            mx = fmaxf(mx, __shfl_xor(mx, 2));
            mx = fmaxf(mx, __shfl_xor(mx, 4));
            mx = fmaxf(mx, __shfl_xor(mx, 8));
            const float mnew = fmaxf(mrow[r], mx);
            const float scale_old = __expf(mrow[r] - mnew);
            const float p0 = __expf(v0 - mnew);
            const float p1 = __expf(v1 - mnew);
            float rs = p0 + p1;
            rs += __shfl_xor(rs, 1);
            rs += __shfl_xor(rs, 2);
            rs += __shfl_xor(rs, 4);
            rs += __shfl_xor(rs, 8);
            lrow[r] = lrow[r] * scale_old + rs;
            mrow[r] = mnew;
#pragma unroll
            for (int dt = 0; dt < 8; ++dt) oacc[dt][r] *= scale_old;
            Plds[w][kg * 4 + r][row16]      = to_bf16(p0);
            Plds[w][kg * 4 + r][16 + row16] = to_bf16(p1);
        }

        bf16x8 ap = *(const bf16x8*)&Plds[w][row16][kg * 8];
#pragma unroll
        for (int dt = 0; dt < 8; ++dt) {
            bf16x8 bv = *(const bf16x8*)&Vtlds[dt * 16 + row16][kg * 8];
            oacc[dt] = MFMA_BF16(ap, bv, oacc[dt], 0, 0, 0);
        }
    }

    const size_t obase = (size_t)(b * PP + q0 + w * 16 + kg * 4) * DD + g * 128;
#pragma unroll
    for (int r = 0; r < 4; ++r) {
        const float inv = 1.0f / lrow[r];
#pragma unroll
        for (int dt = 0; dt < 8; ++dt)
            Out[obase + (size_t)r * DD + dt * 16 + row16] = to_bf16(oacc[dt][r] * inv);
    }
}

// ---- final heads (bf16 inputs; clsh rows have ld=1024: [cls|reg] fused buffer) ----
__global__ __launch_bounds__(64) void k_head(
    const __hip_bfloat16* __restrict__ clsreg, const __hip_bfloat16* __restrict__ ph,
    const float* __restrict__ cls_w2, const float* __restrict__ cls_b2,
    const float* __restrict__ p_w2, const float* __restrict__ p_b2,
    const float* __restrict__ b_scale, const float* __restrict__ b_bias,
    float* __restrict__ outp)
{
    const int bp = blockIdx.x;
    const int lane = threadIdx.x;
    const __hip_bfloat16* hr = clsreg + (size_t)bp * 1024;
    float a0 = 0.0f, a1 = 0.0f;
    for (int i = lane; i < DD; i += 64) {
        float h = bf2f(hr[i]);
        a0 = fmaf(h, cls_w2[i], a0);
        a1 = fmaf(h, cls_w2[DD + i], a1);
    }
    const __hip_bfloat16* pr = ph + (size_t)bp * 1024;
    float c0 = 0.0f, c1 = 0.0f, c2 = 0.0f, c3 = 0.0f;
    for (int i = lane; i < 1024; i += 64) {
        float h = bf2f(pr[i]);
        c0 = fmaf(h, p_w2[i], c0);
        c1 = fmaf(h, p_w2[1024 + i], c1);
        c2 = fmaf(h, p_w2[2048 + i], c2);
        c3 = fmaf(h, p_w2[3072 + i], c3);
    }
#pragma unroll
    for (int off = 32; off > 0; off >>= 1) {
        a0 += __shfl_down(a0, off);
        a1 += __shfl_down(a1, off);
        c0 += __shfl_down(c0, off);
        c1 += __shfl_down(c1, off);
        c2 += __shfl_down(c2, off);
        c3 += __shfl_down(c3, off);
    }
    a0 = __shfl(a0, 0); a1 = __shfl(a1, 0);
    c0 = __shfl(c0, 0); c1 = __shfl(c1, 0);
    c2 = __shfl(c2, 0); c3 = __shfl(c3, 0);
    const float k0 = c0 + p_b2[0];
    const float k1 = c1 + p_b2[1];
    const float scv = b_scale[0], biv = b_bias[0];
    const float k2 = (c2 + p_b2[2]) * scv + biv;
    const float k3 = (c3 + p_b2[3]) * scv + biv;
    float* orow = outp + (size_t)bp * 78;
    if (lane == 0) {
        orow[0] = a0 + cls_b2[0];
        orow[1] = a1 + cls_b2[1];
        orow[2] = k0; orow[3] = k1; orow[4] = k2; orow[5] = k3;
    }
    for (int o = lane; o < 72; o += 64) {
        float ys = (float)o / 71.0f;
        float tv = k0 + ys * (k1 + ys * (k2 + ys * k3));
        orow[6 + o] = 1.0f / (1.0f + expf(-tv));
    }
}

extern "C" void kernel_launch(void* const* d_in, const int* in_sizes, int n_in,
                              void* d_out, int out_size, void* d_ws, size_t ws_size,
                              hipStream_t stream)
{
    const float* feat0  = (const float*)d_in[0];
    const float* feat1  = (const float*)d_in[1];
    const float* feat2  = (const float*)d_in[2];
    const float* priors = (const float*)d_in[3];
    const float* ca_w   = (const float*)d_in[4];
    const float* ca_b   = (const float*)d_in[5];
    const float* off_w  = (const float*)d_in[6];
    const float* off_b  = (const float*)d_in[7];
    const float* dp_w   = (const float*)d_in[8];
    const float* dp_b   = (const float*)d_in[9];
    const float* z_emb  = (const float*)d_in[10];
    const float* gf_w   = (const float*)d_in[11];
    const float* gf_b   = (const float*)d_in[12];
    const float* wq     = (const float*)d_in[13];
    const float* bq     = (const float*)d_in[14];
    const float* wk     = (const float*)d_in[15];
    const float* bk     = (const float*)d_in[16];
    const float* wv     = (const float*)d_in[17];
    const float* bv     = (const float*)d_in[18];
    const float* wo     = (const float*)d_in[19];
    const float* bo     = (const float*)d_in[20];
    const float* cf_w1  = (const float*)d_in[21];
    const float* cf_b1  = (const float*)d_in[22];
    const float* cf_w2  = (const float*)d_in[23];
    const float* cf_b2  = (const float*)d_in[24];
    const float* cls_w1 = (const float*)d_in[25];
    const float* cls_b1 = (const float*)d_in[26];
    const float* cls_w2 = (const float*)d_in[27];
    const float* cls_b2 = (const float*)d_in[28];
    const float* reg_w1 = (const float*)d_in[29];
    const float* reg_b1 = (const float*)d_in[30];
    const float* p_w1   = (const float*)d_in[31];
    const float* p_b1   = (const float*)d_in[32];
    const float* p_w2   = (const float*)d_in[33];
    const float* p_b2   = (const float*)d_in[34];
    const float* b_scale = (const float*)d_in[35];
    const float* b_bias  = (const float*)d_in[36];
    float* out = (float*)d_out;

    char* wsb = (char*)d_ws;
    // persistent bf16 activations
    __hip_bfloat16* feature = (__hip_bfloat16*)(wsb + 0);          // [6144][512]
    __hip_bfloat16* qkvb    = (__hip_bfloat16*)(wsb + 6291456);    // [6144][1536]
    __hip_bfloat16* tb      = (__hip_bfloat16*)(wsb + 25165824);   // [6144][512]
    __hip_bfloat16* rb      = (__hip_bfloat16*)(wsb + 31457280);
    __hip_bfloat16* hb      = (__hip_bfloat16*)(wsb + 37748736);   // [6144][1024]
    __hip_bfloat16* f2      = (__hip_bfloat16*)(wsb + 50331648);   // [6144][512]
    __hip_bfloat16* clsregb = (__hip_bfloat16*)(wsb + 56623104);   // [6144][1024]
    __hip_bfloat16* phb     = (__hip_bfloat16*)(wsb + 69206016);   // [6144][1024]
    // early-phase f32 buffers (dead before the overlapping late users are written)
    float* of1 = (float*)(wsb + 6291456);
    float* of2 = (float*)(wsb + 8595456);
    float* fe1 = (float*)(wsb + 9171456);
    float* fe2 = (float*)(wsb + 11475456);
    __hip_bfloat16* fsb = (__hip_bfloat16*)(wsb + 25165824);       // smp [6144][2688]
    float* fe0 = (float*)(wsb + 58195968);
    float* of0 = (float*)(wsb + 67411968);
    // bf16 weights
    __hip_bfloat16* wqkv_bf   = (__hip_bfloat16*)(wsb + 81788928); // [1536][512]
    __hip_bfloat16* wo_bf     = (__hip_bfloat16*)(wsb + 83361792);
    __hip_bfloat16* cf1_bf    = (__hip_bfloat16*)(wsb + 83886080);
    __hip_bfloat16* cf2_bf    = (__hip_bfloat16*)(wsb + 84934656);
    __hip_bfloat16* clsreg_bf = (__hip_bfloat16*)(wsb + 85983232); // [1024][512]
    __hip_bfloat16* p1_bf     = (__hip_bfloat16*)(wsb + 87031808);
    __hip_bfloat16* gfw2_bf   = (__hip_bfloat16*)(wsb + 88080384); // [512][672] dp-fused gf
    float* bqkv    = (float*)(wsb + 88768512);                     // [1536]
    float* bclsreg = (float*)(wsb + 88774656);                     // [1024]
    float* b2      = (float*)(wsb + 88778752);                     // [512]

    k_wcast<<<(3148288 + 255) / 256, 256, 0, stream>>>(
        wq, wk, wv, wo, cf_w1, cf_w2, cls_w1, reg_w1, p_w1, bq, bk, bv, cls_b1, reg_b1,
        wqkv_bf, wo_bf, cf1_bf, cf2_bf, clsreg_bf, p1_bf, bqkv, bclsreg);
    k_wfuse<<<512, 256, 0, stream>>>(gf_w, dp_w, gfw2_bf);
    k_wfuseb<<<2, 256, 0, stream>>>(gf_w, dp_b, gf_b, b2);

    // fused channel-adjust (+offset head on level 0); tiled, coalesced
    k_adjoff<<<dim3(63, BB), 256, 0, stream>>>(feat0, ca_w, ca_b, off_w, off_b,
                                               fe0, of0, H0 * W0, 1);
    k_adjoff<<<dim3(16, BB), 256, 0, stream>>>(feat1, ca_w, ca_b, off_w, off_b,
                                               fe1, nullptr, H1 * W1, 0);
    k_adjoff<<<dim3(4, BB), 256, 0, stream>>>(feat2, ca_w, ca_b, off_w, off_b,
                                              fe2, nullptr, H2 * W2, 0);
    k_resize<<<(BB * H1 * W1 * CADJ + 255) / 256, 256, 0, stream>>>(of0, of1, H1, W1);
    k_resize<<<(BB * H2 * W2 * CADJ + 255) / 256, 256, 0, stream>>>(of0, of2, H2, W2);
    k_sample<<<BB * PP, 256, 0, stream>>>(priors, fe0, fe1, fe2, of0, of1, of2, z_emb, fsb);

    const int M = BB * PP;
    // grouped gather-fc (dp folded in): per group N=128, K=672
    k_bgemm<<<dim3(1, M / 128, 4), 256, 0, stream>>>(
        fsb, 2688, 672, gfw2_bf, 672, 128 * 672, b2, 128,
        nullptr, 0, feature, DD, 128, 672, 0);
    // QKV fused
    k_bgemm<<<dim3(12, M / 128, 1), 256, 0, stream>>>(
        feature, DD, 0, wqkv_bf, DD, 0, bqkv, 0,
        nullptr, 0, qkvb, 1536, 0, DD, 0);
    k_fattn<<<dim3(12, 32), 256, 0, stream>>>(qkvb, tb);
    k_bgemm<<<dim3(4, M / 128, 1), 256, 0, stream>>>(
        tb, DD, 0, wo_bf, DD, 0, bo, 0, nullptr, 0, rb, DD, 0, DD, 0);
    k_bgemm<<<dim3(8, M / 128, 1), 256, 0, stream>>>(
        rb, DD, 0, cf1_bf, DD, 0, cf_b1, 0, nullptr, 0, hb, 1024, 0, DD, 1);
    k_bgemm<<<dim3(4, M / 128, 1), 256, 0, stream>>>(
        hb, 1024, 0, cf2_bf, 1024, 0, cf_b2, 0, feature, DD, f2, DD, 0, 1024, 0);
    // cls+reg fused: N=1024 ([cls|reg]), relu
    k_bgemm<<<dim3(8, M / 128, 1), 256, 0, stream>>>(
        f2, DD, 0, clsreg_bf, DD, 0, bclsreg, 0, nullptr, 0, clsregb, 1024, 0, DD, 1);
    // p1 on reg half (cols 512..1023 of clsregb)
    k_bgemm<<<dim3(8, M / 128, 1), 256, 0, stream>>>(
        clsregb + 512, 1024, 0, p1_bf, DD, 0, p_b1, 0, nullptr, 0, phb, 1024, 0, DD, 1);

    k_head<<<M, 64, 0, stream>>>(clsregb, phb, cls_w2, cls_b2, p_w2, p_b2, b_scale, b_bias, out);
}

// Round 7
// 375.392 us; speedup vs baseline: 7.9581x; 1.0721x over previous
//
#include <hip/hip_runtime.h>
#include <hip/hip_bf16.h>
#include <math.h>

#define BB 8
#define PP 768
#define NPRI 76
#define SS 36
#define CIN 64
#define CADJ 72
#define DD 512

#define H0 40
#define W0 100
#define H1 20
#define W1 50
#define H2 10
#define W2 25

typedef __attribute__((ext_vector_type(8))) short bf16x8;
typedef __attribute__((ext_vector_type(4))) float f32x4;
#define MFMA_BF16 __builtin_amdgcn_mfma_f32_16x16x32_bf16

typedef const __attribute__((address_space(1))) unsigned int* gas_t;
typedef __attribute__((address_space(3))) unsigned int* las_t;

__device__ __forceinline__ __hip_bfloat16 to_bf16(float v) { return __float2bfloat16(v); }
__device__ __forceinline__ float bf2f(__hip_bfloat16 v) { return __bfloat162float(v); }

// ---- bilinear sample, zeros outside ----
__device__ __forceinline__ float bsample(const float* __restrict__ img, int H, int W,
                                         int C, int c, float x, float y)
{
    float x0f = floorf(x), y0f = floorf(y);
    int x0 = (int)x0f, y0 = (int)y0f;
    float wx1 = x - x0f, wy1 = y - y0f;
    float wx0 = 1.0f - wx1, wy0 = 1.0f - wy1;
    int xc0 = min(max(x0, 0), W - 1);
    int xc1 = min(max(x0 + 1, 0), W - 1);
    int yc0 = min(max(y0, 0), H - 1);
    int yc1 = min(max(y0 + 1, 0), H - 1);
    bool vx0 = (x0 >= 0) && (x0 < W);
    bool vx1 = (x0 + 1 >= 0) && (x0 + 1 < W);
    bool vy0 = (y0 >= 0) && (y0 < H);
    bool vy1 = (y0 + 1 >= 0) && (y0 + 1 < H);
    float w00 = (vx0 && vy0) ? wx0 * wy0 : 0.0f;
    float w01 = (vx1 && vy0) ? wx1 * wy0 : 0.0f;
    float w10 = (vx0 && vy1) ? wx0 * wy1 : 0.0f;
    float w11 = (vx1 && vy1) ? wx1 * wy1 : 0.0f;
    return w00 * img[((size_t)yc0 * W + xc0) * C + c]
         + w01 * img[((size_t)yc0 * W + xc1) * C + c]
         + w10 * img[((size_t)yc1 * W + xc0) * C + c]
         + w11 * img[((size_t)yc1 * W + xc1) * C + c];
}

// ---- weight cast f32 -> bf16 (+ bias concats) ----
__global__ __launch_bounds__(256) void k_wcast(
    const float* __restrict__ wq, const float* __restrict__ wk, const float* __restrict__ wv,
    const float* __restrict__ wo, const float* __restrict__ cf_w1, const float* __restrict__ cf_w2,
    const float* __restrict__ cls_w1, const float* __restrict__ reg_w1, const float* __restrict__ p_w1,
    const float* __restrict__ bq, const float* __restrict__ bk, const float* __restrict__ bv,
    const float* __restrict__ cls_b1, const float* __restrict__ reg_b1,
    __hip_bfloat16* __restrict__ wqkv, __hip_bfloat16* __restrict__ wo_bf,
    __hip_bfloat16* __restrict__ cf1_bf, __hip_bfloat16* __restrict__ cf2_bf,
    __hip_bfloat16* __restrict__ clsreg_bf, __hip_bfloat16* __restrict__ p1_bf,
    float* __restrict__ bqkv, float* __restrict__ bclsreg)
{
    long i = (long)blockIdx.x * 256 + threadIdx.x;
    if (i < 262144) { wqkv[i] = to_bf16(wq[i]); return; }
    i -= 262144;
    if (i < 262144) { wqkv[262144 + i] = to_bf16(wk[i]); return; }
    i -= 262144;
    if (i < 262144) { wqkv[524288 + i] = to_bf16(wv[i]); return; }
    i -= 262144;
    if (i < 262144) { wo_bf[i] = to_bf16(wo[i]); return; }
    i -= 262144;
    if (i < 524288) { cf1_bf[i] = to_bf16(cf_w1[i]); return; }
    i -= 524288;
    if (i < 524288) { cf2_bf[i] = to_bf16(cf_w2[i]); return; }
    i -= 524288;
    if (i < 262144) { clsreg_bf[i] = to_bf16(cls_w1[i]); return; }
    i -= 262144;
    if (i < 262144) { clsreg_bf[262144 + i] = to_bf16(reg_w1[i]); return; }
    i -= 262144;
    if (i < 524288) { p1_bf[i] = to_bf16(p_w1[i]); return; }
    i -= 524288;
    if (i < 512) { bqkv[i] = bq[i]; return; }
    if (i < 1024) { bqkv[i] = bk[i - 512]; return; }
    if (i < 1536) { bqkv[i] = bv[i - 1024]; return; }
    i -= 1536;
    if (i < 512) { bclsreg[i] = cls_b1[i]; return; }
    if (i < 1024) { bclsreg[i] = reg_b1[i - 512]; return; }
}

// ---- fuse dp into gf: Wout[o][i*72+m] = sum_k gf_w[o][i*72+k] * dp_w[k][m]; pad to 672 ----
__global__ __launch_bounds__(256) void k_wfuse(
    const float* __restrict__ gf_w, const float* __restrict__ dp_w,
    __hip_bfloat16* __restrict__ Wout)
{
    const int o = blockIdx.x;
    const int tid = threadIdx.x;
    __shared__ float dpS[CADJ][CADJ + 1];
    __shared__ float gfr[648];
    for (int i = tid; i < CADJ * CADJ; i += 256) dpS[i / CADJ][i % CADJ] = dp_w[i];
    for (int i = tid; i < 648; i += 256) gfr[i] = gf_w[(size_t)o * 648 + i];
    __syncthreads();
    for (int t = tid; t < 672; t += 256) {
        float acc = 0.0f;
        if (t < 648) {
            const int i = t / 72, m = t % 72;
            const float* gr = gfr + i * 72;
#pragma unroll 8
            for (int k = 0; k < 72; ++k) acc = fmaf(gr[k], dpS[k][m], acc);
        }
        Wout[(size_t)o * 672 + t] = to_bf16(acc);
    }
}

// ---- fused bias: b2[o] = gf_b[o] + sum gf_w[o][j] * dp_b[j%72] ----
__global__ __launch_bounds__(256) void k_wfuseb(
    const float* __restrict__ gf_w, const float* __restrict__ dp_b,
    const float* __restrict__ gf_b, float* __restrict__ b2)
{
    const int o = blockIdx.x * 256 + threadIdx.x;
    if (o >= DD) return;
    const float* gr = gf_w + (size_t)o * 648;
    float acc = gf_b[o];
    for (int j = 0; j < 648; ++j) acc = fmaf(gr[j], dp_b[j % 72], acc);
    b2[o] = acc;
}

// ---- fused tiled channel-adjust (+ optional offset head), 64 pixels/block ----
__global__ __launch_bounds__(256) void k_adjoff(
    const float* __restrict__ f, const float* __restrict__ caw, const float* __restrict__ cab,
    const float* __restrict__ offw, const float* __restrict__ offb,
    float* __restrict__ feout, float* __restrict__ offout, int HW, int do_off)
{
    __shared__ float inS[64][65];
    __shared__ float wS[72][64];
    __shared__ float owS[72][73];
    __shared__ float feS[64][73];
    __shared__ float cabS[72], obS[72];

    const int tid = threadIdx.x;
    const int b = blockIdx.y;
    const int pix0 = blockIdx.x * 64;
    const int cnt = min(64, HW - pix0);
    const int px = tid & 63, og = tid >> 6, o0 = og * 18;

    const float* fb = f + (size_t)b * CIN * HW + pix0;
    for (int i = tid; i < 72 * 64; i += 256) wS[i >> 6][i & 63] = caw[i];
    if (do_off)
        for (int i = tid; i < 72 * 72; i += 256) owS[i / 72][i % 72] = offw[i];
    if (tid < 72) { cabS[tid] = cab[tid]; obS[tid] = do_off ? offb[tid] : 0.f; }
    for (int i = tid; i < 64 * 64; i += 256) {
        const int c = i >> 6, p = i & 63;
        inS[c][p] = (p < cnt) ? fb[(size_t)c * HW + p] : 0.f;
    }
    __syncthreads();

    float acc[18];
#pragma unroll
    for (int j = 0; j < 18; ++j) acc[j] = cabS[o0 + j];
#pragma unroll 4
    for (int c = 0; c < 64; ++c) {
        const float v = inS[c][px];
#pragma unroll
        for (int j = 0; j < 18; ++j) acc[j] = fmaf(v, wS[o0 + j][c], acc[j]);
    }
#pragma unroll
    for (int j = 0; j < 18; ++j) feS[px][o0 + j] = acc[j];
    __syncthreads();

    float* feg = feout + ((size_t)b * HW + pix0) * CADJ;
    for (int i = tid; i < cnt * CADJ; i += 256) feg[i] = feS[i / CADJ][i % CADJ];

    if (!do_off) return;

    float acc2[18];
#pragma unroll
    for (int j = 0; j < 18; ++j) acc2[j] = obS[o0 + j];
#pragma unroll 4
    for (int c = 0; c < 72; ++c) {
        const float v = feS[px][c];
#pragma unroll
        for (int j = 0; j < 18; ++j) acc2[j] = fmaf(v, owS[o0 + j][c], acc2[j]);
    }
    __syncthreads();
#pragma unroll
    for (int j = 0; j < 18; ++j) feS[px][o0 + j] = acc2[j];
    __syncthreads();
    float* ofg = offout + ((size_t)b * HW + pix0) * CADJ;
    for (int i = tid; i < cnt * CADJ; i += 256) ofg[i] = feS[i / CADJ][i % CADJ];
}

// ---- align-corners resize ----
__global__ __launch_bounds__(256) void k_resize(const float* __restrict__ src,
    float* __restrict__ dst, int Ht, int Wt)
{
    int idx = blockIdx.x * 256 + threadIdx.x;
    int total = BB * Ht * Wt * CADJ;
    if (idx >= total) return;
    int c = idx % CADJ;
    int j = (idx / CADJ) % Wt;
    int i = (idx / (CADJ * Wt)) % Ht;
    int b = idx / (CADJ * Wt * Ht);
    float sy = fminf((float)i * ((float)(H0 - 1) / (float)(Ht - 1)), (float)(H0 - 1));
    float sx = fminf((float)j * ((float)(W0 - 1) / (float)(Wt - 1)), (float)(W0 - 1));
    dst[idx] = bsample(src + (size_t)b * H0 * W0 * CADJ, H0, W0, CADJ, c, sx, sy);
}

// ---- sampling + z-fuse (dp folded into gf weights); smp bf16 [6144][4*672] ----
__global__ __launch_bounds__(256) void k_sample(
    const float* __restrict__ priors,
    const float* __restrict__ feats0, const float* __restrict__ feats1, const float* __restrict__ feats2,
    const float* __restrict__ offs0,  const float* __restrict__ offs1,  const float* __restrict__ offs2,
    const float* __restrict__ z_emb,
    __hip_bfloat16* __restrict__ fsout)
{
    const int bp = blockIdx.x;
    const int b = bp / PP;
    const int tid = threadIdx.x;

    __shared__ float zw[3][SS];
    __shared__ float wgt[3][SS][4];
    __shared__ int cx0s[3][SS];
    __shared__ int cy0s[3][SS];

    const int Hs[3] = {H0, H1, H2};
    const int Wsz[3] = {W0, W1, W2};
    const float* Fb[3] = { feats0 + (size_t)b * H0 * W0 * CADJ,
                           feats1 + (size_t)b * H1 * W1 * CADJ,
                           feats2 + (size_t)b * H2 * W2 * CADJ };
    const float* Ob[3] = { offs0 + (size_t)b * H0 * W0 * CADJ,
                           offs1 + (size_t)b * H1 * W1 * CADJ,
                           offs2 + (size_t)b * H2 * W2 * CADJ };

    if (tid < 3 * SS) {
        const int s = tid % SS;
        const int l = tid / SS;
        const float t = (float)(35 - s) / 35.0f;
        const int m = (int)floorf(t * 71.0f);
        const float pfx = priors[(size_t)bp * NPRI + 4 + m];
        const float gxv = fminf(fmaxf(pfx / 71.0f, 0.0f), 1.0f) * 2.0f - 1.0f;
        const float gyv = (1.0f - (float)m / 71.0f) * 2.0f - 1.0f;
        const float z = z_emb[s];
        const float e0 = expf(-0.5f * z * z);
        const float e1 = expf(-0.5f * (z - 1.0f) * (z - 1.0f));
        const float e2 = expf(-0.5f * (z - 2.0f) * (z - 2.0f));
        const float inv = 1.0f / (e0 + e1 + e2);
        const float ev[3] = {e0, e1, e2};
        zw[l][s] = ev[l] * inv;

        const int Hl = Hs[l], Wl = Wsz[l];
        const float px = (gxv + 1.0f) * 0.5f * (float)(Wl - 1);
        const float py = (gyv + 1.0f) * 0.5f * (float)(Hl - 1);
        const float dy = bsample(Ob[l], Hl, Wl, CADJ, 2 * s,     px, py);
        const float dx = bsample(Ob[l], Hl, Wl, CADJ, 2 * s + 1, px, py);
        const float sx = px + dx, sy = py + dy;
        const float x0f = floorf(sx), y0f = floorf(sy);
        const int x0 = (int)x0f, y0 = (int)y0f;
        const float wx1 = sx - x0f, wy1 = sy - y0f;
        const float wx0 = 1.0f - wx1, wy0 = 1.0f - wy1;
        const bool vx0 = (x0 >= 0) && (x0 < Wl);
        const bool vx1 = (x0 + 1 >= 0) && (x0 + 1 < Wl);
        const bool vy0 = (y0 >= 0) && (y0 < Hl);
        const bool vy1 = (y0 + 1 >= 0) && (y0 + 1 < Hl);
        wgt[l][s][0] = (vx0 && vy0) ? wx0 * wy0 : 0.0f;
        wgt[l][s][1] = (vx1 && vy0) ? wx1 * wy0 : 0.0f;
        wgt[l][s][2] = (vx0 && vy1) ? wx0 * wy1 : 0.0f;
        wgt[l][s][3] = (vx1 && vy1) ? wx1 * wy1 : 0.0f;
        cx0s[l][s] = x0; cy0s[l][s] = y0;
    }
    __syncthreads();

    __hip_bfloat16* orow = fsout + (size_t)bp * 2688;
    for (int idx = tid; idx < SS * CADJ; idx += 256) {
        const int s = idx / CADJ, k = idx % CADJ;
        float acc = 0.0f;
#pragma unroll
        for (int l = 0; l < 3; ++l) {
            const int Hl = Hs[l], Wl = Wsz[l];
            const int x0 = cx0s[l][s], y0 = cy0s[l][s];
            const int xc0 = min(max(x0, 0), Wl - 1);
            const int xc1 = min(max(x0 + 1, 0), Wl - 1);
            const int yc0 = min(max(y0, 0), Hl - 1);
            const int yc1 = min(max(y0 + 1, 0), Hl - 1);
            const float* F = Fb[l];
            float v = wgt[l][s][0] * F[((size_t)yc0 * Wl + xc0) * CADJ + k]
                    + wgt[l][s][1] * F[((size_t)yc0 * Wl + xc1) * CADJ + k]
                    + wgt[l][s][2] * F[((size_t)yc1 * Wl + xc0) * CADJ + k]
                    + wgt[l][s][3] * F[((size_t)yc1 * Wl + xc1) * CADJ + k];
            acc = fmaf(zw[l][s], v, acc);
        }
        orow[(s / 9) * 672 + (s % 9) * 72 + k] = to_bf16(acc);
    }
    if (tid < 96) {
        const int g = tid / 24, t = tid % 24;
        orow[g * 672 + 648 + t] = to_bf16(0.0f);
    }
}

// ---- bf16 MFMA GEMM, 128x128 tile, global_load_lds staging (linear LDS) ----
// grid = (N/128, M/128, nz); 256 threads = 4 waves 2x2, each wave 64x64 out
__global__ __launch_bounds__(256) void k_bgemm(
    const __hip_bfloat16* __restrict__ A, int lda, long sAz,
    const __hip_bfloat16* __restrict__ W, int ldw, long sWz,
    const float* __restrict__ bias, int sBz,
    const __hip_bfloat16* __restrict__ Res, int ldres,
    __hip_bfloat16* __restrict__ C, int ldc, int sCz,
    int K, int relu)
{
    __shared__ __hip_bfloat16 As[128][32];   // linear: rows 64B (global_load_lds dest)
    __shared__ __hip_bfloat16 Bs[128][32];
    const int tid = threadIdx.x;
    const int lane = tid & 63, w = tid >> 6;
    const int wr = w >> 1, wc = w & 1;
    const int row16 = lane & 15, kg = lane >> 4;
    const int z = blockIdx.z;
    const int m0 = blockIdx.y * 128, n0 = blockIdx.x * 128;
    const __hip_bfloat16* Ab = A + (size_t)z * sAz;
    const __hip_bfloat16* Wb = W + (size_t)z * sWz;
    const int gr = lane >> 2;          // row within 16-row chunk
    const int gc = (lane & 3) * 8;     // col (bf16)

    f32x4 acc[4][4];
#pragma unroll
    for (int i = 0; i < 4; ++i)
#pragma unroll
        for (int j = 0; j < 4; ++j) acc[i][j] = (f32x4){0.f, 0.f, 0.f, 0.f};

    for (int k0 = 0; k0 < K; k0 += 32) {
        __syncthreads();
#pragma unroll
        for (int c = 0; c < 2; ++c) {
            const int r = w * 32 + c * 16;
            __builtin_amdgcn_global_load_lds(
                (gas_t)(Ab + (size_t)(m0 + r + gr) * lda + k0 + gc),
                (las_t)&As[r][0], 16, 0, 0);
            __builtin_amdgcn_global_load_lds(
                (gas_t)(Wb + (size_t)(n0 + r + gr) * ldw + k0 + gc),
                (las_t)&Bs[r][0], 16, 0, 0);
        }
        __syncthreads();
        bf16x8 af[4], bfr[4];
#pragma unroll
        for (int i = 0; i < 4; ++i) af[i]  = *(const bf16x8*)&As[wr * 64 + i * 16 + row16][kg * 8];
#pragma unroll
        for (int j = 0; j < 4; ++j) bfr[j] = *(const bf16x8*)&Bs[wc * 64 + j * 16 + row16][kg * 8];
#pragma unroll
        for (int i = 0; i < 4; ++i)
#pragma unroll
            for (int j = 0; j < 4; ++j)
                acc[i][j] = MFMA_BF16(af[i], bfr[j], acc[i][j], 0, 0, 0);
    }

    const float* bz = bias + (size_t)z * sBz;
    __hip_bfloat16* Cz = C + (size_t)z * sCz;
#pragma unroll
    for (int i = 0; i < 4; ++i) {
#pragma unroll
        for (int r = 0; r < 4; ++r) {
            const int row = m0 + wr * 64 + i * 16 + kg * 4 + r;
#pragma unroll
            for (int j = 0; j < 4; ++j) {
                const int col = n0 + wc * 64 + j * 16 + row16;
                float v = acc[i][j][r] + bz[col];
                if (Res) v += bf2f(Res[(size_t)row * ldres + col]);
                if (relu) v = fmaxf(v, 0.0f);
                Cz[(size_t)row * ldc + col] = to_bf16(v);
            }
        }
    }
}

// ---- V transpose: qkv V-part -> Vt[bg][128 d][768 keys] ----
__global__ __launch_bounds__(256) void k_vt(
    const __hip_bfloat16* __restrict__ qkv, __hip_bfloat16* __restrict__ Vt)
{
    const int kt = blockIdx.x;   // 12 tiles of 64 keys
    const int bg = blockIdx.y;   // 32
    const int b = bg >> 2, g = bg & 3;
    const int tid = threadIdx.x;
    __shared__ unsigned short Vs[64][130];   // padded odd-dword rows

    const __hip_bfloat16* src = qkv + (size_t)(b * PP + kt * 64) * 1536 + 1024 + g * 128;
    for (int i = tid; i < 1024; i += 256) {
        const int row = i >> 4, ch = i & 15;
        *(bf16x8*)&Vs[row][ch * 8] = *(const bf16x8*)(src + (size_t)row * 1536 + ch * 8);
    }
    __syncthreads();
    __hip_bfloat16* dst = Vt + (size_t)bg * 128 * 768 + kt * 64;
    for (int i = tid; i < 1024; i += 256) {
        const int d = i >> 3, kc = i & 7;
        bf16x8 pk;
#pragma unroll
        for (int j = 0; j < 8; ++j) pk[j] = (short)Vs[kc * 8 + j][d];
        *(bf16x8*)(dst + (size_t)d * 768 + kc * 8) = pk;
    }
}

// ---- flash attention v2: 64-key tiles, pre-transposed V, reg-prefetch, defer-max ----
// grid: 384 = 8 xcd * (4 bg * 12 qt); 256 threads (4 waves x 16 q-rows)
__global__ __launch_bounds__(256) void k_fattn(
    const __hip_bfloat16* __restrict__ qkv, const __hip_bfloat16* __restrict__ Vt,
    __hip_bfloat16* __restrict__ Out)
{
    const int id = blockIdx.x;
    const int xcd = id & 7, rest = id >> 3;
    const int bg = xcd * 4 + rest / 12;
    const int qt = rest % 12;
    const int b = bg >> 2, g = bg & 3;
    const int tid = threadIdx.x, lane = tid & 63, w = tid >> 6;
    const int row16 = lane & 15, kg = lane >> 4;
    const int q0 = qt * 64;

    __shared__ __hip_bfloat16 Klds[64][136];   // 64 keys x 128, padded
    __shared__ __hip_bfloat16 Vtl[128][72];    // 128 d x 64 keys, padded
    __shared__ __hip_bfloat16 Plds[4][16][72]; // per-wave P (16 q x 64 keys)

    const size_t rowQ = (size_t)(b * PP + q0 + w * 16 + row16) * 1536 + g * 128;
    bf16x8 aq[4];
#pragma unroll
    for (int t = 0; t < 4; ++t)
        aq[t] = *(const bf16x8*)(qkv + rowQ + t * 32 + kg * 8);

    f32x4 oacc[8];
#pragma unroll
    for (int dt = 0; dt < 8; ++dt) oacc[dt] = (f32x4){0.f, 0.f, 0.f, 0.f};
    float mrow[4] = {-3.0e38f, -3.0e38f, -3.0e38f, -3.0e38f};
    float lrow[4] = {0.f, 0.f, 0.f, 0.f};

    const __hip_bfloat16* Kb = qkv + (size_t)(b * PP) * 1536 + 512 + g * 128;
    const __hip_bfloat16* Vb = Vt + (size_t)bg * 128 * 768;
    const float sc = 0.08838834764831845f;

    const int krow = tid >> 2, kch = tid & 3;   // K: 4 thr/row, 64B each
    const int vrow = tid >> 1, vch = tid & 1;   // Vt: 2 thr/row, 64B each
    bf16x8 kreg[4], vreg[4];

    {   // prefetch tile 0
        const __hip_bfloat16* s1 = Kb + (size_t)krow * 1536 + kch * 32;
        const __hip_bfloat16* s2 = Vb + (size_t)vrow * 768 + vch * 32;
#pragma unroll
        for (int j = 0; j < 4; ++j) { kreg[j] = *(const bf16x8*)(s1 + j * 8);
                                      vreg[j] = *(const bf16x8*)(s2 + j * 8); }
    }

    for (int kt = 0; kt < 12; ++kt) {
        __syncthreads();   // previous compute done reading LDS
#pragma unroll
        for (int j = 0; j < 4; ++j) {
            *(bf16x8*)&Klds[krow][kch * 32 + j * 8] = kreg[j];
            *(bf16x8*)&Vtl[vrow][vch * 32 + j * 8] = vreg[j];
        }
        __syncthreads();
        if (kt < 11) {   // prefetch next tile (overlaps compute below)
            const __hip_bfloat16* s1 = Kb + (size_t)((kt + 1) * 64 + krow) * 1536 + kch * 32;
            const __hip_bfloat16* s2 = Vb + (size_t)vrow * 768 + (kt + 1) * 64 + vch * 32;
#pragma unroll
            for (int j = 0; j < 4; ++j) { kreg[j] = *(const bf16x8*)(s1 + j * 8);
                                          vreg[j] = *(const bf16x8*)(s2 + j * 8); }
        }

        // S = Q @ K^T : 4 sub-tiles of 16 keys
        f32x4 s4[4];
#pragma unroll
        for (int st = 0; st < 4; ++st) s4[st] = (f32x4){0.f, 0.f, 0.f, 0.f};
        __builtin_amdgcn_s_setprio(1);
#pragma unroll
        for (int st = 0; st < 4; ++st)
#pragma unroll
            for (int t = 0; t < 4; ++t)
                s4[st] = MFMA_BF16(aq[t],
                    *(const bf16x8*)&Klds[st * 16 + row16][t * 32 + kg * 8], s4[st], 0, 0, 0);
        __builtin_amdgcn_s_setprio(0);

        // online softmax with defer-max (THR=8)
        float pm[4];
#pragma unroll
        for (int r = 0; r < 4; ++r) {
            float m0 = fmaxf(fmaxf(s4[0][r], s4[1][r]), fmaxf(s4[2][r], s4[3][r])) * sc;
            m0 = fmaxf(m0, __shfl_xor(m0, 1));
            m0 = fmaxf(m0, __shfl_xor(m0, 2));
            m0 = fmaxf(m0, __shfl_xor(m0, 4));
            m0 = fmaxf(m0, __shfl_xor(m0, 8));
            pm[r] = m0;
        }
        const float need = fmaxf(fmaxf(pm[0] - mrow[0], pm[1] - mrow[1]),
                                 fmaxf(pm[2] - mrow[2], pm[3] - mrow[3]));
        if (!__all(need <= 8.0f)) {
#pragma unroll
            for (int r = 0; r < 4; ++r) {
                const float mn = fmaxf(mrow[r], pm[r]);
                const float so = __expf(mrow[r] - mn);
                lrow[r] *= so;
#pragma unroll
                for (int dt = 0; dt < 8; ++dt) oacc[dt][r] *= so;
                mrow[r] = mn;
            }
        }
#pragma unroll
        for (int r = 0; r < 4; ++r) {
            float rs = 0.f;
#pragma unroll
            for (int st = 0; st < 4; ++st) {
                const float p = __expf(s4[st][r] * sc - mrow[r]);
                rs += p;
                Plds[w][kg * 4 + r][st * 16 + row16] = to_bf16(p);
            }
            rs += __shfl_xor(rs, 1);
            rs += __shfl_xor(rs, 2);
            rs += __shfl_xor(rs, 4);
            rs += __shfl_xor(rs, 8);
            lrow[r] += rs;
        }

        // O += P @ V  (two 32-key slices)
        __builtin_amdgcn_s_setprio(1);
#pragma unroll
        for (int ks = 0; ks < 2; ++ks) {
            bf16x8 ap = *(const bf16x8*)&Plds[w][row16][ks * 32 + kg * 8];
#pragma unroll
            for (int dt = 0; dt < 8; ++dt)
                oacc[dt] = MFMA_BF16(ap,
                    *(const bf16x8*)&Vtl[dt * 16 + row16][ks * 32 + kg * 8], oacc[dt], 0, 0, 0);
        }
        __builtin_amdgcn_s_setprio(0);
    }

    const size_t obase = (size_t)(b * PP + q0 + w * 16 + kg * 4) * DD + g * 128;
#pragma unroll
    for (int r = 0; r < 4; ++r) {
        const float inv = 1.0f / lrow[r];
#pragma unroll
        for (int dt = 0; dt < 8; ++dt)
            Out[obase + (size_t)r * DD + dt * 16 + row16] = to_bf16(oacc[dt][r] * inv);
    }
}

// ---- final heads ----
__global__ __launch_bounds__(64) void k_head(
    const __hip_bfloat16* __restrict__ clsreg, const __hip_bfloat16* __restrict__ ph,
    const float* __restrict__ cls_w2, const float* __restrict__ cls_b2,
    const float* __restrict__ p_w2, const float* __restrict__ p_b2,
    const float* __restrict__ b_scale, const float* __restrict__ b_bias,
    float* __restrict__ outp)
{
    const int bp = blockIdx.x;
    const int lane = threadIdx.x;
    const __hip_bfloat16* hr = clsreg + (size_t)bp * 1024;
    float a0 = 0.0f, a1 = 0.0f;
    for (int i = lane; i < DD; i += 64) {
        float h = bf2f(hr[i]);
        a0 = fmaf(h, cls_w2[i], a0);
        a1 = fmaf(h, cls_w2[DD + i], a1);
    }
    const __hip_bfloat16* pr = ph + (size_t)bp * 1024;
    float c0 = 0.0f, c1 = 0.0f, c2 = 0.0f, c3 = 0.0f;
    for (int i = lane; i < 1024; i += 64) {
        float h = bf2f(pr[i]);
        c0 = fmaf(h, p_w2[i], c0);
        c1 = fmaf(h, p_w2[1024 + i], c1);
        c2 = fmaf(h, p_w2[2048 + i], c2);
        c3 = fmaf(h, p_w2[3072 + i], c3);
    }
#pragma unroll
    for (int off = 32; off > 0; off >>= 1) {
        a0 += __shfl_down(a0, off);
        a1 += __shfl_down(a1, off);
        c0 += __shfl_down(c0, off);
        c1 += __shfl_down(c1, off);
        c2 += __shfl_down(c2, off);
        c3 += __shfl_down(c3, off);
    }
    a0 = __shfl(a0, 0); a1 = __shfl(a1, 0);
    c0 = __shfl(c0, 0); c1 = __shfl(c1, 0);
    c2 = __shfl(c2, 0); c3 = __shfl(c3, 0);
    const float k0 = c0 + p_b2[0];
    const float k1 = c1 + p_b2[1];
    const float scv = b_scale[0], biv = b_bias[0];
    const float k2 = (c2 + p_b2[2]) * scv + biv;
    const float k3 = (c3 + p_b2[3]) * scv + biv;
    float* orow = outp + (size_t)bp * 78;
    if (lane == 0) {
        orow[0] = a0 + cls_b2[0];
        orow[1] = a1 + cls_b2[1];
        orow[2] = k0; orow[3] = k1; orow[4] = k2; orow[5] = k3;
    }
    for (int o = lane; o < 72; o += 64) {
        float ys = (float)o / 71.0f;
        float tv = k0 + ys * (k1 + ys * (k2 + ys * k3));
        orow[6 + o] = 1.0f / (1.0f + expf(-tv));
    }
}

extern "C" void kernel_launch(void* const* d_in, const int* in_sizes, int n_in,
                              void* d_out, int out_size, void* d_ws, size_t ws_size,
                              hipStream_t stream)
{
    const float* feat0  = (const float*)d_in[0];
    const float* feat1  = (const float*)d_in[1];
    const float* feat2  = (const float*)d_in[2];
    const float* priors = (const float*)d_in[3];
    const float* ca_w   = (const float*)d_in[4];
    const float* ca_b   = (const float*)d_in[5];
    const float* off_w  = (const float*)d_in[6];
    const float* off_b  = (const float*)d_in[7];
    const float* dp_w   = (const float*)d_in[8];
    const float* dp_b   = (const float*)d_in[9];
    const float* z_emb  = (const float*)d_in[10];
    const float* gf_w   = (const float*)d_in[11];
    const float* gf_b   = (const float*)d_in[12];
    const float* wq     = (const float*)d_in[13];
    const float* bq     = (const float*)d_in[14];
    const float* wk     = (const float*)d_in[15];
    const float* bk     = (const float*)d_in[16];
    const float* wv     = (const float*)d_in[17];
    const float* bv     = (const float*)d_in[18];
    const float* wo     = (const float*)d_in[19];
    const float* bo     = (const float*)d_in[20];
    const float* cf_w1  = (const float*)d_in[21];
    const float* cf_b1  = (const float*)d_in[22];
    const float* cf_w2  = (const float*)d_in[23];
    const float* cf_b2  = (const float*)d_in[24];
    const float* cls_w1 = (const float*)d_in[25];
    const float* cls_b1 = (const float*)d_in[26];
    const float* cls_w2 = (const float*)d_in[27];
    const float* cls_b2 = (const float*)d_in[28];
    const float* reg_w1 = (const float*)d_in[29];
    const float* reg_b1 = (const float*)d_in[30];
    const float* p_w1   = (const float*)d_in[31];
    const float* p_b1   = (const float*)d_in[32];
    const float* p_w2   = (const float*)d_in[33];
    const float* p_b2   = (const float*)d_in[34];
    const float* b_scale = (const float*)d_in[35];
    const float* b_bias  = (const float*)d_in[36];
    float* out = (float*)d_out;

    char* wsb = (char*)d_ws;
    __hip_bfloat16* feature = (__hip_bfloat16*)(wsb + 0);          // [6144][512]
    __hip_bfloat16* qkvb    = (__hip_bfloat16*)(wsb + 6291456);    // [6144][1536]
    __hip_bfloat16* tb      = (__hip_bfloat16*)(wsb + 25165824);   // [6144][512]
    __hip_bfloat16* vtb     = (__hip_bfloat16*)(wsb + 31457280);   // Vt [32][128][768]
    __hip_bfloat16* rb      = (__hip_bfloat16*)(wsb + 31457280);   // wo out (after fattn)
    __hip_bfloat16* hb      = (__hip_bfloat16*)(wsb + 37748736);   // [6144][1024]
    __hip_bfloat16* f2      = (__hip_bfloat16*)(wsb + 50331648);   // [6144][512]
    __hip_bfloat16* clsregb = (__hip_bfloat16*)(wsb + 56623104);   // [6144][1024]
    __hip_bfloat16* phb     = (__hip_bfloat16*)(wsb + 69206016);   // [6144][1024]
    float* of1 = (float*)(wsb + 6291456);
    float* of2 = (float*)(wsb + 8595456);
    float* fe1 = (float*)(wsb + 9171456);
    float* fe2 = (float*)(wsb + 11475456);
    __hip_bfloat16* fsb = (__hip_bfloat16*)(wsb + 25165824);       // smp [6144][2688]
    float* fe0 = (float*)(wsb + 58195968);
    float* of0 = (float*)(wsb + 67411968);
    __hip_bfloat16* wqkv_bf   = (__hip_bfloat16*)(wsb + 81788928); // [1536][512]
    __hip_bfloat16* wo_bf     = (__hip_bfloat16*)(wsb + 83361792);
    __hip_bfloat16* cf1_bf    = (__hip_bfloat16*)(wsb + 83886080);
    __hip_bfloat16* cf2_bf    = (__hip_bfloat16*)(wsb + 84934656);
    __hip_bfloat16* clsreg_bf = (__hip_bfloat16*)(wsb + 85983232); // [1024][512]
    __hip_bfloat16* p1_bf     = (__hip_bfloat16*)(wsb + 87031808);
    __hip_bfloat16* gfw2_bf   = (__hip_bfloat16*)(wsb + 88080384); // [512][672]
    float* bqkv    = (float*)(wsb + 88768512);
    float* bclsreg = (float*)(wsb + 88774656);
    float* b2      = (float*)(wsb + 88778752);

    k_wcast<<<(3148288 + 255) / 256, 256, 0, stream>>>(
        wq, wk, wv, wo, cf_w1, cf_w2, cls_w1, reg_w1, p_w1, bq, bk, bv, cls_b1, reg_b1,
        wqkv_bf, wo_bf, cf1_bf, cf2_bf, clsreg_bf, p1_bf, bqkv, bclsreg);
    k_wfuse<<<512, 256, 0, stream>>>(gf_w, dp_w, gfw2_bf);
    k_wfuseb<<<2, 256, 0, stream>>>(gf_w, dp_b, gf_b, b2);

    k_adjoff<<<dim3(63, BB), 256, 0, stream>>>(feat0, ca_w, ca_b, off_w, off_b,
                                               fe0, of0, H0 * W0, 1);
    k_adjoff<<<dim3(16, BB), 256, 0, stream>>>(feat1, ca_w, ca_b, off_w, off_b,
                                               fe1, nullptr, H1 * W1, 0);
    k_adjoff<<<dim3(4, BB), 256, 0, stream>>>(feat2, ca_w, ca_b, off_w, off_b,
                                              fe2, nullptr, H2 * W2, 0);
    k_resize<<<(BB * H1 * W1 * CADJ + 255) / 256, 256, 0, stream>>>(of0, of1, H1, W1);
    k_resize<<<(BB * H2 * W2 * CADJ + 255) / 256, 256, 0, stream>>>(of0, of2, H2, W2);
    k_sample<<<BB * PP, 256, 0, stream>>>(priors, fe0, fe1, fe2, of0, of1, of2, z_emb, fsb);

    const int M = BB * PP;
    k_bgemm<<<dim3(1, M / 128, 4), 256, 0, stream>>>(
        fsb, 2688, 672, gfw2_bf, 672, 128 * 672, b2, 128,
        nullptr, 0, feature, DD, 128, 672, 0);
    k_bgemm<<<dim3(12, M / 128, 1), 256, 0, stream>>>(
        feature, DD, 0, wqkv_bf, DD, 0, bqkv, 0,
        nullptr, 0, qkvb, 1536, 0, DD, 0);
    k_vt<<<dim3(12, 32), 256, 0, stream>>>(qkvb, vtb);
    k_fattn<<<384, 256, 0, stream>>>(qkvb, vtb, tb);
    k_bgemm<<<dim3(4, M / 128, 1), 256, 0, stream>>>(
        tb, DD, 0, wo_bf, DD, 0, bo, 0, nullptr, 0, rb, DD, 0, DD, 0);
    k_bgemm<<<dim3(8, M / 128, 1), 256, 0, stream>>>(
        rb, DD, 0, cf1_bf, DD, 0, cf_b1, 0, nullptr, 0, hb, 1024, 0, DD, 1);
    k_bgemm<<<dim3(4, M / 128, 1), 256, 0, stream>>>(
        hb, 1024, 0, cf2_bf, 1024, 0, cf_b2, 0, feature, DD, f2, DD, 0, 1024, 0);
    k_bgemm<<<dim3(8, M / 128, 1), 256, 0, stream>>>(
        f2, DD, 0, clsreg_bf, DD, 0, bclsreg, 0, nullptr, 0, clsregb, 1024, 0, DD, 1);
    k_bgemm<<<dim3(8, M / 128, 1), 256, 0, stream>>>(
        clsregb + 512, 1024, 0, p1_bf, DD, 0, p_b1, 0, nullptr, 0, phb, 1024, 0, DD, 1);

    k_head<<<M, 64, 0, stream>>>(clsregb, phb, cls_w2, cls_b2, p_w2, p_b2, b_scale, b_bias, out);
}

// Round 8
// 372.086 us; speedup vs baseline: 8.0288x; 1.0089x over previous
//
#include <hip/hip_runtime.h>
#include <hip/hip_bf16.h>
#include <math.h>

#define BB 8
#define PP 768
#define NPRI 76
#define SS 36
#define CIN 64
#define CADJ 72
#define DD 512

#define H0 40
#define W0 100
#define H1 20
#define W1 50
#define H2 10
#define W2 25

typedef __attribute__((ext_vector_type(8))) short bf16x8;
typedef __attribute__((ext_vector_type(4))) float f32x4;
#define MFMA_BF16 __builtin_amdgcn_mfma_f32_16x16x32_bf16

typedef const __attribute__((address_space(1))) unsigned int* gas_t;
typedef __attribute__((address_space(3))) unsigned int* las_t;

__device__ __forceinline__ __hip_bfloat16 to_bf16(float v) { return __float2bfloat16(v); }
__device__ __forceinline__ float bf2f(__hip_bfloat16 v) { return __bfloat162float(v); }

// ---- bilinear sample, zeros outside ----
__device__ __forceinline__ float bsample(const float* __restrict__ img, int H, int W,
                                         int C, int c, float x, float y)
{
    float x0f = floorf(x), y0f = floorf(y);
    int x0 = (int)x0f, y0 = (int)y0f;
    float wx1 = x - x0f, wy1 = y - y0f;
    float wx0 = 1.0f - wx1, wy0 = 1.0f - wy1;
    int xc0 = min(max(x0, 0), W - 1);
    int xc1 = min(max(x0 + 1, 0), W - 1);
    int yc0 = min(max(y0, 0), H - 1);
    int yc1 = min(max(y0 + 1, 0), H - 1);
    bool vx0 = (x0 >= 0) && (x0 < W);
    bool vx1 = (x0 + 1 >= 0) && (x0 + 1 < W);
    bool vy0 = (y0 >= 0) && (y0 < H);
    bool vy1 = (y0 + 1 >= 0) && (y0 + 1 < H);
    float w00 = (vx0 && vy0) ? wx0 * wy0 : 0.0f;
    float w01 = (vx1 && vy0) ? wx1 * wy0 : 0.0f;
    float w10 = (vx0 && vy1) ? wx0 * wy1 : 0.0f;
    float w11 = (vx1 && vy1) ? wx1 * wy1 : 0.0f;
    return w00 * img[((size_t)yc0 * W + xc0) * C + c]
         + w01 * img[((size_t)yc0 * W + xc1) * C + c]
         + w10 * img[((size_t)yc1 * W + xc0) * C + c]
         + w11 * img[((size_t)yc1 * W + xc1) * C + c];
}

// ---- weight cast f32 -> bf16 (+ bias concats) ----
__global__ __launch_bounds__(256) void k_wcast(
    const float* __restrict__ wq, const float* __restrict__ wk, const float* __restrict__ wv,
    const float* __restrict__ wo, const float* __restrict__ cf_w1, const float* __restrict__ cf_w2,
    const float* __restrict__ cls_w1, const float* __restrict__ reg_w1, const float* __restrict__ p_w1,
    const float* __restrict__ bq, const float* __restrict__ bk, const float* __restrict__ bv,
    const float* __restrict__ cls_b1, const float* __restrict__ reg_b1,
    __hip_bfloat16* __restrict__ wqkv, __hip_bfloat16* __restrict__ wo_bf,
    __hip_bfloat16* __restrict__ cf1_bf, __hip_bfloat16* __restrict__ cf2_bf,
    __hip_bfloat16* __restrict__ clsreg_bf, __hip_bfloat16* __restrict__ p1_bf,
    float* __restrict__ bqkv, float* __restrict__ bclsreg)
{
    long i = (long)blockIdx.x * 256 + threadIdx.x;
    if (i < 262144) { wqkv[i] = to_bf16(wq[i]); return; }
    i -= 262144;
    if (i < 262144) { wqkv[262144 + i] = to_bf16(wk[i]); return; }
    i -= 262144;
    if (i < 262144) { wqkv[524288 + i] = to_bf16(wv[i]); return; }
    i -= 262144;
    if (i < 262144) { wo_bf[i] = to_bf16(wo[i]); return; }
    i -= 262144;
    if (i < 524288) { cf1_bf[i] = to_bf16(cf_w1[i]); return; }
    i -= 524288;
    if (i < 524288) { cf2_bf[i] = to_bf16(cf_w2[i]); return; }
    i -= 524288;
    if (i < 262144) { clsreg_bf[i] = to_bf16(cls_w1[i]); return; }
    i -= 262144;
    if (i < 262144) { clsreg_bf[262144 + i] = to_bf16(reg_w1[i]); return; }
    i -= 262144;
    if (i < 524288) { p1_bf[i] = to_bf16(p_w1[i]); return; }
    i -= 524288;
    if (i < 512) { bqkv[i] = bq[i]; return; }
    if (i < 1024) { bqkv[i] = bk[i - 512]; return; }
    if (i < 1536) { bqkv[i] = bv[i - 1024]; return; }
    i -= 1536;
    if (i < 512) { bclsreg[i] = cls_b1[i]; return; }
    if (i < 1024) { bclsreg[i] = reg_b1[i - 512]; return; }
}

// ---- fuse dp into gf: Wout[o][i*72+m] = sum_k gf_w[o][i*72+k] * dp_w[k][m]; pad to 672 ----
__global__ __launch_bounds__(256) void k_wfuse(
    const float* __restrict__ gf_w, const float* __restrict__ dp_w,
    __hip_bfloat16* __restrict__ Wout)
{
    const int o = blockIdx.x;
    const int tid = threadIdx.x;
    __shared__ float dpS[CADJ][CADJ + 1];
    __shared__ float gfr[648];
    for (int i = tid; i < CADJ * CADJ; i += 256) dpS[i / CADJ][i % CADJ] = dp_w[i];
    for (int i = tid; i < 648; i += 256) gfr[i] = gf_w[(size_t)o * 648 + i];
    __syncthreads();
    for (int t = tid; t < 672; t += 256) {
        float acc = 0.0f;
        if (t < 648) {
            const int i = t / 72, m = t % 72;
            const float* gr = gfr + i * 72;
#pragma unroll 8
            for (int k = 0; k < 72; ++k) acc = fmaf(gr[k], dpS[k][m], acc);
        }
        Wout[(size_t)o * 672 + t] = to_bf16(acc);
    }
}

// ---- fused bias: b2[o] = gf_b[o] + sum gf_w[o][j] * dp_b[j%72] ----
__global__ __launch_bounds__(256) void k_wfuseb(
    const float* __restrict__ gf_w, const float* __restrict__ dp_b,
    const float* __restrict__ gf_b, float* __restrict__ b2)
{
    const int o = blockIdx.x * 256 + threadIdx.x;
    if (o >= DD) return;
    const float* gr = gf_w + (size_t)o * 648;
    float acc = gf_b[o];
    for (int j = 0; j < 648; ++j) acc = fmaf(gr[j], dp_b[j % 72], acc);
    b2[o] = acc;
}

// ---- fused tiled channel-adjust (+ optional offset head), 64 pixels/block ----
__global__ __launch_bounds__(256) void k_adjoff(
    const float* __restrict__ f, const float* __restrict__ caw, const float* __restrict__ cab,
    const float* __restrict__ offw, const float* __restrict__ offb,
    float* __restrict__ feout, float* __restrict__ offout, int HW, int do_off)
{
    __shared__ float inS[64][65];
    __shared__ float wS[72][64];
    __shared__ float owS[72][73];
    __shared__ float feS[64][73];
    __shared__ float cabS[72], obS[72];

    const int tid = threadIdx.x;
    const int b = blockIdx.y;
    const int pix0 = blockIdx.x * 64;
    const int cnt = min(64, HW - pix0);
    const int px = tid & 63, og = tid >> 6, o0 = og * 18;

    const float* fb = f + (size_t)b * CIN * HW + pix0;
    for (int i = tid; i < 72 * 64; i += 256) wS[i >> 6][i & 63] = caw[i];
    if (do_off)
        for (int i = tid; i < 72 * 72; i += 256) owS[i / 72][i % 72] = offw[i];
    if (tid < 72) { cabS[tid] = cab[tid]; obS[tid] = do_off ? offb[tid] : 0.f; }
    for (int i = tid; i < 64 * 64; i += 256) {
        const int c = i >> 6, p = i & 63;
        inS[c][p] = (p < cnt) ? fb[(size_t)c * HW + p] : 0.f;
    }
    __syncthreads();

    float acc[18];
#pragma unroll
    for (int j = 0; j < 18; ++j) acc[j] = cabS[o0 + j];
#pragma unroll 4
    for (int c = 0; c < 64; ++c) {
        const float v = inS[c][px];
#pragma unroll
        for (int j = 0; j < 18; ++j) acc[j] = fmaf(v, wS[o0 + j][c], acc[j]);
    }
#pragma unroll
    for (int j = 0; j < 18; ++j) feS[px][o0 + j] = acc[j];
    __syncthreads();

    float* feg = feout + ((size_t)b * HW + pix0) * CADJ;
    for (int i = tid; i < cnt * CADJ; i += 256) feg[i] = feS[i / CADJ][i % CADJ];

    if (!do_off) return;

    float acc2[18];
#pragma unroll
    for (int j = 0; j < 18; ++j) acc2[j] = obS[o0 + j];
#pragma unroll 4
    for (int c = 0; c < 72; ++c) {
        const float v = feS[px][c];
#pragma unroll
        for (int j = 0; j < 18; ++j) acc2[j] = fmaf(v, owS[o0 + j][c], acc2[j]);
    }
    __syncthreads();
#pragma unroll
    for (int j = 0; j < 18; ++j) feS[px][o0 + j] = acc2[j];
    __syncthreads();
    float* ofg = offout + ((size_t)b * HW + pix0) * CADJ;
    for (int i = tid; i < cnt * CADJ; i += 256) ofg[i] = feS[i / CADJ][i % CADJ];
}

// ---- align-corners resize ----
__global__ __launch_bounds__(256) void k_resize(const float* __restrict__ src,
    float* __restrict__ dst, int Ht, int Wt)
{
    int idx = blockIdx.x * 256 + threadIdx.x;
    int total = BB * Ht * Wt * CADJ;
    if (idx >= total) return;
    int c = idx % CADJ;
    int j = (idx / CADJ) % Wt;
    int i = (idx / (CADJ * Wt)) % Ht;
    int b = idx / (CADJ * Wt * Ht);
    float sy = fminf((float)i * ((float)(H0 - 1) / (float)(Ht - 1)), (float)(H0 - 1));
    float sx = fminf((float)j * ((float)(W0 - 1) / (float)(Wt - 1)), (float)(W0 - 1));
    dst[idx] = bsample(src + (size_t)b * H0 * W0 * CADJ, H0, W0, CADJ, c, sx, sy);
}

// ---- sampling + z-fuse, v2: precomputed corner bases + zw-folded weights,
//      float2 channel pairs, XCD-swizzled blocks. smp bf16 [6144][4*672] ----
__global__ __launch_bounds__(256) void k_sample(
    const float* __restrict__ priors,
    const float* __restrict__ feats0, const float* __restrict__ feats1, const float* __restrict__ feats2,
    const float* __restrict__ offs0,  const float* __restrict__ offs1,  const float* __restrict__ offs2,
    const float* __restrict__ z_emb,
    __hip_bfloat16* __restrict__ fsout)
{
    const int bid = blockIdx.x;
    const int bp = (bid & 7) * 768 + (bid >> 3);   // XCD x owns batch x (bid%8 -> XCD)
    const int b = bp / PP;
    const int tid = threadIdx.x;

    __shared__ int   ib[3][SS][4];    // clamped corner element-offsets
    __shared__ float wz[3][SS][4];    // zw-folded bilinear weights

    const int Hs[3] = {H0, H1, H2};
    const int Wsz[3] = {W0, W1, W2};
    const float* Fb[3] = { feats0 + (size_t)b * H0 * W0 * CADJ,
                           feats1 + (size_t)b * H1 * W1 * CADJ,
                           feats2 + (size_t)b * H2 * W2 * CADJ };
    const float* Ob[3] = { offs0 + (size_t)b * H0 * W0 * CADJ,
                           offs1 + (size_t)b * H1 * W1 * CADJ,
                           offs2 + (size_t)b * H2 * W2 * CADJ };

    if (tid < 3 * SS) {
        const int s = tid % SS;
        const int l = tid / SS;
        const float t = (float)(35 - s) / 35.0f;
        const int m = (int)floorf(t * 71.0f);
        const float pfx = priors[(size_t)bp * NPRI + 4 + m];
        const float gxv = fminf(fmaxf(pfx / 71.0f, 0.0f), 1.0f) * 2.0f - 1.0f;
        const float gyv = (1.0f - (float)m / 71.0f) * 2.0f - 1.0f;
        const float z = z_emb[s];
        const float e0 = expf(-0.5f * z * z);
        const float e1 = expf(-0.5f * (z - 1.0f) * (z - 1.0f));
        const float e2 = expf(-0.5f * (z - 2.0f) * (z - 2.0f));
        const float inv = 1.0f / (e0 + e1 + e2);
        const float ev[3] = {e0, e1, e2};
        const float zwl = ev[l] * inv;

        const int Hl = Hs[l], Wl = Wsz[l];
        const float px = (gxv + 1.0f) * 0.5f * (float)(Wl - 1);
        const float py = (gyv + 1.0f) * 0.5f * (float)(Hl - 1);
        const float dy = bsample(Ob[l], Hl, Wl, CADJ, 2 * s,     px, py);
        const float dx = bsample(Ob[l], Hl, Wl, CADJ, 2 * s + 1, px, py);
        const float sx = px + dx, sy = py + dy;
        const float x0f = floorf(sx), y0f = floorf(sy);
        const int x0 = (int)x0f, y0 = (int)y0f;
        const float wx1 = sx - x0f, wy1 = sy - y0f;
        const float wx0 = 1.0f - wx1, wy0 = 1.0f - wy1;
        const bool vx0 = (x0 >= 0) && (x0 < Wl);
        const bool vx1 = (x0 + 1 >= 0) && (x0 + 1 < Wl);
        const bool vy0 = (y0 >= 0) && (y0 < Hl);
        const bool vy1 = (y0 + 1 >= 0) && (y0 + 1 < Hl);
        const int xc0 = min(max(x0, 0), Wl - 1);
        const int xc1 = min(max(x0 + 1, 0), Wl - 1);
        const int yc0 = min(max(y0, 0), Hl - 1);
        const int yc1 = min(max(y0 + 1, 0), Hl - 1);
        wz[l][s][0] = ((vx0 && vy0) ? wx0 * wy0 : 0.0f) * zwl;
        wz[l][s][1] = ((vx1 && vy0) ? wx1 * wy0 : 0.0f) * zwl;
        wz[l][s][2] = ((vx0 && vy1) ? wx0 * wy1 : 0.0f) * zwl;
        wz[l][s][3] = ((vx1 && vy1) ? wx1 * wy1 : 0.0f) * zwl;
        ib[l][s][0] = (yc0 * Wl + xc0) * CADJ;
        ib[l][s][1] = (yc0 * Wl + xc1) * CADJ;
        ib[l][s][2] = (yc1 * Wl + xc0) * CADJ;
        ib[l][s][3] = (yc1 * Wl + xc1) * CADJ;
    }
    __syncthreads();

    __hip_bfloat16* orow = fsout + (size_t)bp * 2688;
    for (int idx = tid; idx < SS * 36; idx += 256) {
        const int s = idx / 36, k2 = (idx % 36) * 2;
        float a0 = 0.0f, a1 = 0.0f;
#pragma unroll
        for (int l = 0; l < 3; ++l) {
            const float* F = Fb[l];
            const int*   ibs = ib[l][s];
            const float* ws  = wz[l][s];
#pragma unroll
            for (int c = 0; c < 4; ++c) {
                const float2 v = *(const float2*)(F + ibs[c] + k2);
                a0 = fmaf(ws[c], v.x, a0);
                a1 = fmaf(ws[c], v.y, a1);
            }
        }
        __hip_bfloat162 pk;
        pk.x = to_bf16(a0);
        pk.y = to_bf16(a1);
        *(__hip_bfloat162*)&orow[(s / 9) * 672 + (s % 9) * 72 + k2] = pk;
    }
    if (tid < 96) {
        const int g = tid / 24, t = tid % 24;
        orow[g * 672 + 648 + t] = to_bf16(0.0f);
    }
}

// ---- bf16 MFMA GEMM, 128x128 tile, global_load_lds staging (linear LDS) ----
__global__ __launch_bounds__(256) void k_bgemm(
    const __hip_bfloat16* __restrict__ A, int lda, long sAz,
    const __hip_bfloat16* __restrict__ W, int ldw, long sWz,
    const float* __restrict__ bias, int sBz,
    const __hip_bfloat16* __restrict__ Res, int ldres,
    __hip_bfloat16* __restrict__ C, int ldc, int sCz,
    int K, int relu)
{
    __shared__ __hip_bfloat16 As[128][32];
    __shared__ __hip_bfloat16 Bs[128][32];
    const int tid = threadIdx.x;
    const int lane = tid & 63, w = tid >> 6;
    const int wr = w >> 1, wc = w & 1;
    const int row16 = lane & 15, kg = lane >> 4;
    const int z = blockIdx.z;
    const int m0 = blockIdx.y * 128, n0 = blockIdx.x * 128;
    const __hip_bfloat16* Ab = A + (size_t)z * sAz;
    const __hip_bfloat16* Wb = W + (size_t)z * sWz;
    const int gr = lane >> 2;
    const int gc = (lane & 3) * 8;

    f32x4 acc[4][4];
#pragma unroll
    for (int i = 0; i < 4; ++i)
#pragma unroll
        for (int j = 0; j < 4; ++j) acc[i][j] = (f32x4){0.f, 0.f, 0.f, 0.f};

    for (int k0 = 0; k0 < K; k0 += 32) {
        __syncthreads();
#pragma unroll
        for (int c = 0; c < 2; ++c) {
            const int r = w * 32 + c * 16;
            __builtin_amdgcn_global_load_lds(
                (gas_t)(Ab + (size_t)(m0 + r + gr) * lda + k0 + gc),
                (las_t)&As[r][0], 16, 0, 0);
            __builtin_amdgcn_global_load_lds(
                (gas_t)(Wb + (size_t)(n0 + r + gr) * ldw + k0 + gc),
                (las_t)&Bs[r][0], 16, 0, 0);
        }
        __syncthreads();
        bf16x8 af[4], bfr[4];
#pragma unroll
        for (int i = 0; i < 4; ++i) af[i]  = *(const bf16x8*)&As[wr * 64 + i * 16 + row16][kg * 8];
#pragma unroll
        for (int j = 0; j < 4; ++j) bfr[j] = *(const bf16x8*)&Bs[wc * 64 + j * 16 + row16][kg * 8];
#pragma unroll
        for (int i = 0; i < 4; ++i)
#pragma unroll
            for (int j = 0; j < 4; ++j)
                acc[i][j] = MFMA_BF16(af[i], bfr[j], acc[i][j], 0, 0, 0);
    }

    const float* bz = bias + (size_t)z * sBz;
    __hip_bfloat16* Cz = C + (size_t)z * sCz;
#pragma unroll
    for (int i = 0; i < 4; ++i) {
#pragma unroll
        for (int r = 0; r < 4; ++r) {
            const int row = m0 + wr * 64 + i * 16 + kg * 4 + r;
#pragma unroll
            for (int j = 0; j < 4; ++j) {
                const int col = n0 + wc * 64 + j * 16 + row16;
                float v = acc[i][j][r] + bz[col];
                if (Res) v += bf2f(Res[(size_t)row * ldres + col]);
                if (relu) v = fmaxf(v, 0.0f);
                Cz[(size_t)row * ldc + col] = to_bf16(v);
            }
        }
    }
}

// ---- V transpose: qkv V-part -> Vt[bg][128 d][768 keys] ----
__global__ __launch_bounds__(256) void k_vt(
    const __hip_bfloat16* __restrict__ qkv, __hip_bfloat16* __restrict__ Vt)
{
    const int kt = blockIdx.x;
    const int bg = blockIdx.y;
    const int b = bg >> 2, g = bg & 3;
    const int tid = threadIdx.x;
    __shared__ unsigned short Vs[64][130];

    const __hip_bfloat16* src = qkv + (size_t)(b * PP + kt * 64) * 1536 + 1024 + g * 128;
    for (int i = tid; i < 1024; i += 256) {
        const int row = i >> 4, ch = i & 15;
        *(bf16x8*)&Vs[row][ch * 8] = *(const bf16x8*)(src + (size_t)row * 1536 + ch * 8);
    }
    __syncthreads();
    __hip_bfloat16* dst = Vt + (size_t)bg * 128 * 768 + kt * 64;
    for (int i = tid; i < 1024; i += 256) {
        const int d = i >> 3, kc = i & 7;
        bf16x8 pk;
#pragma unroll
        for (int j = 0; j < 8; ++j) pk[j] = (short)Vs[kc * 8 + j][d];
        *(bf16x8*)(dst + (size_t)d * 768 + kc * 8) = pk;
    }
}

// ---- flash attention v2 ----
__global__ __launch_bounds__(256) void k_fattn(
    const __hip_bfloat16* __restrict__ qkv, const __hip_bfloat16* __restrict__ Vt,
    __hip_bfloat16* __restrict__ Out)
{
    const int id = blockIdx.x;
    const int xcd = id & 7, rest = id >> 3;
    const int bg = xcd * 4 + rest / 12;
    const int qt = rest % 12;
    const int b = bg >> 2, g = bg & 3;
    const int tid = threadIdx.x, lane = tid & 63, w = tid >> 6;
    const int row16 = lane & 15, kg = lane >> 4;
    const int q0 = qt * 64;

    __shared__ __hip_bfloat16 Klds[64][136];
    __shared__ __hip_bfloat16 Vtl[128][72];
    __shared__ __hip_bfloat16 Plds[4][16][72];

    const size_t rowQ = (size_t)(b * PP + q0 + w * 16 + row16) * 1536 + g * 128;
    bf16x8 aq[4];
#pragma unroll
    for (int t = 0; t < 4; ++t)
        aq[t] = *(const bf16x8*)(qkv + rowQ + t * 32 + kg * 8);

    f32x4 oacc[8];
#pragma unroll
    for (int dt = 0; dt < 8; ++dt) oacc[dt] = (f32x4){0.f, 0.f, 0.f, 0.f};
    float mrow[4] = {-3.0e38f, -3.0e38f, -3.0e38f, -3.0e38f};
    float lrow[4] = {0.f, 0.f, 0.f, 0.f};

    const __hip_bfloat16* Kb = qkv + (size_t)(b * PP) * 1536 + 512 + g * 128;
    const __hip_bfloat16* Vb = Vt + (size_t)bg * 128 * 768;
    const float sc = 0.08838834764831845f;

    const int krow = tid >> 2, kch = tid & 3;
    const int vrow = tid >> 1, vch = tid & 1;
    bf16x8 kreg[4], vreg[4];

    {
        const __hip_bfloat16* s1 = Kb + (size_t)krow * 1536 + kch * 32;
        const __hip_bfloat16* s2 = Vb + (size_t)vrow * 768 + vch * 32;
#pragma unroll
        for (int j = 0; j < 4; ++j) { kreg[j] = *(const bf16x8*)(s1 + j * 8);
                                      vreg[j] = *(const bf16x8*)(s2 + j * 8); }
    }

    for (int kt = 0; kt < 12; ++kt) {
        __syncthreads();
#pragma unroll
        for (int j = 0; j < 4; ++j) {
            *(bf16x8*)&Klds[krow][kch * 32 + j * 8] = kreg[j];
            *(bf16x8*)&Vtl[vrow][vch * 32 + j * 8] = vreg[j];
        }
        __syncthreads();
        if (kt < 11) {
            const __hip_bfloat16* s1 = Kb + (size_t)((kt + 1) * 64 + krow) * 1536 + kch * 32;
            const __hip_bfloat16* s2 = Vb + (size_t)vrow * 768 + (kt + 1) * 64 + vch * 32;
#pragma unroll
            for (int j = 0; j < 4; ++j) { kreg[j] = *(const bf16x8*)(s1 + j * 8);
                                          vreg[j] = *(const bf16x8*)(s2 + j * 8); }
        }

        f32x4 s4[4];
#pragma unroll
        for (int st = 0; st < 4; ++st) s4[st] = (f32x4){0.f, 0.f, 0.f, 0.f};
        __builtin_amdgcn_s_setprio(1);
#pragma unroll
        for (int st = 0; st < 4; ++st)
#pragma unroll
            for (int t = 0; t < 4; ++t)
                s4[st] = MFMA_BF16(aq[t],
                    *(const bf16x8*)&Klds[st * 16 + row16][t * 32 + kg * 8], s4[st], 0, 0, 0);
        __builtin_amdgcn_s_setprio(0);

        float pm[4];
#pragma unroll
        for (int r = 0; r < 4; ++r) {
            float m0 = fmaxf(fmaxf(s4[0][r], s4[1][r]), fmaxf(s4[2][r], s4[3][r])) * sc;
            m0 = fmaxf(m0, __shfl_xor(m0, 1));
            m0 = fmaxf(m0, __shfl_xor(m0, 2));
            m0 = fmaxf(m0, __shfl_xor(m0, 4));
            m0 = fmaxf(m0, __shfl_xor(m0, 8));
            pm[r] = m0;
        }
        const float need = fmaxf(fmaxf(pm[0] - mrow[0], pm[1] - mrow[1]),
                                 fmaxf(pm[2] - mrow[2], pm[3] - mrow[3]));
        if (!__all(need <= 8.0f)) {
#pragma unroll
            for (int r = 0; r < 4; ++r) {
                const float mn = fmaxf(mrow[r], pm[r]);
                const float so = __expf(mrow[r] - mn);
                lrow[r] *= so;
#pragma unroll
                for (int dt = 0; dt < 8; ++dt) oacc[dt][r] *= so;
                mrow[r] = mn;
            }
        }
#pragma unroll
        for (int r = 0; r < 4; ++r) {
            float rs = 0.f;
#pragma unroll
            for (int st = 0; st < 4; ++st) {
                const float p = __expf(s4[st][r] * sc - mrow[r]);
                rs += p;
                Plds[w][kg * 4 + r][st * 16 + row16] = to_bf16(p);
            }
            rs += __shfl_xor(rs, 1);
            rs += __shfl_xor(rs, 2);
            rs += __shfl_xor(rs, 4);
            rs += __shfl_xor(rs, 8);
            lrow[r] += rs;
        }

        __builtin_amdgcn_s_setprio(1);
#pragma unroll
        for (int ks = 0; ks < 2; ++ks) {
            bf16x8 ap = *(const bf16x8*)&Plds[w][row16][ks * 32 + kg * 8];
#pragma unroll
            for (int dt = 0; dt < 8; ++dt)
                oacc[dt] = MFMA_BF16(ap,
                    *(const bf16x8*)&Vtl[dt * 16 + row16][ks * 32 + kg * 8], oacc[dt], 0, 0, 0);
        }
        __builtin_amdgcn_s_setprio(0);
    }

    const size_t obase = (size_t)(b * PP + q0 + w * 16 + kg * 4) * DD + g * 128;
#pragma unroll
    for (int r = 0; r < 4; ++r) {
        const float inv = 1.0f / lrow[r];
#pragma unroll
        for (int dt = 0; dt < 8; ++dt)
            Out[obase + (size_t)r * DD + dt * 16 + row16] = to_bf16(oacc[dt][r] * inv);
    }
}

// ---- final heads ----
__global__ __launch_bounds__(64) void k_head(
    const __hip_bfloat16* __restrict__ clsreg, const __hip_bfloat16* __restrict__ ph,
    const float* __restrict__ cls_w2, const float* __restrict__ cls_b2,
    const float* __restrict__ p_w2, const float* __restrict__ p_b2,
    const float* __restrict__ b_scale, const float* __restrict__ b_bias,
    float* __restrict__ outp)
{
    const int bp = blockIdx.x;
    const int lane = threadIdx.x;
    const __hip_bfloat16* hr = clsreg + (size_t)bp * 1024;
    float a0 = 0.0f, a1 = 0.0f;
    for (int i = lane; i < DD; i += 64) {
        float h = bf2f(hr[i]);
        a0 = fmaf(h, cls_w2[i], a0);
        a1 = fmaf(h, cls_w2[DD + i], a1);
    }
    const __hip_bfloat16* pr = ph + (size_t)bp * 1024;
    float c0 = 0.0f, c1 = 0.0f, c2 = 0.0f, c3 = 0.0f;
    for (int i = lane; i < 1024; i += 64) {
        float h = bf2f(pr[i]);
        c0 = fmaf(h, p_w2[i], c0);
        c1 = fmaf(h, p_w2[1024 + i], c1);
        c2 = fmaf(h, p_w2[2048 + i], c2);
        c3 = fmaf(h, p_w2[3072 + i], c3);
    }
#pragma unroll
    for (int off = 32; off > 0; off >>= 1) {
        a0 += __shfl_down(a0, off);
        a1 += __shfl_down(a1, off);
        c0 += __shfl_down(c0, off);
        c1 += __shfl_down(c1, off);
        c2 += __shfl_down(c2, off);
        c3 += __shfl_down(c3, off);
    }
    a0 = __shfl(a0, 0); a1 = __shfl(a1, 0);
    c0 = __shfl(c0, 0); c1 = __shfl(c1, 0);
    c2 = __shfl(c2, 0); c3 = __shfl(c3, 0);
    const float k0 = c0 + p_b2[0];
    const float k1 = c1 + p_b2[1];
    const float scv = b_scale[0], biv = b_bias[0];
    const float k2 = (c2 + p_b2[2]) * scv + biv;
    const float k3 = (c3 + p_b2[3]) * scv + biv;
    float* orow = outp + (size_t)bp * 78;
    if (lane == 0) {
        orow[0] = a0 + cls_b2[0];
        orow[1] = a1 + cls_b2[1];
        orow[2] = k0; orow[3] = k1; orow[4] = k2; orow[5] = k3;
    }
    for (int o = lane; o < 72; o += 64) {
        float ys = (float)o / 71.0f;
        float tv = k0 + ys * (k1 + ys * (k2 + ys * k3));
        orow[6 + o] = 1.0f / (1.0f + expf(-tv));
    }
}

extern "C" void kernel_launch(void* const* d_in, const int* in_sizes, int n_in,
                              void* d_out, int out_size, void* d_ws, size_t ws_size,
                              hipStream_t stream)
{
    const float* feat0  = (const float*)d_in[0];
    const float* feat1  = (const float*)d_in[1];
    const float* feat2  = (const float*)d_in[2];
    const float* priors = (const float*)d_in[3];
    const float* ca_w   = (const float*)d_in[4];
    const float* ca_b   = (const float*)d_in[5];
    const float* off_w  = (const float*)d_in[6];
    const float* off_b  = (const float*)d_in[7];
    const float* dp_w   = (const float*)d_in[8];
    const float* dp_b   = (const float*)d_in[9];
    const float* z_emb  = (const float*)d_in[10];
    const float* gf_w   = (const float*)d_in[11];
    const float* gf_b   = (const float*)d_in[12];
    const float* wq     = (const float*)d_in[13];
    const float* bq     = (const float*)d_in[14];
    const float* wk     = (const float*)d_in[15];
    const float* bk     = (const float*)d_in[16];
    const float* wv     = (const float*)d_in[17];
    const float* bv     = (const float*)d_in[18];
    const float* wo     = (const float*)d_in[19];
    const float* bo     = (const float*)d_in[20];
    const float* cf_w1  = (const float*)d_in[21];
    const float* cf_b1  = (const float*)d_in[22];
    const float* cf_w2  = (const float*)d_in[23];
    const float* cf_b2  = (const float*)d_in[24];
    const float* cls_w1 = (const float*)d_in[25];
    const float* cls_b1 = (const float*)d_in[26];
    const float* cls_w2 = (const float*)d_in[27];
    const float* cls_b2 = (const float*)d_in[28];
    const float* reg_w1 = (const float*)d_in[29];
    const float* reg_b1 = (const float*)d_in[30];
    const float* p_w1   = (const float*)d_in[31];
    const float* p_b1   = (const float*)d_in[32];
    const float* p_w2   = (const float*)d_in[33];
    const float* p_b2   = (const float*)d_in[34];
    const float* b_scale = (const float*)d_in[35];
    const float* b_bias  = (const float*)d_in[36];
    float* out = (float*)d_out;

    char* wsb = (char*)d_ws;
    __hip_bfloat16* feature = (__hip_bfloat16*)(wsb + 0);          // [6144][512]
    __hip_bfloat16* qkvb    = (__hip_bfloat16*)(wsb + 6291456);    // [6144][1536]
    __hip_bfloat16* tb      = (__hip_bfloat16*)(wsb + 25165824);   // [6144][512]
    __hip_bfloat16* vtb     = (__hip_bfloat16*)(wsb + 31457280);   // Vt [32][128][768]
    __hip_bfloat16* rb      = (__hip_bfloat16*)(wsb + 31457280);   // wo out (after fattn)
    __hip_bfloat16* hb      = (__hip_bfloat16*)(wsb + 37748736);   // [6144][1024]
    __hip_bfloat16* f2      = (__hip_bfloat16*)(wsb + 50331648);   // [6144][512]
    __hip_bfloat16* clsregb = (__hip_bfloat16*)(wsb + 56623104);   // [6144][1024]
    __hip_bfloat16* phb     = (__hip_bfloat16*)(wsb + 69206016);   // [6144][1024]
    float* of1 = (float*)(wsb + 6291456);
    float* of2 = (float*)(wsb + 8595456);
    float* fe1 = (float*)(wsb + 9171456);
    float* fe2 = (float*)(wsb + 11475456);
    __hip_bfloat16* fsb = (__hip_bfloat16*)(wsb + 25165824);       // smp [6144][2688]
    float* fe0 = (float*)(wsb + 58195968);
    float* of0 = (float*)(wsb + 67411968);
    __hip_bfloat16* wqkv_bf   = (__hip_bfloat16*)(wsb + 81788928); // [1536][512]
    __hip_bfloat16* wo_bf     = (__hip_bfloat16*)(wsb + 83361792);
    __hip_bfloat16* cf1_bf    = (__hip_bfloat16*)(wsb + 83886080);
    __hip_bfloat16* cf2_bf    = (__hip_bfloat16*)(wsb + 84934656);
    __hip_bfloat16* clsreg_bf = (__hip_bfloat16*)(wsb + 85983232); // [1024][512]
    __hip_bfloat16* p1_bf     = (__hip_bfloat16*)(wsb + 87031808);
    __hip_bfloat16* gfw2_bf   = (__hip_bfloat16*)(wsb + 88080384); // [512][672]
    float* bqkv    = (float*)(wsb + 88768512);
    float* bclsreg = (float*)(wsb + 88774656);
    float* b2      = (float*)(wsb + 88778752);

    k_wcast<<<(3148288 + 255) / 256, 256, 0, stream>>>(
        wq, wk, wv, wo, cf_w1, cf_w2, cls_w1, reg_w1, p_w1, bq, bk, bv, cls_b1, reg_b1,
        wqkv_bf, wo_bf, cf1_bf, cf2_bf, clsreg_bf, p1_bf, bqkv, bclsreg);
    k_wfuse<<<512, 256, 0, stream>>>(gf_w, dp_w, gfw2_bf);
    k_wfuseb<<<2, 256, 0, stream>>>(gf_w, dp_b, gf_b, b2);

    k_adjoff<<<dim3(63, BB), 256, 0, stream>>>(feat0, ca_w, ca_b, off_w, off_b,
                                               fe0, of0, H0 * W0, 1);
    k_adjoff<<<dim3(16, BB), 256, 0, stream>>>(feat1, ca_w, ca_b, off_w, off_b,
                                               fe1, nullptr, H1 * W1, 0);
    k_adjoff<<<dim3(4, BB), 256, 0, stream>>>(feat2, ca_w, ca_b, off_w, off_b,
                                              fe2, nullptr, H2 * W2, 0);
    k_resize<<<(BB * H1 * W1 * CADJ + 255) / 256, 256, 0, stream>>>(of0, of1, H1, W1);
    k_resize<<<(BB * H2 * W2 * CADJ + 255) / 256, 256, 0, stream>>>(of0, of2, H2, W2);
    k_sample<<<BB * PP, 256, 0, stream>>>(priors, fe0, fe1, fe2, of0, of1, of2, z_emb, fsb);

    const int M = BB * PP;
    k_bgemm<<<dim3(1, M / 128, 4), 256, 0, stream>>>(
        fsb, 2688, 672, gfw2_bf, 672, 128 * 672, b2, 128,
        nullptr, 0, feature, DD, 128, 672, 0);
    k_bgemm<<<dim3(12, M / 128, 1), 256, 0, stream>>>(
        feature, DD, 0, wqkv_bf, DD, 0, bqkv, 0,
        nullptr, 0, qkvb, 1536, 0, DD, 0);
    k_vt<<<dim3(12, 32), 256, 0, stream>>>(qkvb, vtb);
    k_fattn<<<384, 256, 0, stream>>>(qkvb, vtb, tb);
    k_bgemm<<<dim3(4, M / 128, 1), 256, 0, stream>>>(
        tb, DD, 0, wo_bf, DD, 0, bo, 0, nullptr, 0, rb, DD, 0, DD, 0);
    k_bgemm<<<dim3(8, M / 128, 1), 256, 0, stream>>>(
        rb, DD, 0, cf1_bf, DD, 0, cf_b1, 0, nullptr, 0, hb, 1024, 0, DD, 1);
    k_bgemm<<<dim3(4, M / 128, 1), 256, 0, stream>>>(
        hb, 1024, 0, cf2_bf, 1024, 0, cf_b2, 0, feature, DD, f2, DD, 0, 1024, 0);
    k_bgemm<<<dim3(8, M / 128, 1), 256, 0, stream>>>(
        f2, DD, 0, clsreg_bf, DD, 0, bclsreg, 0, nullptr, 0, clsregb, 1024, 0, DD, 1);
    k_bgemm<<<dim3(8, M / 128, 1), 256, 0, stream>>>(
        clsregb + 512, 1024, 0, p1_bf, DD, 0, p_b1, 0, nullptr, 0, phb, 1024, 0, DD, 1);

    k_head<<<M, 64, 0, stream>>>(clsregb, phb, cls_w2, cls_b2, p_w2, p_b2, b_scale, b_bias, out);
}

// Round 9
// 320.079 us; speedup vs baseline: 9.3334x; 1.1625x over previous
//
#include <hip/hip_runtime.h>
#include <hip/hip_bf16.h>
#include <math.h>

#define BB 8
#define PP 768
#define NPRI 76
#define SS 36
#define CIN 64
#define CADJ 72
#define DD 512

#define H0 40
#define W0 100
#define H1 20
#define W1 50
#define H2 10
#define W2 25

typedef __attribute__((ext_vector_type(8))) short bf16x8;
typedef __attribute__((ext_vector_type(4))) float f32x4;
#define MFMA_BF16 __builtin_amdgcn_mfma_f32_16x16x32_bf16

typedef const __attribute__((address_space(1))) unsigned int* gas_t;
typedef __attribute__((address_space(3))) unsigned int* las_t;

__device__ __forceinline__ __hip_bfloat16 to_bf16(float v) { return __float2bfloat16(v); }
__device__ __forceinline__ float bf2f(__hip_bfloat16 v) { return __bfloat162float(v); }

// ---- bilinear sample, zeros outside ----
__device__ __forceinline__ float bsample(const float* __restrict__ img, int H, int W,
                                         int C, int c, float x, float y)
{
    float x0f = floorf(x), y0f = floorf(y);
    int x0 = (int)x0f, y0 = (int)y0f;
    float wx1 = x - x0f, wy1 = y - y0f;
    float wx0 = 1.0f - wx1, wy0 = 1.0f - wy1;
    int xc0 = min(max(x0, 0), W - 1);
    int xc1 = min(max(x0 + 1, 0), W - 1);
    int yc0 = min(max(y0, 0), H - 1);
    int yc1 = min(max(y0 + 1, 0), H - 1);
    bool vx0 = (x0 >= 0) && (x0 < W);
    bool vx1 = (x0 + 1 >= 0) && (x0 + 1 < W);
    bool vy0 = (y0 >= 0) && (y0 < H);
    bool vy1 = (y0 + 1 >= 0) && (y0 + 1 < H);
    float w00 = (vx0 && vy0) ? wx0 * wy0 : 0.0f;
    float w01 = (vx1 && vy0) ? wx1 * wy0 : 0.0f;
    float w10 = (vx0 && vy1) ? wx0 * wy1 : 0.0f;
    float w11 = (vx1 && vy1) ? wx1 * wy1 : 0.0f;
    return w00 * img[((size_t)yc0 * W + xc0) * C + c]
         + w01 * img[((size_t)yc0 * W + xc1) * C + c]
         + w10 * img[((size_t)yc1 * W + xc0) * C + c]
         + w11 * img[((size_t)yc1 * W + xc1) * C + c];
}

// ---- merged weight prep: wfuse (bid<512) | wfuseb (bid 512/513) | wcast (rest) ----
__global__ __launch_bounds__(256) void k_wprep(
    const float* __restrict__ wq, const float* __restrict__ wk, const float* __restrict__ wv,
    const float* __restrict__ wo, const float* __restrict__ cf_w1, const float* __restrict__ cf_w2,
    const float* __restrict__ cls_w1, const float* __restrict__ reg_w1, const float* __restrict__ p_w1,
    const float* __restrict__ bq, const float* __restrict__ bk, const float* __restrict__ bv,
    const float* __restrict__ cls_b1, const float* __restrict__ reg_b1,
    const float* __restrict__ gf_w, const float* __restrict__ dp_w,
    const float* __restrict__ dp_b, const float* __restrict__ gf_b,
    __hip_bfloat16* __restrict__ wqkv, __hip_bfloat16* __restrict__ wo_bf,
    __hip_bfloat16* __restrict__ cf1_bf, __hip_bfloat16* __restrict__ cf2_bf,
    __hip_bfloat16* __restrict__ clsreg_bf, __hip_bfloat16* __restrict__ p1_bf,
    __hip_bfloat16* __restrict__ gfw2, float* __restrict__ b2,
    float* __restrict__ bqkv, float* __restrict__ bclsreg)
{
    __shared__ float dpS[CADJ][CADJ + 1];
    __shared__ float gfr[648];
    const int bid = blockIdx.x;
    const int tid = threadIdx.x;

    if (bid < 512) {  // dp-fold into gf weights, o = bid
        const int o = bid;
        for (int i = tid; i < CADJ * CADJ; i += 256) dpS[i / CADJ][i % CADJ] = dp_w[i];
        for (int i = tid; i < 648; i += 256) gfr[i] = gf_w[(size_t)o * 648 + i];
        __syncthreads();
        for (int t = tid; t < 672; t += 256) {
            float acc = 0.0f;
            if (t < 648) {
                const int i = t / 72, m = t % 72;
                const float* gr = gfr + i * 72;
#pragma unroll 8
                for (int k = 0; k < 72; ++k) acc = fmaf(gr[k], dpS[k][m], acc);
            }
            gfw2[(size_t)o * 672 + t] = to_bf16(acc);
        }
        return;
    }
    if (bid < 514) {  // fused bias b2
        const int o = (bid - 512) * 256 + tid;
        if (o < DD) {
            const float* gr = gf_w + (size_t)o * 648;
            float acc = gf_b[o];
            for (int j = 0; j < 648; ++j) acc = fmaf(gr[j], dp_b[j % 72], acc);
            b2[o] = acc;
        }
        return;
    }
    long i = (long)(bid - 514) * 256 + tid;
    if (i < 262144) { wqkv[i] = to_bf16(wq[i]); return; }
    i -= 262144;
    if (i < 262144) { wqkv[262144 + i] = to_bf16(wk[i]); return; }
    i -= 262144;
    if (i < 262144) { wqkv[524288 + i] = to_bf16(wv[i]); return; }
    i -= 262144;
    if (i < 262144) { wo_bf[i] = to_bf16(wo[i]); return; }
    i -= 262144;
    if (i < 524288) { cf1_bf[i] = to_bf16(cf_w1[i]); return; }
    i -= 524288;
    if (i < 524288) { cf2_bf[i] = to_bf16(cf_w2[i]); return; }
    i -= 524288;
    if (i < 262144) { clsreg_bf[i] = to_bf16(cls_w1[i]); return; }
    i -= 262144;
    if (i < 262144) { clsreg_bf[262144 + i] = to_bf16(reg_w1[i]); return; }
    i -= 262144;
    if (i < 524288) { p1_bf[i] = to_bf16(p_w1[i]); return; }
    i -= 524288;
    if (i < 512) { bqkv[i] = bq[i]; return; }
    if (i < 1024) { bqkv[i] = bk[i - 512]; return; }
    if (i < 1536) { bqkv[i] = bv[i - 1024]; return; }
    i -= 1536;
    if (i < 512) { bclsreg[i] = cls_b1[i]; return; }
    if (i < 1024) { bclsreg[i] = reg_b1[i - 512]; return; }
}

// ---- fused tiled channel-adjust (+ optional offset head), 64 pixels/block ----
__global__ __launch_bounds__(256) void k_adjoff(
    const float* __restrict__ f, const float* __restrict__ caw, const float* __restrict__ cab,
    const float* __restrict__ offw, const float* __restrict__ offb,
    float* __restrict__ feout, float* __restrict__ offout, int HW, int do_off)
{
    __shared__ float inS[64][65];
    __shared__ float wS[72][64];
    __shared__ float owS[72][73];
    __shared__ float feS[64][73];
    __shared__ float cabS[72], obS[72];

    const int tid = threadIdx.x;
    const int b = blockIdx.y;
    const int pix0 = blockIdx.x * 64;
    const int cnt = min(64, HW - pix0);
    const int px = tid & 63, og = tid >> 6, o0 = og * 18;

    const float* fb = f + (size_t)b * CIN * HW + pix0;
    for (int i = tid; i < 72 * 64; i += 256) wS[i >> 6][i & 63] = caw[i];
    if (do_off)
        for (int i = tid; i < 72 * 72; i += 256) owS[i / 72][i % 72] = offw[i];
    if (tid < 72) { cabS[tid] = cab[tid]; obS[tid] = do_off ? offb[tid] : 0.f; }
    for (int i = tid; i < 64 * 64; i += 256) {
        const int c = i >> 6, p = i & 63;
        inS[c][p] = (p < cnt) ? fb[(size_t)c * HW + p] : 0.f;
    }
    __syncthreads();

    float acc[18];
#pragma unroll
    for (int j = 0; j < 18; ++j) acc[j] = cabS[o0 + j];
#pragma unroll 4
    for (int c = 0; c < 64; ++c) {
        const float v = inS[c][px];
#pragma unroll
        for (int j = 0; j < 18; ++j) acc[j] = fmaf(v, wS[o0 + j][c], acc[j]);
    }
#pragma unroll
    for (int j = 0; j < 18; ++j) feS[px][o0 + j] = acc[j];
    __syncthreads();

    float* feg = feout + ((size_t)b * HW + pix0) * CADJ;
    for (int i = tid; i < cnt * CADJ; i += 256) feg[i] = feS[i / CADJ][i % CADJ];

    if (!do_off) return;

    float acc2[18];
#pragma unroll
    for (int j = 0; j < 18; ++j) acc2[j] = obS[o0 + j];
#pragma unroll 4
    for (int c = 0; c < 72; ++c) {
        const float v = feS[px][c];
#pragma unroll
        for (int j = 0; j < 18; ++j) acc2[j] = fmaf(v, owS[o0 + j][c], acc2[j]);
    }
    __syncthreads();
#pragma unroll
    for (int j = 0; j < 18; ++j) feS[px][o0 + j] = acc2[j];
    __syncthreads();
    float* ofg = offout + ((size_t)b * HW + pix0) * CADJ;
    for (int i = tid; i < cnt * CADJ; i += 256) ofg[i] = feS[i / CADJ][i % CADJ];
}

// ---- merged align-corners resize (levels 1 and 2 in one dispatch) ----
__global__ __launch_bounds__(256) void k_resize2(const float* __restrict__ src,
    float* __restrict__ of1, float* __restrict__ of2)
{
    const int T1 = BB * H1 * W1 * CADJ;
    const int T2 = BB * H2 * W2 * CADJ;
    int idx = blockIdx.x * 256 + threadIdx.x;
    if (idx < T1) {
        const int c = idx % CADJ;
        const int j = (idx / CADJ) % W1;
        const int i = (idx / (CADJ * W1)) % H1;
        const int b = idx / (CADJ * W1 * H1);
        float sy = fminf((float)i * ((float)(H0 - 1) / (float)(H1 - 1)), (float)(H0 - 1));
        float sx = fminf((float)j * ((float)(W0 - 1) / (float)(W1 - 1)), (float)(W0 - 1));
        of1[idx] = bsample(src + (size_t)b * H0 * W0 * CADJ, H0, W0, CADJ, c, sx, sy);
        return;
    }
    idx -= T1;
    if (idx >= T2) return;
    const int c = idx % CADJ;
    const int j = (idx / CADJ) % W2;
    const int i = (idx / (CADJ * W2)) % H2;
    const int b = idx / (CADJ * W2 * H2);
    float sy = fminf((float)i * ((float)(H0 - 1) / (float)(H2 - 1)), (float)(H0 - 1));
    float sx = fminf((float)j * ((float)(W0 - 1) / (float)(W2 - 1)), (float)(W0 - 1));
    of2[idx] = bsample(src + (size_t)b * H0 * W0 * CADJ, H0, W0, CADJ, c, sx, sy);
}

// ---- sampling + z-fuse v3: 4 priors/block (grid 1536, XCD-batch-aligned) ----
__global__ __launch_bounds__(256) void k_sample(
    const float* __restrict__ priors,
    const float* __restrict__ feats0, const float* __restrict__ feats1, const float* __restrict__ feats2,
    const float* __restrict__ offs0,  const float* __restrict__ offs1,  const float* __restrict__ offs2,
    const float* __restrict__ z_emb,
    __hip_bfloat16* __restrict__ fsout)
{
    const int bid = blockIdx.x;                    // 1536
    const int gi = (bid & 7) * 192 + (bid >> 3);   // XCD x owns batch x
    const int bp0 = gi * 4;
    const int b = bp0 / PP;
    const int tid = threadIdx.x;

    __shared__ int   ib[4][3][SS][4];
    __shared__ float wz[4][3][SS][4];

    const int Hs[3] = {H0, H1, H2};
    const int Wsz[3] = {W0, W1, W2};
    const float* Fb[3] = { feats0 + (size_t)b * H0 * W0 * CADJ,
                           feats1 + (size_t)b * H1 * W1 * CADJ,
                           feats2 + (size_t)b * H2 * W2 * CADJ };
    const float* Ob[3] = { offs0 + (size_t)b * H0 * W0 * CADJ,
                           offs1 + (size_t)b * H1 * W1 * CADJ,
                           offs2 + (size_t)b * H2 * W2 * CADJ };

    for (int it = tid; it < 4 * 3 * SS; it += 256) {
        const int p = it / 108;
        const int l = (it % 108) / SS;
        const int s = it % SS;
        const int bp = bp0 + p;
        const float t = (float)(35 - s) / 35.0f;
        const int m = (int)floorf(t * 71.0f);
        const float pfx = priors[(size_t)bp * NPRI + 4 + m];
        const float gxv = fminf(fmaxf(pfx / 71.0f, 0.0f), 1.0f) * 2.0f - 1.0f;
        const float gyv = (1.0f - (float)m / 71.0f) * 2.0f - 1.0f;
        const float z = z_emb[s];
        const float e0 = expf(-0.5f * z * z);
        const float e1 = expf(-0.5f * (z - 1.0f) * (z - 1.0f));
        const float e2 = expf(-0.5f * (z - 2.0f) * (z - 2.0f));
        const float inv = 1.0f / (e0 + e1 + e2);
        const float ev[3] = {e0, e1, e2};
        const float zwl = ev[l] * inv;

        const int Hl = Hs[l], Wl = Wsz[l];
        const float px = (gxv + 1.0f) * 0.5f * (float)(Wl - 1);
        const float py = (gyv + 1.0f) * 0.5f * (float)(Hl - 1);
        const float dy = bsample(Ob[l], Hl, Wl, CADJ, 2 * s,     px, py);
        const float dx = bsample(Ob[l], Hl, Wl, CADJ, 2 * s + 1, px, py);
        const float sx = px + dx, sy = py + dy;
        const float x0f = floorf(sx), y0f = floorf(sy);
        const int x0 = (int)x0f, y0 = (int)y0f;
        const float wx1 = sx - x0f, wy1 = sy - y0f;
        const float wx0 = 1.0f - wx1, wy0 = 1.0f - wy1;
        const bool vx0 = (x0 >= 0) && (x0 < Wl);
        const bool vx1 = (x0 + 1 >= 0) && (x0 + 1 < Wl);
        const bool vy0 = (y0 >= 0) && (y0 < Hl);
        const bool vy1 = (y0 + 1 >= 0) && (y0 + 1 < Hl);
        const int xc0 = min(max(x0, 0), Wl - 1);
        const int xc1 = min(max(x0 + 1, 0), Wl - 1);
        const int yc0 = min(max(y0, 0), Hl - 1);
        const int yc1 = min(max(y0 + 1, 0), Hl - 1);
        wz[p][l][s][0] = ((vx0 && vy0) ? wx0 * wy0 : 0.0f) * zwl;
        wz[p][l][s][1] = ((vx1 && vy0) ? wx1 * wy0 : 0.0f) * zwl;
        wz[p][l][s][2] = ((vx0 && vy1) ? wx0 * wy1 : 0.0f) * zwl;
        wz[p][l][s][3] = ((vx1 && vy1) ? wx1 * wy1 : 0.0f) * zwl;
        ib[p][l][s][0] = (yc0 * Wl + xc0) * CADJ;
        ib[p][l][s][1] = (yc0 * Wl + xc1) * CADJ;
        ib[p][l][s][2] = (yc1 * Wl + xc0) * CADJ;
        ib[p][l][s][3] = (yc1 * Wl + xc1) * CADJ;
    }
    __syncthreads();

    for (int idx = tid; idx < 4 * SS * 36; idx += 256) {
        const int p = idx / 1296;
        const int rem = idx % 1296;
        const int s = rem / 36, k2 = (rem % 36) * 2;
        float a0 = 0.0f, a1 = 0.0f;
#pragma unroll
        for (int l = 0; l < 3; ++l) {
            const float* F = Fb[l];
            const int*   ibs = ib[p][l][s];
            const float* ws  = wz[p][l][s];
#pragma unroll
            for (int c = 0; c < 4; ++c) {
                const float2 v = *(const float2*)(F + ibs[c] + k2);
                a0 = fmaf(ws[c], v.x, a0);
                a1 = fmaf(ws[c], v.y, a1);
            }
        }
        __hip_bfloat162 pk;
        pk.x = to_bf16(a0);
        pk.y = to_bf16(a1);
        __hip_bfloat16* orow = fsout + (size_t)(bp0 + p) * 2688;
        *(__hip_bfloat162*)&orow[(s / 9) * 672 + (s % 9) * 72 + k2] = pk;
    }
    for (int t2 = tid; t2 < 4 * 96; t2 += 256) {
        const int p = t2 / 96, g = (t2 % 96) / 24, t = t2 % 24;
        fsout[(size_t)(bp0 + p) * 2688 + g * 672 + 648 + t] = to_bf16(0.0f);
    }
}

// ---- bf16 MFMA GEMM, 128x128 tile, global_load_lds staging (for large-N) ----
__global__ __launch_bounds__(256) void k_bgemm(
    const __hip_bfloat16* __restrict__ A, int lda, long sAz,
    const __hip_bfloat16* __restrict__ W, int ldw, long sWz,
    const float* __restrict__ bias, int sBz,
    const __hip_bfloat16* __restrict__ Res, int ldres,
    __hip_bfloat16* __restrict__ C, int ldc, int sCz,
    int K, int relu)
{
    __shared__ __hip_bfloat16 As[128][32];
    __shared__ __hip_bfloat16 Bs[128][32];
    const int tid = threadIdx.x;
    const int lane = tid & 63, w = tid >> 6;
    const int wr = w >> 1, wc = w & 1;
    const int row16 = lane & 15, kg = lane >> 4;
    const int z = blockIdx.z;
    const int m0 = blockIdx.y * 128, n0 = blockIdx.x * 128;
    const __hip_bfloat16* Ab = A + (size_t)z * sAz;
    const __hip_bfloat16* Wb = W + (size_t)z * sWz;
    const int gr = lane >> 2;
    const int gc = (lane & 3) * 8;

    f32x4 acc[4][4];
#pragma unroll
    for (int i = 0; i < 4; ++i)
#pragma unroll
        for (int j = 0; j < 4; ++j) acc[i][j] = (f32x4){0.f, 0.f, 0.f, 0.f};

    for (int k0 = 0; k0 < K; k0 += 32) {
        __syncthreads();
#pragma unroll
        for (int c = 0; c < 2; ++c) {
            const int r = w * 32 + c * 16;
            __builtin_amdgcn_global_load_lds(
                (gas_t)(Ab + (size_t)(m0 + r + gr) * lda + k0 + gc),
                (las_t)&As[r][0], 16, 0, 0);
            __builtin_amdgcn_global_load_lds(
                (gas_t)(Wb + (size_t)(n0 + r + gr) * ldw + k0 + gc),
                (las_t)&Bs[r][0], 16, 0, 0);
        }
        __syncthreads();
        bf16x8 af[4], bfr[4];
#pragma unroll
        for (int i = 0; i < 4; ++i) af[i]  = *(const bf16x8*)&As[wr * 64 + i * 16 + row16][kg * 8];
#pragma unroll
        for (int j = 0; j < 4; ++j) bfr[j] = *(const bf16x8*)&Bs[wc * 64 + j * 16 + row16][kg * 8];
#pragma unroll
        for (int i = 0; i < 4; ++i)
#pragma unroll
            for (int j = 0; j < 4; ++j)
                acc[i][j] = MFMA_BF16(af[i], bfr[j], acc[i][j], 0, 0, 0);
    }

    const float* bz = bias + (size_t)z * sBz;
    __hip_bfloat16* Cz = C + (size_t)z * sCz;
#pragma unroll
    for (int i = 0; i < 4; ++i) {
#pragma unroll
        for (int r = 0; r < 4; ++r) {
            const int row = m0 + wr * 64 + i * 16 + kg * 4 + r;
#pragma unroll
            for (int j = 0; j < 4; ++j) {
                const int col = n0 + wc * 64 + j * 16 + row16;
                float v = acc[i][j][r] + bz[col];
                if (Res) v += bf2f(Res[(size_t)row * ldres + col]);
                if (relu) v = fmaxf(v, 0.0f);
                Cz[(size_t)row * ldc + col] = to_bf16(v);
            }
        }
    }
}

// ---- bf16 MFMA GEMM, 64x64 tile (4 waves of 32x32) — for small-N GEMMs:
// grid = (N/64, M/64, nz); 3-6 blocks/CU instead of <=1.5 with 128 tiles
__global__ __launch_bounds__(256) void k_bgemm64(
    const __hip_bfloat16* __restrict__ A, int lda, long sAz,
    const __hip_bfloat16* __restrict__ W, int ldw, long sWz,
    const float* __restrict__ bias, int sBz,
    const __hip_bfloat16* __restrict__ Res, int ldres,
    __hip_bfloat16* __restrict__ C, int ldc, int sCz,
    int K, int relu)
{
    __shared__ __hip_bfloat16 As[64][32];
    __shared__ __hip_bfloat16 Bs[64][32];
    const int tid = threadIdx.x;
    const int lane = tid & 63, w = tid >> 6;
    const int wr = w >> 1, wc = w & 1;
    const int row16 = lane & 15, kg = lane >> 4;
    const int z = blockIdx.z;
    const int m0 = blockIdx.y * 64, n0 = blockIdx.x * 64;
    const __hip_bfloat16* Ab = A + (size_t)z * sAz;
    const __hip_bfloat16* Wb = W + (size_t)z * sWz;
    const int gr = lane >> 2;          // 16 rows per wave
    const int gc = (lane & 3) * 8;

    f32x4 acc[2][2];
#pragma unroll
    for (int i = 0; i < 2; ++i)
#pragma unroll
        for (int j = 0; j < 2; ++j) acc[i][j] = (f32x4){0.f, 0.f, 0.f, 0.f};

    for (int k0 = 0; k0 < K; k0 += 32) {
        __syncthreads();
        __builtin_amdgcn_global_load_lds(
            (gas_t)(Ab + (size_t)(m0 + w * 16 + gr) * lda + k0 + gc),
            (las_t)&As[w * 16][0], 16, 0, 0);
        __builtin_amdgcn_global_load_lds(
            (gas_t)(Wb + (size_t)(n0 + w * 16 + gr) * ldw + k0 + gc),
            (las_t)&Bs[w * 16][0], 16, 0, 0);
        __syncthreads();
        bf16x8 af[2], bfr[2];
#pragma unroll
        for (int i = 0; i < 2; ++i) af[i]  = *(const bf16x8*)&As[wr * 32 + i * 16 + row16][kg * 8];
#pragma unroll
        for (int j = 0; j < 2; ++j) bfr[j] = *(const bf16x8*)&Bs[wc * 32 + j * 16 + row16][kg * 8];
#pragma unroll
        for (int i = 0; i < 2; ++i)
#pragma unroll
            for (int j = 0; j < 2; ++j)
                acc[i][j] = MFMA_BF16(af[i], bfr[j], acc[i][j], 0, 0, 0);
    }

    const float* bz = bias + (size_t)z * sBz;
    __hip_bfloat16* Cz = C + (size_t)z * sCz;
#pragma unroll
    for (int i = 0; i < 2; ++i) {
#pragma unroll
        for (int r = 0; r < 4; ++r) {
            const int row = m0 + wr * 32 + i * 16 + kg * 4 + r;
#pragma unroll
            for (int j = 0; j < 2; ++j) {
                const int col = n0 + wc * 32 + j * 16 + row16;
                float v = acc[i][j][r] + bz[col];
                if (Res) v += bf2f(Res[(size_t)row * ldres + col]);
                if (relu) v = fmaxf(v, 0.0f);
                Cz[(size_t)row * ldc + col] = to_bf16(v);
            }
        }
    }
}

// ---- V transpose: qkv V-part -> Vt[bg][128 d][768 keys] ----
__global__ __launch_bounds__(256) void k_vt(
    const __hip_bfloat16* __restrict__ qkv, __hip_bfloat16* __restrict__ Vt)
{
    const int kt = blockIdx.x;
    const int bg = blockIdx.y;
    const int b = bg >> 2, g = bg & 3;
    const int tid = threadIdx.x;
    __shared__ unsigned short Vs[64][130];

    const __hip_bfloat16* src = qkv + (size_t)(b * PP + kt * 64) * 1536 + 1024 + g * 128;
    for (int i = tid; i < 1024; i += 256) {
        const int row = i >> 4, ch = i & 15;
        *(bf16x8*)&Vs[row][ch * 8] = *(const bf16x8*)(src + (size_t)row * 1536 + ch * 8);
    }
    __syncthreads();
    __hip_bfloat16* dst = Vt + (size_t)bg * 128 * 768 + kt * 64;
    for (int i = tid; i < 1024; i += 256) {
        const int d = i >> 3, kc = i & 7;
        bf16x8 pk;
#pragma unroll
        for (int j = 0; j < 8; ++j) pk[j] = (short)Vs[kc * 8 + j][d];
        *(bf16x8*)(dst + (size_t)d * 768 + kc * 8) = pk;
    }
}

// ---- flash attention v2 ----
__global__ __launch_bounds__(256) void k_fattn(
    const __hip_bfloat16* __restrict__ qkv, const __hip_bfloat16* __restrict__ Vt,
    __hip_bfloat16* __restrict__ Out)
{
    const int id = blockIdx.x;
    const int xcd = id & 7, rest = id >> 3;
    const int bg = xcd * 4 + rest / 12;
    const int qt = rest % 12;
    const int b = bg >> 2, g = bg & 3;
    const int tid = threadIdx.x, lane = tid & 63, w = tid >> 6;
    const int row16 = lane & 15, kg = lane >> 4;
    const int q0 = qt * 64;

    __shared__ __hip_bfloat16 Klds[64][136];
    __shared__ __hip_bfloat16 Vtl[128][72];
    __shared__ __hip_bfloat16 Plds[4][16][72];

    const size_t rowQ = (size_t)(b * PP + q0 + w * 16 + row16) * 1536 + g * 128;
    bf16x8 aq[4];
#pragma unroll
    for (int t = 0; t < 4; ++t)
        aq[t] = *(const bf16x8*)(qkv + rowQ + t * 32 + kg * 8);

    f32x4 oacc[8];
#pragma unroll
    for (int dt = 0; dt < 8; ++dt) oacc[dt] = (f32x4){0.f, 0.f, 0.f, 0.f};
    float mrow[4] = {-3.0e38f, -3.0e38f, -3.0e38f, -3.0e38f};
    float lrow[4] = {0.f, 0.f, 0.f, 0.f};

    const __hip_bfloat16* Kb = qkv + (size_t)(b * PP) * 1536 + 512 + g * 128;
    const __hip_bfloat16* Vb = Vt + (size_t)bg * 128 * 768;
    const float sc = 0.08838834764831845f;

    const int krow = tid >> 2, kch = tid & 3;
    const int vrow = tid >> 1, vch = tid & 1;
    bf16x8 kreg[4], vreg[4];

    {
        const __hip_bfloat16* s1 = Kb + (size_t)krow * 1536 + kch * 32;
        const __hip_bfloat16* s2 = Vb + (size_t)vrow * 768 + vch * 32;
#pragma unroll
        for (int j = 0; j < 4; ++j) { kreg[j] = *(const bf16x8*)(s1 + j * 8);
                                      vreg[j] = *(const bf16x8*)(s2 + j * 8); }
    }

    for (int kt = 0; kt < 12; ++kt) {
        __syncthreads();
#pragma unroll
        for (int j = 0; j < 4; ++j) {
            *(bf16x8*)&Klds[krow][kch * 32 + j * 8] = kreg[j];
            *(bf16x8*)&Vtl[vrow][vch * 32 + j * 8] = vreg[j];
        }
        __syncthreads();
        if (kt < 11) {
            const __hip_bfloat16* s1 = Kb + (size_t)((kt + 1) * 64 + krow) * 1536 + kch * 32;
            const __hip_bfloat16* s2 = Vb + (size_t)vrow * 768 + (kt + 1) * 64 + vch * 32;
#pragma unroll
            for (int j = 0; j < 4; ++j) { kreg[j] = *(const bf16x8*)(s1 + j * 8);
                                          vreg[j] = *(const bf16x8*)(s2 + j * 8); }
        }

        f32x4 s4[4];
#pragma unroll
        for (int st = 0; st < 4; ++st) s4[st] = (f32x4){0.f, 0.f, 0.f, 0.f};
        __builtin_amdgcn_s_setprio(1);
#pragma unroll
        for (int st = 0; st < 4; ++st)
#pragma unroll
            for (int t = 0; t < 4; ++t)
                s4[st] = MFMA_BF16(aq[t],
                    *(const bf16x8*)&Klds[st * 16 + row16][t * 32 + kg * 8], s4[st], 0, 0, 0);
        __builtin_amdgcn_s_setprio(0);

        float pm[4];
#pragma unroll
        for (int r = 0; r < 4; ++r) {
            float m0 = fmaxf(fmaxf(s4[0][r], s4[1][r]), fmaxf(s4[2][r], s4[3][r])) * sc;
            m0 = fmaxf(m0, __shfl_xor(m0, 1));
            m0 = fmaxf(m0, __shfl_xor(m0, 2));
            m0 = fmaxf(m0, __shfl_xor(m0, 4));
            m0 = fmaxf(m0, __shfl_xor(m0, 8));
            pm[r] = m0;
        }
        const float need = fmaxf(fmaxf(pm[0] - mrow[0], pm[1] - mrow[1]),
                                 fmaxf(pm[2] - mrow[2], pm[3] - mrow[3]));
        if (!__all(need <= 8.0f)) {
#pragma unroll
            for (int r = 0; r < 4; ++r) {
                const float mn = fmaxf(mrow[r], pm[r]);
                const float so = __expf(mrow[r] - mn);
                lrow[r] *= so;
#pragma unroll
                for (int dt = 0; dt < 8; ++dt) oacc[dt][r] *= so;
                mrow[r] = mn;
            }
        }
#pragma unroll
        for (int r = 0; r < 4; ++r) {
            float rs = 0.f;
#pragma unroll
            for (int st = 0; st < 4; ++st) {
                const float p = __expf(s4[st][r] * sc - mrow[r]);
                rs += p;
                Plds[w][kg * 4 + r][st * 16 + row16] = to_bf16(p);
            }
            rs += __shfl_xor(rs, 1);
            rs += __shfl_xor(rs, 2);
            rs += __shfl_xor(rs, 4);
            rs += __shfl_xor(rs, 8);
            lrow[r] += rs;
        }

        __builtin_amdgcn_s_setprio(1);
#pragma unroll
        for (int ks = 0; ks < 2; ++ks) {
            bf16x8 ap = *(const bf16x8*)&Plds[w][row16][ks * 32 + kg * 8];
#pragma unroll
            for (int dt = 0; dt < 8; ++dt)
                oacc[dt] = MFMA_BF16(ap,
                    *(const bf16x8*)&Vtl[dt * 16 + row16][ks * 32 + kg * 8], oacc[dt], 0, 0, 0);
        }
        __builtin_amdgcn_s_setprio(0);
    }

    const size_t obase = (size_t)(b * PP + q0 + w * 16 + kg * 4) * DD + g * 128;
#pragma unroll
    for (int r = 0; r < 4; ++r) {
        const float inv = 1.0f / lrow[r];
#pragma unroll
        for (int dt = 0; dt < 8; ++dt)
            Out[obase + (size_t)r * DD + dt * 16 + row16] = to_bf16(oacc[dt][r] * inv);
    }
}

// ---- final heads ----
__global__ __launch_bounds__(64) void k_head(
    const __hip_bfloat16* __restrict__ clsreg, const __hip_bfloat16* __restrict__ ph,
    const float* __restrict__ cls_w2, const float* __restrict__ cls_b2,
    const float* __restrict__ p_w2, const float* __restrict__ p_b2,
    const float* __restrict__ b_scale, const float* __restrict__ b_bias,
    float* __restrict__ outp)
{
    const int bp = blockIdx.x;
    const int lane = threadIdx.x;
    const __hip_bfloat16* hr = clsreg + (size_t)bp * 1024;
    float a0 = 0.0f, a1 = 0.0f;
    for (int i = lane; i < DD; i += 64) {
        float h = bf2f(hr[i]);
        a0 = fmaf(h, cls_w2[i], a0);
        a1 = fmaf(h, cls_w2[DD + i], a1);
    }
    const __hip_bfloat16* pr = ph + (size_t)bp * 1024;
    float c0 = 0.0f, c1 = 0.0f, c2 = 0.0f, c3 = 0.0f;
    for (int i = lane; i < 1024; i += 64) {
        float h = bf2f(pr[i]);
        c0 = fmaf(h, p_w2[i], c0);
        c1 = fmaf(h, p_w2[1024 + i], c1);
        c2 = fmaf(h, p_w2[2048 + i], c2);
        c3 = fmaf(h, p_w2[3072 + i], c3);
    }
#pragma unroll
    for (int off = 32; off > 0; off >>= 1) {
        a0 += __shfl_down(a0, off);
        a1 += __shfl_down(a1, off);
        c0 += __shfl_down(c0, off);
        c1 += __shfl_down(c1, off);
        c2 += __shfl_down(c2, off);
        c3 += __shfl_down(c3, off);
    }
    a0 = __shfl(a0, 0); a1 = __shfl(a1, 0);
    c0 = __shfl(c0, 0); c1 = __shfl(c1, 0);
    c2 = __shfl(c2, 0); c3 = __shfl(c3, 0);
    const float k0 = c0 + p_b2[0];
    const float k1 = c1 + p_b2[1];
    const float scv = b_scale[0], biv = b_bias[0];
    const float k2 = (c2 + p_b2[2]) * scv + biv;
    const float k3 = (c3 + p_b2[3]) * scv + biv;
    float* orow = outp + (size_t)bp * 78;
    if (lane == 0) {
        orow[0] = a0 + cls_b2[0];
        orow[1] = a1 + cls_b2[1];
        orow[2] = k0; orow[3] = k1; orow[4] = k2; orow[5] = k3;
    }
    for (int o = lane; o < 72; o += 64) {
        float ys = (float)o / 71.0f;
        float tv = k0 + ys * (k1 + ys * (k2 + ys * k3));
        orow[6 + o] = 1.0f / (1.0f + expf(-tv));
    }
}

extern "C" void kernel_launch(void* const* d_in, const int* in_sizes, int n_in,
                              void* d_out, int out_size, void* d_ws, size_t ws_size,
                              hipStream_t stream)
{
    const float* feat0  = (const float*)d_in[0];
    const float* feat1  = (const float*)d_in[1];
    const float* feat2  = (const float*)d_in[2];
    const float* priors = (const float*)d_in[3];
    const float* ca_w   = (const float*)d_in[4];
    const float* ca_b   = (const float*)d_in[5];
    const float* off_w  = (const float*)d_in[6];
    const float* off_b  = (const float*)d_in[7];
    const float* dp_w   = (const float*)d_in[8];
    const float* dp_b   = (const float*)d_in[9];
    const float* z_emb  = (const float*)d_in[10];
    const float* gf_w   = (const float*)d_in[11];
    const float* gf_b   = (const float*)d_in[12];
    const float* wq     = (const float*)d_in[13];
    const float* bq     = (const float*)d_in[14];
    const float* wk     = (const float*)d_in[15];
    const float* bk     = (const float*)d_in[16];
    const float* wv     = (const float*)d_in[17];
    const float* bv     = (const float*)d_in[18];
    const float* wo     = (const float*)d_in[19];
    const float* bo     = (const float*)d_in[20];
    const float* cf_w1  = (const float*)d_in[21];
    const float* cf_b1  = (const float*)d_in[22];
    const float* cf_w2  = (const float*)d_in[23];
    const float* cf_b2  = (const float*)d_in[24];
    const float* cls_w1 = (const float*)d_in[25];
    const float* cls_b1 = (const float*)d_in[26];
    const float* cls_w2 = (const float*)d_in[27];
    const float* cls_b2 = (const float*)d_in[28];
    const float* reg_w1 = (const float*)d_in[29];
    const float* reg_b1 = (const float*)d_in[30];
    const float* p_w1   = (const float*)d_in[31];
    const float* p_b1   = (const float*)d_in[32];
    const float* p_w2   = (const float*)d_in[33];
    const float* p_b2   = (const float*)d_in[34];
    const float* b_scale = (const float*)d_in[35];
    const float* b_bias  = (const float*)d_in[36];
    float* out = (float*)d_out;

    char* wsb = (char*)d_ws;
    __hip_bfloat16* feature = (__hip_bfloat16*)(wsb + 0);          // [6144][512]
    __hip_bfloat16* qkvb    = (__hip_bfloat16*)(wsb + 6291456);    // [6144][1536]
    __hip_bfloat16* tb      = (__hip_bfloat16*)(wsb + 25165824);   // [6144][512]
    __hip_bfloat16* vtb     = (__hip_bfloat16*)(wsb + 31457280);   // Vt [32][128][768]
    __hip_bfloat16* rb      = (__hip_bfloat16*)(wsb + 31457280);   // wo out (after fattn)
    __hip_bfloat16* hb      = (__hip_bfloat16*)(wsb + 37748736);   // [6144][1024]
    __hip_bfloat16* f2      = (__hip_bfloat16*)(wsb + 50331648);   // [6144][512]
    __hip_bfloat16* clsregb = (__hip_bfloat16*)(wsb + 56623104);   // [6144][1024]
    __hip_bfloat16* phb     = (__hip_bfloat16*)(wsb + 69206016);   // [6144][1024]
    float* of1 = (float*)(wsb + 6291456);
    float* of2 = (float*)(wsb + 8595456);
    float* fe1 = (float*)(wsb + 9171456);
    float* fe2 = (float*)(wsb + 11475456);
    __hip_bfloat16* fsb = (__hip_bfloat16*)(wsb + 25165824);       // smp [6144][2688]
    float* fe0 = (float*)(wsb + 58195968);
    float* of0 = (float*)(wsb + 67411968);
    __hip_bfloat16* wqkv_bf   = (__hip_bfloat16*)(wsb + 81788928); // [1536][512]
    __hip_bfloat16* wo_bf     = (__hip_bfloat16*)(wsb + 83361792);
    __hip_bfloat16* cf1_bf    = (__hip_bfloat16*)(wsb + 83886080);
    __hip_bfloat16* cf2_bf    = (__hip_bfloat16*)(wsb + 84934656);
    __hip_bfloat16* clsreg_bf = (__hip_bfloat16*)(wsb + 85983232); // [1024][512]
    __hip_bfloat16* p1_bf     = (__hip_bfloat16*)(wsb + 87031808);
    __hip_bfloat16* gfw2_bf   = (__hip_bfloat16*)(wsb + 88080384); // [512][672]
    float* bqkv    = (float*)(wsb + 88768512);
    float* bclsreg = (float*)(wsb + 88774656);
    float* b2      = (float*)(wsb + 88778752);

    // merged weight prep: 512 (wfuse) + 2 (wfuseb) + 12298 (wcast)
    k_wprep<<<12812, 256, 0, stream>>>(
        wq, wk, wv, wo, cf_w1, cf_w2, cls_w1, reg_w1, p_w1, bq, bk, bv, cls_b1, reg_b1,
        gf_w, dp_w, dp_b, gf_b,
        wqkv_bf, wo_bf, cf1_bf, cf2_bf, clsreg_bf, p1_bf, gfw2_bf, b2, bqkv, bclsreg);

    k_adjoff<<<dim3(63, BB), 256, 0, stream>>>(feat0, ca_w, ca_b, off_w, off_b,
                                               fe0, of0, H0 * W0, 1);
    k_adjoff<<<dim3(16, BB), 256, 0, stream>>>(feat1, ca_w, ca_b, off_w, off_b,
                                               fe1, nullptr, H1 * W1, 0);
    k_adjoff<<<dim3(4, BB), 256, 0, stream>>>(feat2, ca_w, ca_b, off_w, off_b,
                                              fe2, nullptr, H2 * W2, 0);
    k_resize2<<<(BB * (H1 * W1 + H2 * W2) * CADJ + 255) / 256, 256, 0, stream>>>(of0, of1, of2);
    k_sample<<<1536, 256, 0, stream>>>(priors, fe0, fe1, fe2, of0, of1, of2, z_emb, fsb);

    const int M = BB * PP;
    // gf (dp folded): per group N=128, K=672 — 64x64 tiles, grid (2,96,4)=768
    k_bgemm64<<<dim3(2, M / 64, 4), 256, 0, stream>>>(
        fsb, 2688, 672, gfw2_bf, 672, 128 * 672, b2, 128,
        nullptr, 0, feature, DD, 128, 672, 0);
    // QKV: N=1536, keep 128x128 (576 blocks)
    k_bgemm<<<dim3(12, M / 128, 1), 256, 0, stream>>>(
        feature, DD, 0, wqkv_bf, DD, 0, bqkv, 0,
        nullptr, 0, qkvb, 1536, 0, DD, 0);
    k_vt<<<dim3(12, 32), 256, 0, stream>>>(qkvb, vtb);
    k_fattn<<<384, 256, 0, stream>>>(qkvb, vtb, tb);
    k_bgemm64<<<dim3(8, M / 64, 1), 256, 0, stream>>>(
        tb, DD, 0, wo_bf, DD, 0, bo, 0, nullptr, 0, rb, DD, 0, DD, 0);
    k_bgemm64<<<dim3(16, M / 64, 1), 256, 0, stream>>>(
        rb, DD, 0, cf1_bf, DD, 0, cf_b1, 0, nullptr, 0, hb, 1024, 0, DD, 1);
    k_bgemm64<<<dim3(8, M / 64, 1), 256, 0, stream>>>(
        hb, 1024, 0, cf2_bf, 1024, 0, cf_b2, 0, feature, DD, f2, DD, 0, 1024, 0);
    k_bgemm64<<<dim3(16, M / 64, 1), 256, 0, stream>>>(
        f2, DD, 0, clsreg_bf, DD, 0, bclsreg, 0, nullptr, 0, clsregb, 1024, 0, DD, 1);
    k_bgemm64<<<dim3(16, M / 64, 1), 256, 0, stream>>>(
        clsregb + 512, 1024, 0, p1_bf, DD, 0, p_b1, 0, nullptr, 0, phb, 1024, 0, DD, 1);

    k_head<<<M, 64, 0, stream>>>(clsregb, phb, cls_w2, cls_b2, p_w2, p_b2, b_scale, b_bias, out);
}

// Round 10
// 306.417 us; speedup vs baseline: 9.7495x; 1.0446x over previous
//
#include <hip/hip_runtime.h>
#include <hip/hip_bf16.h>
#include <math.h>

#define BB 8
#define PP 768
#define NPRI 76
#define SS 36
#define CIN 64
#define CADJ 72
#define DD 512

#define H0 40
#define W0 100
#define H1 20
#define W1 50
#define H2 10
#define W2 25

typedef __attribute__((ext_vector_type(8))) short bf16x8;
typedef __attribute__((ext_vector_type(4))) short bf16x4;
typedef __attribute__((ext_vector_type(4))) float f32x4;
#define MFMA_BF16 __builtin_amdgcn_mfma_f32_16x16x32_bf16

typedef const __attribute__((address_space(1))) unsigned int* gas_t;
typedef __attribute__((address_space(3))) unsigned int* las_t;

__device__ __forceinline__ __hip_bfloat16 to_bf16(float v) { return __float2bfloat16(v); }
__device__ __forceinline__ float bf2f(__hip_bfloat16 v) { return __bfloat162float(v); }
__device__ __forceinline__ short to_bf16s(float v) {
    __hip_bfloat16 h = __float2bfloat16(v);
    return *reinterpret_cast<short*>(&h);
}

// ---- bilinear sample, zeros outside ----
__device__ __forceinline__ float bsample(const float* __restrict__ img, int H, int W,
                                         int C, int c, float x, float y)
{
    float x0f = floorf(x), y0f = floorf(y);
    int x0 = (int)x0f, y0 = (int)y0f;
    float wx1 = x - x0f, wy1 = y - y0f;
    float wx0 = 1.0f - wx1, wy0 = 1.0f - wy1;
    int xc0 = min(max(x0, 0), W - 1);
    int xc1 = min(max(x0 + 1, 0), W - 1);
    int yc0 = min(max(y0, 0), H - 1);
    int yc1 = min(max(y0 + 1, 0), H - 1);
    bool vx0 = (x0 >= 0) && (x0 < W);
    bool vx1 = (x0 + 1 >= 0) && (x0 + 1 < W);
    bool vy0 = (y0 >= 0) && (y0 < H);
    bool vy1 = (y0 + 1 >= 0) && (y0 + 1 < H);
    float w00 = (vx0 && vy0) ? wx0 * wy0 : 0.0f;
    float w01 = (vx1 && vy0) ? wx1 * wy0 : 0.0f;
    float w10 = (vx0 && vy1) ? wx0 * wy1 : 0.0f;
    float w11 = (vx1 && vy1) ? wx1 * wy1 : 0.0f;
    return w00 * img[((size_t)yc0 * W + xc0) * C + c]
         + w01 * img[((size_t)yc0 * W + xc1) * C + c]
         + w10 * img[((size_t)yc1 * W + xc0) * C + c]
         + w11 * img[((size_t)yc1 * W + xc1) * C + c];
}

// ---- merged weight prep: wfuse (bid<512) | wfuseb (bid 512/513) | wcast (rest) ----
__global__ __launch_bounds__(256) void k_wprep(
    const float* __restrict__ wq, const float* __restrict__ wk, const float* __restrict__ wv,
    const float* __restrict__ wo, const float* __restrict__ cf_w1, const float* __restrict__ cf_w2,
    const float* __restrict__ cls_w1, const float* __restrict__ reg_w1, const float* __restrict__ p_w1,
    const float* __restrict__ bq, const float* __restrict__ bk, const float* __restrict__ bv,
    const float* __restrict__ cls_b1, const float* __restrict__ reg_b1,
    const float* __restrict__ gf_w, const float* __restrict__ dp_w,
    const float* __restrict__ dp_b, const float* __restrict__ gf_b,
    __hip_bfloat16* __restrict__ wqkv, __hip_bfloat16* __restrict__ wo_bf,
    __hip_bfloat16* __restrict__ cf1_bf, __hip_bfloat16* __restrict__ cf2_bf,
    __hip_bfloat16* __restrict__ clsreg_bf, __hip_bfloat16* __restrict__ p1_bf,
    __hip_bfloat16* __restrict__ gfw2, float* __restrict__ b2,
    float* __restrict__ bqkv, float* __restrict__ bclsreg)
{
    __shared__ float dpS[CADJ][CADJ + 1];
    __shared__ float gfr[648];
    const int bid = blockIdx.x;
    const int tid = threadIdx.x;

    if (bid < 512) {
        const int o = bid;
        for (int i = tid; i < CADJ * CADJ; i += 256) dpS[i / CADJ][i % CADJ] = dp_w[i];
        for (int i = tid; i < 648; i += 256) gfr[i] = gf_w[(size_t)o * 648 + i];
        __syncthreads();
        for (int t = tid; t < 672; t += 256) {
            float acc = 0.0f;
            if (t < 648) {
                const int i = t / 72, m = t % 72;
                const float* gr = gfr + i * 72;
#pragma unroll 8
                for (int k = 0; k < 72; ++k) acc = fmaf(gr[k], dpS[k][m], acc);
            }
            gfw2[(size_t)o * 672 + t] = to_bf16(acc);
        }
        return;
    }
    if (bid < 514) {
        const int o = (bid - 512) * 256 + tid;
        if (o < DD) {
            const float* gr = gf_w + (size_t)o * 648;
            float acc = gf_b[o];
            for (int j = 0; j < 648; ++j) acc = fmaf(gr[j], dp_b[j % 72], acc);
            b2[o] = acc;
        }
        return;
    }
    long i = (long)(bid - 514) * 256 + tid;
    if (i < 262144) { wqkv[i] = to_bf16(wq[i]); return; }
    i -= 262144;
    if (i < 262144) { wqkv[262144 + i] = to_bf16(wk[i]); return; }
    i -= 262144;
    if (i < 262144) { wqkv[524288 + i] = to_bf16(wv[i]); return; }
    i -= 262144;
    if (i < 262144) { wo_bf[i] = to_bf16(wo[i]); return; }
    i -= 262144;
    if (i < 524288) { cf1_bf[i] = to_bf16(cf_w1[i]); return; }
    i -= 524288;
    if (i < 524288) { cf2_bf[i] = to_bf16(cf_w2[i]); return; }
    i -= 524288;
    if (i < 262144) { clsreg_bf[i] = to_bf16(cls_w1[i]); return; }
    i -= 262144;
    if (i < 262144) { clsreg_bf[262144 + i] = to_bf16(reg_w1[i]); return; }
    i -= 262144;
    if (i < 524288) { p1_bf[i] = to_bf16(p_w1[i]); return; }
    i -= 524288;
    if (i < 512) { bqkv[i] = bq[i]; return; }
    if (i < 1024) { bqkv[i] = bk[i - 512]; return; }
    if (i < 1536) { bqkv[i] = bv[i - 1024]; return; }
    i -= 1536;
    if (i < 512) { bclsreg[i] = cls_b1[i]; return; }
    if (i < 1024) { bclsreg[i] = reg_b1[i - 512]; return; }
}

// ---- fused tiled channel-adjust (+ optional offset head), 64 pixels/block ----
__global__ __launch_bounds__(256) void k_adjoff(
    const float* __restrict__ f, const float* __restrict__ caw, const float* __restrict__ cab,
    const float* __restrict__ offw, const float* __restrict__ offb,
    float* __restrict__ feout, float* __restrict__ offout, int HW, int do_off)
{
    __shared__ float inS[64][65];
    __shared__ float wS[72][64];
    __shared__ float owS[72][73];
    __shared__ float feS[64][73];
    __shared__ float cabS[72], obS[72];

    const int tid = threadIdx.x;
    const int b = blockIdx.y;
    const int pix0 = blockIdx.x * 64;
    const int cnt = min(64, HW - pix0);
    const int px = tid & 63, og = tid >> 6, o0 = og * 18;

    const float* fb = f + (size_t)b * CIN * HW + pix0;
    for (int i = tid; i < 72 * 64; i += 256) wS[i >> 6][i & 63] = caw[i];
    if (do_off)
        for (int i = tid; i < 72 * 72; i += 256) owS[i / 72][i % 72] = offw[i];
    if (tid < 72) { cabS[tid] = cab[tid]; obS[tid] = do_off ? offb[tid] : 0.f; }
    for (int i = tid; i < 64 * 64; i += 256) {
        const int c = i >> 6, p = i & 63;
        inS[c][p] = (p < cnt) ? fb[(size_t)c * HW + p] : 0.f;
    }
    __syncthreads();

    float acc[18];
#pragma unroll
    for (int j = 0; j < 18; ++j) acc[j] = cabS[o0 + j];
#pragma unroll 4
    for (int c = 0; c < 64; ++c) {
        const float v = inS[c][px];
#pragma unroll
        for (int j = 0; j < 18; ++j) acc[j] = fmaf(v, wS[o0 + j][c], acc[j]);
    }
#pragma unroll
    for (int j = 0; j < 18; ++j) feS[px][o0 + j] = acc[j];
    __syncthreads();

    float* feg = feout + ((size_t)b * HW + pix0) * CADJ;
    for (int i = tid; i < cnt * CADJ; i += 256) feg[i] = feS[i / CADJ][i % CADJ];

    if (!do_off) return;

    float acc2[18];
#pragma unroll
    for (int j = 0; j < 18; ++j) acc2[j] = obS[o0 + j];
#pragma unroll 4
    for (int c = 0; c < 72; ++c) {
        const float v = feS[px][c];
#pragma unroll
        for (int j = 0; j < 18; ++j) acc2[j] = fmaf(v, owS[o0 + j][c], acc2[j]);
    }
    __syncthreads();
#pragma unroll
    for (int j = 0; j < 18; ++j) feS[px][o0 + j] = acc2[j];
    __syncthreads();
    float* ofg = offout + ((size_t)b * HW + pix0) * CADJ;
    for (int i = tid; i < cnt * CADJ; i += 256) ofg[i] = feS[i / CADJ][i % CADJ];
}

// ---- merged align-corners resize (levels 1 and 2 in one dispatch) ----
__global__ __launch_bounds__(256) void k_resize2(const float* __restrict__ src,
    float* __restrict__ of1, float* __restrict__ of2)
{
    const int T1 = BB * H1 * W1 * CADJ;
    const int T2 = BB * H2 * W2 * CADJ;
    int idx = blockIdx.x * 256 + threadIdx.x;
    if (idx < T1) {
        const int c = idx % CADJ;
        const int j = (idx / CADJ) % W1;
        const int i = (idx / (CADJ * W1)) % H1;
        const int b = idx / (CADJ * W1 * H1);
        float sy = fminf((float)i * ((float)(H0 - 1) / (float)(H1 - 1)), (float)(H0 - 1));
        float sx = fminf((float)j * ((float)(W0 - 1) / (float)(W1 - 1)), (float)(W0 - 1));
        of1[idx] = bsample(src + (size_t)b * H0 * W0 * CADJ, H0, W0, CADJ, c, sx, sy);
        return;
    }
    idx -= T1;
    if (idx >= T2) return;
    const int c = idx % CADJ;
    const int j = (idx / CADJ) % W2;
    const int i = (idx / (CADJ * W2)) % H2;
    const int b = idx / (CADJ * W2 * H2);
    float sy = fminf((float)i * ((float)(H0 - 1) / (float)(H2 - 1)), (float)(H0 - 1));
    float sx = fminf((float)j * ((float)(W0 - 1) / (float)(W2 - 1)), (float)(W0 - 1));
    of2[idx] = bsample(src + (size_t)b * H0 * W0 * CADJ, H0, W0, CADJ, c, sx, sy);
}

// ---- sampling + z-fuse v4: 2 priors/block (grid 3072), float4 channel quads ----
__global__ __launch_bounds__(256) void k_sample(
    const float* __restrict__ priors,
    const float* __restrict__ feats0, const float* __restrict__ feats1, const float* __restrict__ feats2,
    const float* __restrict__ offs0,  const float* __restrict__ offs1,  const float* __restrict__ offs2,
    const float* __restrict__ z_emb,
    __hip_bfloat16* __restrict__ fsout)
{
    const int bid = blockIdx.x;                    // 3072
    const int gi = (bid & 7) * 384 + (bid >> 3);   // XCD x owns batch x
    const int bp0 = gi * 2;
    const int b = bp0 / PP;
    const int tid = threadIdx.x;

    __shared__ int   ib[2][3][SS][4];
    __shared__ float wz[2][3][SS][4];

    const int Hs[3] = {H0, H1, H2};
    const int Wsz[3] = {W0, W1, W2};
    const float* Fb[3] = { feats0 + (size_t)b * H0 * W0 * CADJ,
                           feats1 + (size_t)b * H1 * W1 * CADJ,
                           feats2 + (size_t)b * H2 * W2 * CADJ };
    const float* Ob[3] = { offs0 + (size_t)b * H0 * W0 * CADJ,
                           offs1 + (size_t)b * H1 * W1 * CADJ,
                           offs2 + (size_t)b * H2 * W2 * CADJ };

    if (tid < 2 * 3 * SS) {   // 216 items, single pass
        const int p = tid / 108;
        const int l = (tid % 108) / SS;
        const int s = tid % SS;
        const int bp = bp0 + p;
        const float t = (float)(35 - s) / 35.0f;
        const int m = (int)floorf(t * 71.0f);
        const float pfx = priors[(size_t)bp * NPRI + 4 + m];
        const float gxv = fminf(fmaxf(pfx / 71.0f, 0.0f), 1.0f) * 2.0f - 1.0f;
        const float gyv = (1.0f - (float)m / 71.0f) * 2.0f - 1.0f;
        const float z = z_emb[s];
        const float e0 = expf(-0.5f * z * z);
        const float e1 = expf(-0.5f * (z - 1.0f) * (z - 1.0f));
        const float e2 = expf(-0.5f * (z - 2.0f) * (z - 2.0f));
        const float inv = 1.0f / (e0 + e1 + e2);
        const float ev[3] = {e0, e1, e2};
        const float zwl = ev[l] * inv;

        const int Hl = Hs[l], Wl = Wsz[l];
        const float px = (gxv + 1.0f) * 0.5f * (float)(Wl - 1);
        const float py = (gyv + 1.0f) * 0.5f * (float)(Hl - 1);
        const float dy = bsample(Ob[l], Hl, Wl, CADJ, 2 * s,     px, py);
        const float dx = bsample(Ob[l], Hl, Wl, CADJ, 2 * s + 1, px, py);
        const float sx = px + dx, sy = py + dy;
        const float x0f = floorf(sx), y0f = floorf(sy);
        const int x0 = (int)x0f, y0 = (int)y0f;
        const float wx1 = sx - x0f, wy1 = sy - y0f;
        const float wx0 = 1.0f - wx1, wy0 = 1.0f - wy1;
        const bool vx0 = (x0 >= 0) && (x0 < Wl);
        const bool vx1 = (x0 + 1 >= 0) && (x0 + 1 < Wl);
        const bool vy0 = (y0 >= 0) && (y0 < Hl);
        const bool vy1 = (y0 + 1 >= 0) && (y0 + 1 < Hl);
        const int xc0 = min(max(x0, 0), Wl - 1);
        const int xc1 = min(max(x0 + 1, 0), Wl - 1);
        const int yc0 = min(max(y0, 0), Hl - 1);
        const int yc1 = min(max(y0 + 1, 0), Hl - 1);
        wz[p][l][s][0] = ((vx0 && vy0) ? wx0 * wy0 : 0.0f) * zwl;
        wz[p][l][s][1] = ((vx1 && vy0) ? wx1 * wy0 : 0.0f) * zwl;
        wz[p][l][s][2] = ((vx0 && vy1) ? wx0 * wy1 : 0.0f) * zwl;
        wz[p][l][s][3] = ((vx1 && vy1) ? wx1 * wy1 : 0.0f) * zwl;
        ib[p][l][s][0] = (yc0 * Wl + xc0) * CADJ;
        ib[p][l][s][1] = (yc0 * Wl + xc1) * CADJ;
        ib[p][l][s][2] = (yc1 * Wl + xc0) * CADJ;
        ib[p][l][s][3] = (yc1 * Wl + xc1) * CADJ;
    }
    __syncthreads();

    // main: 2 priors x 36 s x 18 channel-quads = 1296 items; float4 loads
    for (int idx = tid; idx < 2 * SS * 18; idx += 256) {
        const int p = idx / 648;
        const int rem = idx % 648;
        const int s = rem / 18, k4 = (rem % 18) * 4;
        float a0 = 0.f, a1 = 0.f, a2 = 0.f, a3 = 0.f;
#pragma unroll
        for (int l = 0; l < 3; ++l) {
            const float* F = Fb[l];
            const int*   ibs = ib[p][l][s];
            const float* ws  = wz[p][l][s];
#pragma unroll
            for (int c = 0; c < 4; ++c) {
                const float4 v = *(const float4*)(F + ibs[c] + k4);
                a0 = fmaf(ws[c], v.x, a0);
                a1 = fmaf(ws[c], v.y, a1);
                a2 = fmaf(ws[c], v.z, a2);
                a3 = fmaf(ws[c], v.w, a3);
            }
        }
        bf16x4 pk;
        pk[0] = to_bf16s(a0); pk[1] = to_bf16s(a1);
        pk[2] = to_bf16s(a2); pk[3] = to_bf16s(a3);
        __hip_bfloat16* orow = fsout + (size_t)(bp0 + p) * 2688;
        *(bf16x4*)&orow[(s / 9) * 672 + (s % 9) * 72 + k4] = pk;
    }
    if (tid < 2 * 96) {
        const int p = tid / 96, g = (tid % 96) / 24, t = tid % 24;
        fsout[(size_t)(bp0 + p) * 2688 + g * 672 + 648 + t] = to_bf16(0.0f);
    }
}

// ---- bf16 MFMA GEMM, 128x128 tile, global_load_lds staging (QKV) ----
__global__ __launch_bounds__(256) void k_bgemm(
    const __hip_bfloat16* __restrict__ A, int lda, long sAz,
    const __hip_bfloat16* __restrict__ W, int ldw, long sWz,
    const float* __restrict__ bias, int sBz,
    const __hip_bfloat16* __restrict__ Res, int ldres,
    __hip_bfloat16* __restrict__ C, int ldc, int sCz,
    int K, int relu)
{
    __shared__ __hip_bfloat16 As[128][32];
    __shared__ __hip_bfloat16 Bs[128][32];
    const int tid = threadIdx.x;
    const int lane = tid & 63, w = tid >> 6;
    const int wr = w >> 1, wc = w & 1;
    const int row16 = lane & 15, kg = lane >> 4;
    const int z = blockIdx.z;
    const int m0 = blockIdx.y * 128, n0 = blockIdx.x * 128;
    const __hip_bfloat16* Ab = A + (size_t)z * sAz;
    const __hip_bfloat16* Wb = W + (size_t)z * sWz;
    const int gr = lane >> 2;
    const int gc = (lane & 3) * 8;

    f32x4 acc[4][4];
#pragma unroll
    for (int i = 0; i < 4; ++i)
#pragma unroll
        for (int j = 0; j < 4; ++j) acc[i][j] = (f32x4){0.f, 0.f, 0.f, 0.f};

    for (int k0 = 0; k0 < K; k0 += 32) {
        __syncthreads();
#pragma unroll
        for (int c = 0; c < 2; ++c) {
            const int r = w * 32 + c * 16;
            __builtin_amdgcn_global_load_lds(
                (gas_t)(Ab + (size_t)(m0 + r + gr) * lda + k0 + gc),
                (las_t)&As[r][0], 16, 0, 0);
            __builtin_amdgcn_global_load_lds(
                (gas_t)(Wb + (size_t)(n0 + r + gr) * ldw + k0 + gc),
                (las_t)&Bs[r][0], 16, 0, 0);
        }
        __syncthreads();
        bf16x8 af[4], bfr[4];
#pragma unroll
        for (int i = 0; i < 4; ++i) af[i]  = *(const bf16x8*)&As[wr * 64 + i * 16 + row16][kg * 8];
#pragma unroll
        for (int j = 0; j < 4; ++j) bfr[j] = *(const bf16x8*)&Bs[wc * 64 + j * 16 + row16][kg * 8];
#pragma unroll
        for (int i = 0; i < 4; ++i)
#pragma unroll
            for (int j = 0; j < 4; ++j)
                acc[i][j] = MFMA_BF16(af[i], bfr[j], acc[i][j], 0, 0, 0);
    }

    const float* bz = bias + (size_t)z * sBz;
    __hip_bfloat16* Cz = C + (size_t)z * sCz;
#pragma unroll
    for (int i = 0; i < 4; ++i) {
#pragma unroll
        for (int r = 0; r < 4; ++r) {
            const int row = m0 + wr * 64 + i * 16 + kg * 4 + r;
#pragma unroll
            for (int j = 0; j < 4; ++j) {
                const int col = n0 + wc * 64 + j * 16 + row16;
                float v = acc[i][j][r] + bz[col];
                if (Res) v += bf2f(Res[(size_t)row * ldres + col]);
                if (relu) v = fmaxf(v, 0.0f);
                Cz[(size_t)row * ldc + col] = to_bf16(v);
            }
        }
    }
}

// ---- bf16 MFMA GEMM, 64x64 tile, DOUBLE-BUFFERED LDS (1 barrier per K-step) ----
// grid = (N/64, M/64, nz)
__global__ __launch_bounds__(256) void k_bgemm64(
    const __hip_bfloat16* __restrict__ A, int lda, long sAz,
    const __hip_bfloat16* __restrict__ W, int ldw, long sWz,
    const float* __restrict__ bias, int sBz,
    const __hip_bfloat16* __restrict__ Res, int ldres,
    __hip_bfloat16* __restrict__ C, int ldc, int sCz,
    int K, int relu)
{
    __shared__ __hip_bfloat16 As[2][64][32];   // 2 x 4KB
    __shared__ __hip_bfloat16 Bs[2][64][32];
    const int tid = threadIdx.x;
    const int lane = tid & 63, w = tid >> 6;
    const int wr = w >> 1, wc = w & 1;
    const int row16 = lane & 15, kg = lane >> 4;
    const int z = blockIdx.z;
    const int m0 = blockIdx.y * 64, n0 = blockIdx.x * 64;
    const __hip_bfloat16* Ab = A + (size_t)z * sAz;
    const __hip_bfloat16* Wb = W + (size_t)z * sWz;
    const int gr = lane >> 2;          // 16 rows per wave
    const int gc = (lane & 3) * 8;

    f32x4 acc[2][2];
#pragma unroll
    for (int i = 0; i < 2; ++i)
#pragma unroll
        for (int j = 0; j < 2; ++j) acc[i][j] = (f32x4){0.f, 0.f, 0.f, 0.f};

    // prologue: stage tile 0 into buffer 0
    __builtin_amdgcn_global_load_lds(
        (gas_t)(Ab + (size_t)(m0 + w * 16 + gr) * lda + gc),
        (las_t)&As[0][w * 16][0], 16, 0, 0);
    __builtin_amdgcn_global_load_lds(
        (gas_t)(Wb + (size_t)(n0 + w * 16 + gr) * ldw + gc),
        (las_t)&Bs[0][w * 16][0], 16, 0, 0);
    __syncthreads();   // implicit vmcnt(0) drain before barrier

    int cur = 0;
    for (int k0 = 0; k0 < K; k0 += 32) {
        if (k0 + 32 < K) {   // issue next tile's loads before compute (overlap)
            const int nxt = cur ^ 1;
            __builtin_amdgcn_global_load_lds(
                (gas_t)(Ab + (size_t)(m0 + w * 16 + gr) * lda + k0 + 32 + gc),
                (las_t)&As[nxt][w * 16][0], 16, 0, 0);
            __builtin_amdgcn_global_load_lds(
                (gas_t)(Wb + (size_t)(n0 + w * 16 + gr) * ldw + k0 + 32 + gc),
                (las_t)&Bs[nxt][w * 16][0], 16, 0, 0);
        }
        bf16x8 af[2], bfr[2];
#pragma unroll
        for (int i = 0; i < 2; ++i) af[i]  = *(const bf16x8*)&As[cur][wr * 32 + i * 16 + row16][kg * 8];
#pragma unroll
        for (int j = 0; j < 2; ++j) bfr[j] = *(const bf16x8*)&Bs[cur][wc * 32 + j * 16 + row16][kg * 8];
#pragma unroll
        for (int i = 0; i < 2; ++i)
#pragma unroll
            for (int j = 0; j < 2; ++j)
                acc[i][j] = MFMA_BF16(af[i], bfr[j], acc[i][j], 0, 0, 0);
        __syncthreads();   // drains the prefetch (vmcnt 0) + protects cur reuse
        cur ^= 1;
    }

    const float* bz = bias + (size_t)z * sBz;
    __hip_bfloat16* Cz = C + (size_t)z * sCz;
#pragma unroll
    for (int i = 0; i < 2; ++i) {
#pragma unroll
        for (int r = 0; r < 4; ++r) {
            const int row = m0 + wr * 32 + i * 16 + kg * 4 + r;
#pragma unroll
            for (int j = 0; j < 2; ++j) {
                const int col = n0 + wc * 32 + j * 16 + row16;
                float v = acc[i][j][r] + bz[col];
                if (Res) v += bf2f(Res[(size_t)row * ldres + col]);
                if (relu) v = fmaxf(v, 0.0f);
                Cz[(size_t)row * ldc + col] = to_bf16(v);
            }
        }
    }
}

// ---- V transpose: qkv V-part -> Vt[bg][128 d][768 keys] ----
__global__ __launch_bounds__(256) void k_vt(
    const __hip_bfloat16* __restrict__ qkv, __hip_bfloat16* __restrict__ Vt)
{
    const int kt = blockIdx.x;
    const int bg = blockIdx.y;
    const int b = bg >> 2, g = bg & 3;
    const int tid = threadIdx.x;
    __shared__ unsigned short Vs[64][130];

    const __hip_bfloat16* src = qkv + (size_t)(b * PP + kt * 64) * 1536 + 1024 + g * 128;
    for (int i = tid; i < 1024; i += 256) {
        const int row = i >> 4, ch = i & 15;
        *(bf16x8*)&Vs[row][ch * 8] = *(const bf16x8*)(src + (size_t)row * 1536 + ch * 8);
    }
    __syncthreads();
    __hip_bfloat16* dst = Vt + (size_t)bg * 128 * 768 + kt * 64;
    for (int i = tid; i < 1024; i += 256) {
        const int d = i >> 3, kc = i & 7;
        bf16x8 pk;
#pragma unroll
        for (int j = 0; j < 8; ++j) pk[j] = (short)Vs[kc * 8 + j][d];
        *(bf16x8*)(dst + (size_t)d * 768 + kc * 8) = pk;
    }
}

// ---- flash attention v2 ----
__global__ __launch_bounds__(256) void k_fattn(
    const __hip_bfloat16* __restrict__ qkv, const __hip_bfloat16* __restrict__ Vt,
    __hip_bfloat16* __restrict__ Out)
{
    const int id = blockIdx.x;
    const int xcd = id & 7, rest = id >> 3;
    const int bg = xcd * 4 + rest / 12;
    const int qt = rest % 12;
    const int b = bg >> 2, g = bg & 3;
    const int tid = threadIdx.x, lane = tid & 63, w = tid >> 6;
    const int row16 = lane & 15, kg = lane >> 4;
    const int q0 = qt * 64;

    __shared__ __hip_bfloat16 Klds[64][136];
    __shared__ __hip_bfloat16 Vtl[128][72];
    __shared__ __hip_bfloat16 Plds[4][16][72];

    const size_t rowQ = (size_t)(b * PP + q0 + w * 16 + row16) * 1536 + g * 128;
    bf16x8 aq[4];
#pragma unroll
    for (int t = 0; t < 4; ++t)
        aq[t] = *(const bf16x8*)(qkv + rowQ + t * 32 + kg * 8);

    f32x4 oacc[8];
#pragma unroll
    for (int dt = 0; dt < 8; ++dt) oacc[dt] = (f32x4){0.f, 0.f, 0.f, 0.f};
    float mrow[4] = {-3.0e38f, -3.0e38f, -3.0e38f, -3.0e38f};
    float lrow[4] = {0.f, 0.f, 0.f, 0.f};

    const __hip_bfloat16* Kb = qkv + (size_t)(b * PP) * 1536 + 512 + g * 128;
    const __hip_bfloat16* Vb = Vt + (size_t)bg * 128 * 768;
    const float sc = 0.08838834764831845f;

    const int krow = tid >> 2, kch = tid & 3;
    const int vrow = tid >> 1, vch = tid & 1;
    bf16x8 kreg[4], vreg[4];

    {
        const __hip_bfloat16* s1 = Kb + (size_t)krow * 1536 + kch * 32;
        const __hip_bfloat16* s2 = Vb + (size_t)vrow * 768 + vch * 32;
#pragma unroll
        for (int j = 0; j < 4; ++j) { kreg[j] = *(const bf16x8*)(s1 + j * 8);
                                      vreg[j] = *(const bf16x8*)(s2 + j * 8); }
    }

    for (int kt = 0; kt < 12; ++kt) {
        __syncthreads();
#pragma unroll
        for (int j = 0; j < 4; ++j) {
            *(bf16x8*)&Klds[krow][kch * 32 + j * 8] = kreg[j];
            *(bf16x8*)&Vtl[vrow][vch * 32 + j * 8] = vreg[j];
        }
        __syncthreads();
        if (kt < 11) {
            const __hip_bfloat16* s1 = Kb + (size_t)((kt + 1) * 64 + krow) * 1536 + kch * 32;
            const __hip_bfloat16* s2 = Vb + (size_t)vrow * 768 + (kt + 1) * 64 + vch * 32;
#pragma unroll
            for (int j = 0; j < 4; ++j) { kreg[j] = *(const bf16x8*)(s1 + j * 8);
                                          vreg[j] = *(const bf16x8*)(s2 + j * 8); }
        }

        f32x4 s4[4];
#pragma unroll
        for (int st = 0; st < 4; ++st) s4[st] = (f32x4){0.f, 0.f, 0.f, 0.f};
        __builtin_amdgcn_s_setprio(1);
#pragma unroll
        for (int st = 0; st < 4; ++st)
#pragma unroll
            for (int t = 0; t < 4; ++t)
                s4[st] = MFMA_BF16(aq[t],
                    *(const bf16x8*)&Klds[st * 16 + row16][t * 32 + kg * 8], s4[st], 0, 0, 0);
        __builtin_amdgcn_s_setprio(0);

        float pm[4];
#pragma unroll
        for (int r = 0; r < 4; ++r) {
            float m0 = fmaxf(fmaxf(s4[0][r], s4[1][r]), fmaxf(s4[2][r], s4[3][r])) * sc;
            m0 = fmaxf(m0, __shfl_xor(m0, 1));
            m0 = fmaxf(m0, __shfl_xor(m0, 2));
            m0 = fmaxf(m0, __shfl_xor(m0, 4));
            m0 = fmaxf(m0, __shfl_xor(m0, 8));
            pm[r] = m0;
        }
        const float need = fmaxf(fmaxf(pm[0] - mrow[0], pm[1] - mrow[1]),
                                 fmaxf(pm[2] - mrow[2], pm[3] - mrow[3]));
        if (!__all(need <= 8.0f)) {
#pragma unroll
            for (int r = 0; r < 4; ++r) {
                const float mn = fmaxf(mrow[r], pm[r]);
                const float so = __expf(mrow[r] - mn);
                lrow[r] *= so;
#pragma unroll
                for (int dt = 0; dt < 8; ++dt) oacc[dt][r] *= so;
                mrow[r] = mn;
            }
        }
#pragma unroll
        for (int r = 0; r < 4; ++r) {
            float rs = 0.f;
#pragma unroll
            for (int st = 0; st < 4; ++st) {
                const float p = __expf(s4[st][r] * sc - mrow[r]);
                rs += p;
                Plds[w][kg * 4 + r][st * 16 + row16] = to_bf16(p);
            }
            rs += __shfl_xor(rs, 1);
            rs += __shfl_xor(rs, 2);
            rs += __shfl_xor(rs, 4);
            rs += __shfl_xor(rs, 8);
            lrow[r] += rs;
        }

        __builtin_amdgcn_s_setprio(1);
#pragma unroll
        for (int ks = 0; ks < 2; ++ks) {
            bf16x8 ap = *(const bf16x8*)&Plds[w][row16][ks * 32 + kg * 8];
#pragma unroll
            for (int dt = 0; dt < 8; ++dt)
                oacc[dt] = MFMA_BF16(ap,
                    *(const bf16x8*)&Vtl[dt * 16 + row16][ks * 32 + kg * 8], oacc[dt], 0, 0, 0);
        }
        __builtin_amdgcn_s_setprio(0);
    }

    const size_t obase = (size_t)(b * PP + q0 + w * 16 + kg * 4) * DD + g * 128;
#pragma unroll
    for (int r = 0; r < 4; ++r) {
        const float inv = 1.0f / lrow[r];
#pragma unroll
        for (int dt = 0; dt < 8; ++dt)
            Out[obase + (size_t)r * DD + dt * 16 + row16] = to_bf16(oacc[dt][r] * inv);
    }
}

// ---- final heads ----
__global__ __launch_bounds__(64) void k_head(
    const __hip_bfloat16* __restrict__ clsreg, const __hip_bfloat16* __restrict__ ph,
    const float* __restrict__ cls_w2, const float* __restrict__ cls_b2,
    const float* __restrict__ p_w2, const float* __restrict__ p_b2,
    const float* __restrict__ b_scale, const float* __restrict__ b_bias,
    float* __restrict__ outp)
{
    const int bp = blockIdx.x;
    const int lane = threadIdx.x;
    const __hip_bfloat16* hr = clsreg + (size_t)bp * 1024;
    float a0 = 0.0f, a1 = 0.0f;
    for (int i = lane; i < DD; i += 64) {
        float h = bf2f(hr[i]);
        a0 = fmaf(h, cls_w2[i], a0);
        a1 = fmaf(h, cls_w2[DD + i], a1);
    }
    const __hip_bfloat16* pr = ph + (size_t)bp * 1024;
    float c0 = 0.0f, c1 = 0.0f, c2 = 0.0f, c3 = 0.0f;
    for (int i = lane; i < 1024; i += 64) {
        float h = bf2f(pr[i]);
        c0 = fmaf(h, p_w2[i], c0);
        c1 = fmaf(h, p_w2[1024 + i], c1);
        c2 = fmaf(h, p_w2[2048 + i], c2);
        c3 = fmaf(h, p_w2[3072 + i], c3);
    }
#pragma unroll
    for (int off = 32; off > 0; off >>= 1) {
        a0 += __shfl_down(a0, off);
        a1 += __shfl_down(a1, off);
        c0 += __shfl_down(c0, off);
        c1 += __shfl_down(c1, off);
        c2 += __shfl_down(c2, off);
        c3 += __shfl_down(c3, off);
    }
    a0 = __shfl(a0, 0); a1 = __shfl(a1, 0);
    c0 = __shfl(c0, 0); c1 = __shfl(c1, 0);
    c2 = __shfl(c2, 0); c3 = __shfl(c3, 0);
    const float k0 = c0 + p_b2[0];
    const float k1 = c1 + p_b2[1];
    const float scv = b_scale[0], biv = b_bias[0];
    const float k2 = (c2 + p_b2[2]) * scv + biv;
    const float k3 = (c3 + p_b2[3]) * scv + biv;
    float* orow = outp + (size_t)bp * 78;
    if (lane == 0) {
        orow[0] = a0 + cls_b2[0];
        orow[1] = a1 + cls_b2[1];
        orow[2] = k0; orow[3] = k1; orow[4] = k2; orow[5] = k3;
    }
    for (int o = lane; o < 72; o += 64) {
        float ys = (float)o / 71.0f;
        float tv = k0 + ys * (k1 + ys * (k2 + ys * k3));
        orow[6 + o] = 1.0f / (1.0f + expf(-tv));
    }
}

extern "C" void kernel_launch(void* const* d_in, const int* in_sizes, int n_in,
                              void* d_out, int out_size, void* d_ws, size_t ws_size,
                              hipStream_t stream)
{
    const float* feat0  = (const float*)d_in[0];
    const float* feat1  = (const float*)d_in[1];
    const float* feat2  = (const float*)d_in[2];
    const float* priors = (const float*)d_in[3];
    const float* ca_w   = (const float*)d_in[4];
    const float* ca_b   = (const float*)d_in[5];
    const float* off_w  = (const float*)d_in[6];
    const float* off_b  = (const float*)d_in[7];
    const float* dp_w   = (const float*)d_in[8];
    const float* dp_b   = (const float*)d_in[9];
    const float* z_emb  = (const float*)d_in[10];
    const float* gf_w   = (const float*)d_in[11];
    const float* gf_b   = (const float*)d_in[12];
    const float* wq     = (const float*)d_in[13];
    const float* bq     = (const float*)d_in[14];
    const float* wk     = (const float*)d_in[15];
    const float* bk     = (const float*)d_in[16];
    const float* wv     = (const float*)d_in[17];
    const float* bv     = (const float*)d_in[18];
    const float* wo     = (const float*)d_in[19];
    const float* bo     = (const float*)d_in[20];
    const float* cf_w1  = (const float*)d_in[21];
    const float* cf_b1  = (const float*)d_in[22];
    const float* cf_w2  = (const float*)d_in[23];
    const float* cf_b2  = (const float*)d_in[24];
    const float* cls_w1 = (const float*)d_in[25];
    const float* cls_b1 = (const float*)d_in[26];
    const float* cls_w2 = (const float*)d_in[27];
    const float* cls_b2 = (const float*)d_in[28];
    const float* reg_w1 = (const float*)d_in[29];
    const float* reg_b1 = (const float*)d_in[30];
    const float* p_w1   = (const float*)d_in[31];
    const float* p_b1   = (const float*)d_in[32];
    const float* p_w2   = (const float*)d_in[33];
    const float* p_b2   = (const float*)d_in[34];
    const float* b_scale = (const float*)d_in[35];
    const float* b_bias  = (const float*)d_in[36];
    float* out = (float*)d_out;

    char* wsb = (char*)d_ws;
    __hip_bfloat16* feature = (__hip_bfloat16*)(wsb + 0);          // [6144][512]
    __hip_bfloat16* qkvb    = (__hip_bfloat16*)(wsb + 6291456);    // [6144][1536]
    __hip_bfloat16* tb      = (__hip_bfloat16*)(wsb + 25165824);   // [6144][512]
    __hip_bfloat16* vtb     = (__hip_bfloat16*)(wsb + 31457280);   // Vt [32][128][768]
    __hip_bfloat16* rb      = (__hip_bfloat16*)(wsb + 31457280);   // wo out (after fattn)
    __hip_bfloat16* hb      = (__hip_bfloat16*)(wsb + 37748736);   // [6144][1024]
    __hip_bfloat16* f2      = (__hip_bfloat16*)(wsb + 50331648);   // [6144][512]
    __hip_bfloat16* clsregb = (__hip_bfloat16*)(wsb + 56623104);   // [6144][1024]
    __hip_bfloat16* phb     = (__hip_bfloat16*)(wsb + 69206016);   // [6144][1024]
    float* of1 = (float*)(wsb + 6291456);
    float* of2 = (float*)(wsb + 8595456);
    float* fe1 = (float*)(wsb + 9171456);
    float* fe2 = (float*)(wsb + 11475456);
    __hip_bfloat16* fsb = (__hip_bfloat16*)(wsb + 25165824);       // smp [6144][2688]
    float* fe0 = (float*)(wsb + 58195968);
    float* of0 = (float*)(wsb + 67411968);
    __hip_bfloat16* wqkv_bf   = (__hip_bfloat16*)(wsb + 81788928); // [1536][512]
    __hip_bfloat16* wo_bf     = (__hip_bfloat16*)(wsb + 83361792);
    __hip_bfloat16* cf1_bf    = (__hip_bfloat16*)(wsb + 83886080);
    __hip_bfloat16* cf2_bf    = (__hip_bfloat16*)(wsb + 84934656);
    __hip_bfloat16* clsreg_bf = (__hip_bfloat16*)(wsb + 85983232); // [1024][512]
    __hip_bfloat16* p1_bf     = (__hip_bfloat16*)(wsb + 87031808);
    __hip_bfloat16* gfw2_bf   = (__hip_bfloat16*)(wsb + 88080384); // [512][672]
    float* bqkv    = (float*)(wsb + 88768512);
    float* bclsreg = (float*)(wsb + 88774656);
    float* b2      = (float*)(wsb + 88778752);

    k_wprep<<<12812, 256, 0, stream>>>(
        wq, wk, wv, wo, cf_w1, cf_w2, cls_w1, reg_w1, p_w1, bq, bk, bv, cls_b1, reg_b1,
        gf_w, dp_w, dp_b, gf_b,
        wqkv_bf, wo_bf, cf1_bf, cf2_bf, clsreg_bf, p1_bf, gfw2_bf, b2, bqkv, bclsreg);

    k_adjoff<<<dim3(63, BB), 256, 0, stream>>>(feat0, ca_w, ca_b, off_w, off_b,
                                               fe0, of0, H0 * W0, 1);
    k_adjoff<<<dim3(16, BB), 256, 0, stream>>>(feat1, ca_w, ca_b, off_w, off_b,
                                               fe1, nullptr, H1 * W1, 0);
    k_adjoff<<<dim3(4, BB), 256, 0, stream>>>(feat2, ca_w, ca_b, off_w, off_b,
                                              fe2, nullptr, H2 * W2, 0);
    k_resize2<<<(BB * (H1 * W1 + H2 * W2) * CADJ + 255) / 256, 256, 0, stream>>>(of0, of1, of2);
    k_sample<<<3072, 256, 0, stream>>>(priors, fe0, fe1, fe2, of0, of1, of2, z_emb, fsb);

    const int M = BB * PP;
    k_bgemm64<<<dim3(2, M / 64, 4), 256, 0, stream>>>(
        fsb, 2688, 672, gfw2_bf, 672, 128 * 672, b2, 128,
        nullptr, 0, feature, DD, 128, 672, 0);
    k_bgemm<<<dim3(12, M / 128, 1), 256, 0, stream>>>(
        feature, DD, 0, wqkv_bf, DD, 0, bqkv, 0,
        nullptr, 0, qkvb, 1536, 0, DD, 0);
    k_vt<<<dim3(12, 32), 256, 0, stream>>>(qkvb, vtb);
    k_fattn<<<384, 256, 0, stream>>>(qkvb, vtb, tb);
    k_bgemm64<<<dim3(8, M / 64, 1), 256, 0, stream>>>(
        tb, DD, 0, wo_bf, DD, 0, bo, 0, nullptr, 0, rb, DD, 0, DD, 0);
    k_bgemm64<<<dim3(16, M / 64, 1), 256, 0, stream>>>(
        rb, DD, 0, cf1_bf, DD, 0, cf_b1, 0, nullptr, 0, hb, 1024, 0, DD, 1);
    k_bgemm64<<<dim3(8, M / 64, 1), 256, 0, stream>>>(
        hb, 1024, 0, cf2_bf, 1024, 0, cf_b2, 0, feature, DD, f2, DD, 0, 1024, 0);
    k_bgemm64<<<dim3(16, M / 64, 1), 256, 0, stream>>>(
        f2, DD, 0, clsreg_bf, DD, 0, bclsreg, 0, nullptr, 0, clsregb, 1024, 0, DD, 1);
    k_bgemm64<<<dim3(16, M / 64, 1), 256, 0, stream>>>(
        clsregb + 512, 1024, 0, p1_bf, DD, 0, p_b1, 0, nullptr, 0, phb, 1024, 0, DD, 1);

    k_head<<<M, 64, 0, stream>>>(clsregb, phb, cls_w2, cls_b2, p_w2, p_b2, b_scale, b_bias, out);
}